// Round 7
// baseline (10142.844 us; speedup 1.0000x reference)
//
#include <hip/hip_runtime.h>

#define EPS_LN 1e-5f

static constexpr int Bn  = 64;
static constexpr int Sn  = 512;
static constexpr int Hn  = 512;
static constexpr int G4n = 2048;

typedef unsigned int uint32;
typedef unsigned long long uint64;
typedef _Float16 h2v __attribute__((ext_vector_type(2)));

__device__ __forceinline__ float sigf(float x)     { return 1.0f / (1.0f + __expf(-x)); }
__device__ __forceinline__ float tanhfast(float x) { return 1.0f - 2.0f / (1.0f + __expf(2.0f * x)); }

// dot2: acc += w.lo*h.lo + w.hi*h.hi   (f16 inputs, fp32 accumulate)
__device__ __forceinline__ float dot2h(uint32 w, uint32 h, float acc) {
#if defined(__has_builtin)
#if __has_builtin(__builtin_amdgcn_fdot2)
  return __builtin_amdgcn_fdot2(__builtin_bit_cast(h2v, w), __builtin_bit_cast(h2v, h), acc, false);
#define DOT2_DONE 1
#endif
#endif
#ifndef DOT2_DONE
  h2v wv = __builtin_bit_cast(h2v, w);
  h2v hv = __builtin_bit_cast(h2v, h);
  return acc + (float)wv.x * (float)hv.x + (float)wv.y * (float)hv.y;
#endif
}
__device__ __forceinline__ uint32 packh2(float a, float b) {
  h2v v; v.x = (_Float16)a; v.y = (_Float16)b;
  return __builtin_bit_cast(uint32, v);
}

// ---- block reductions (256-thread kernels) ----
__device__ __forceinline__ float blk_sum(float v, float* sm, int tid) {
#pragma unroll
  for (int o = 32; o; o >>= 1) v += __shfl_down(v, o, 64);
  __syncthreads();
  if ((tid & 63) == 0) sm[tid >> 6] = v;
  __syncthreads();
  return sm[0] + sm[1] + sm[2] + sm[3];
}
__device__ __forceinline__ float blk_max(float v, float* sm, int tid) {
#pragma unroll
  for (int o = 32; o; o >>= 1) v = fmaxf(v, __shfl_down(v, o, 64));
  __syncthreads();
  if ((tid & 63) == 0) sm[tid >> 6] = v;
  __syncthreads();
  return fmaxf(fmaxf(sm[0], sm[1]), fmaxf(sm[2], sm[3]));
}

// ---- fused 4-value reduction across a 512-thread (8-wave) block ----
__device__ __forceinline__ void blk_sum4_w8(float& a, float& b, float& c, float& d,
                                            float* sm, int tid) {
#pragma unroll
  for (int o = 32; o; o >>= 1) {
    a += __shfl_down(a, o, 64);
    b += __shfl_down(b, o, 64);
    c += __shfl_down(c, o, 64);
    d += __shfl_down(d, o, 64);
  }
  __syncthreads();
  if ((tid & 63) == 0) {
    float4 v; v.x = a; v.y = b; v.z = c; v.w = d;
    *(float4*)&sm[(tid >> 6) * 4] = v;
  }
  __syncthreads();
  float ra = 0.f, rb = 0.f, rc = 0.f, rd = 0.f;
#pragma unroll
  for (int w = 0; w < 8; ++w) {
    float4 v = *(const float4*)&sm[w * 4];
    ra += v.x; rb += v.y; rc += v.z; rd += v.w;
  }
  a = ra; b = rb; c = rc; d = rd;
}

// ---- Wh pack: WhP[l][kp][n] = half2(Wh[l][n][2kp], Wh[l][n][2kp+1]) ----
__global__ __launch_bounds__(256) void wh_pack_k(
    const float* __restrict__ Wh, uint32* __restrict__ WhP)
{
  __shared__ float tile[32][33];
  const int l = blockIdx.z;
  const int k0 = blockIdx.x * 32;
  const int n0 = blockIdx.y * 32;
  const int row = threadIdx.x >> 5, col = threadIdx.x & 31;
  const float* src = Wh + (long)l * G4n * Hn;
  uint32* dst = WhP + (long)l * 256 * G4n;
#pragma unroll
  for (int rr = 0; rr < 4; ++rr) {
    int nn = row + rr * 8;
    tile[nn][col] = src[(long)(n0 + nn) * Hn + k0 + col];
  }
  __syncthreads();
#pragma unroll
  for (int rr = 0; rr < 2; ++rr) {
    int kpl = row + rr * 8;                     // 0..15
    int kp = (k0 >> 1) + kpl;
    dst[(long)kp * G4n + n0 + col] = packh2(tile[col][2*kpl], tile[col][2*kpl+1]);
  }
}

__global__ void init_zbuf_k(uint64* zbuf)
{
  long i = (long)blockIdx.x * 512 + threadIdx.x;
  zbuf[i] = 0ULL;
}

// ---- f16-packed GEMM: C[M,N] = A[M,K] @ Bw[N,K]^T + bias[N]; tiles 128x128 ----
// K=32 staging slabs (half the barrier count of the K=16 version); on-the-fly f16
// pack during LDS staging; fdot2 inner loop (2 MAC/instr); fp32 accumulate.
__global__ __launch_bounds__(256) void gemm_bias_k(
    const float* __restrict__ A, long lda,
    const float* __restrict__ Bw,
    const float* __restrict__ bias,
    float* __restrict__ C, long ldc, int K)
{
  __shared__ __align__(16) uint32 Ah[16][128];   // [k-pair][row]
  __shared__ __align__(16) uint32 Bh[16][128];
  const int tid = threadIdx.x;
  const long m0 = (long)blockIdx.y * 128;
  const long n0 = (long)blockIdx.x * 128;
  const int tx = tid & 15, ty = tid >> 4;
  const int lrow = tid >> 1;
  const int lc0  = (tid & 1) * 16;
  const int kb   = (tid & 1) * 8;
  float acc[8][8];
#pragma unroll
  for (int i = 0; i < 8; ++i)
#pragma unroll
    for (int j = 0; j < 8; ++j) acc[i][j] = 0.f;

  const float* Arow = A + (m0 + lrow) * lda;
  const float* Brow = Bw + (n0 + lrow) * (long)K;

  for (int k0 = 0; k0 < K; k0 += 32) {
    float4 a0 = *(const float4*)(Arow + k0 + lc0);
    float4 a1 = *(const float4*)(Arow + k0 + lc0 + 4);
    float4 a2 = *(const float4*)(Arow + k0 + lc0 + 8);
    float4 a3 = *(const float4*)(Arow + k0 + lc0 + 12);
    float4 b0 = *(const float4*)(Brow + k0 + lc0);
    float4 b1 = *(const float4*)(Brow + k0 + lc0 + 4);
    float4 b2 = *(const float4*)(Brow + k0 + lc0 + 8);
    float4 b3 = *(const float4*)(Brow + k0 + lc0 + 12);
    __syncthreads();
    Ah[kb+0][lrow] = packh2(a0.x, a0.y);
    Ah[kb+1][lrow] = packh2(a0.z, a0.w);
    Ah[kb+2][lrow] = packh2(a1.x, a1.y);
    Ah[kb+3][lrow] = packh2(a1.z, a1.w);
    Ah[kb+4][lrow] = packh2(a2.x, a2.y);
    Ah[kb+5][lrow] = packh2(a2.z, a2.w);
    Ah[kb+6][lrow] = packh2(a3.x, a3.y);
    Ah[kb+7][lrow] = packh2(a3.z, a3.w);
    Bh[kb+0][lrow] = packh2(b0.x, b0.y);
    Bh[kb+1][lrow] = packh2(b0.z, b0.w);
    Bh[kb+2][lrow] = packh2(b1.x, b1.y);
    Bh[kb+3][lrow] = packh2(b1.z, b1.w);
    Bh[kb+4][lrow] = packh2(b2.x, b2.y);
    Bh[kb+5][lrow] = packh2(b2.z, b2.w);
    Bh[kb+6][lrow] = packh2(b3.x, b3.y);
    Bh[kb+7][lrow] = packh2(b3.z, b3.w);
    __syncthreads();
#pragma unroll
    for (int kp = 0; kp < 16; ++kp) {
      uint32 a8[8], b8[8];
      *(uint4*)&a8[0] = *(const uint4*)&Ah[kp][ty*8];
      *(uint4*)&a8[4] = *(const uint4*)&Ah[kp][ty*8+4];
      *(uint4*)&b8[0] = *(const uint4*)&Bh[kp][tx*8];
      *(uint4*)&b8[4] = *(const uint4*)&Bh[kp][tx*8+4];
#pragma unroll
      for (int i = 0; i < 8; ++i)
#pragma unroll
        for (int j = 0; j < 8; ++j) acc[i][j] = dot2h(a8[i], b8[j], acc[i][j]);
    }
  }
#pragma unroll
  for (int i = 0; i < 8; ++i) {
    long m = m0 + ty*8 + i;
    float* crow = C + m * ldc + n0 + tx*8;
    const float* br = bias + n0 + tx*8;
    float4 o0, o1;
    o0.x = acc[i][0]+br[0]; o0.y = acc[i][1]+br[1]; o0.z = acc[i][2]+br[2]; o0.w = acc[i][3]+br[3];
    o1.x = acc[i][4]+br[4]; o1.y = acc[i][5]+br[5]; o1.z = acc[i][6]+br[6]; o1.w = acc[i][7]+br[7];
    *(float4*)crow = o0; *(float4*)(crow+4) = o1;
  }
}

// ---- ip-chunk GEMM (f16-packed fdot2, K=32 slabs), time-major: row r = t*64+b ----
__global__ __launch_bounds__(256) void gemm_ip_k(
    const float* __restrict__ A,       // [B,S,H]
    const float* __restrict__ Bw,      // [2048,512]
    const float* __restrict__ bias,
    float* __restrict__ C,             // [TCH*64, 2048]
    int s0)
{
  __shared__ __align__(16) uint32 Ah[16][128];
  __shared__ __align__(16) uint32 Bh[16][128];
  const int tid = threadIdx.x;
  const long m0 = (long)blockIdx.y * 128;
  const long n0 = (long)blockIdx.x * 128;
  const int tx = tid & 15, ty = tid >> 4;
  const int lrow = tid >> 1;
  const int lc0  = (tid & 1) * 16;
  const int kb   = (tid & 1) * 8;
  float acc[8][8];
#pragma unroll
  for (int i = 0; i < 8; ++i)
#pragma unroll
    for (int j = 0; j < 8; ++j) acc[i][j] = 0.f;

  const long r  = m0 + lrow;
  const long b  = r & 63;
  const long sl = r >> 6;
  const float* Arow = A + (b * Sn + s0 + sl) * Hn;
  const float* Brow = Bw + (n0 + lrow) * 512L;

  for (int k0 = 0; k0 < 512; k0 += 32) {
    float4 a0 = *(const float4*)(Arow + k0 + lc0);
    float4 a1 = *(const float4*)(Arow + k0 + lc0 + 4);
    float4 a2 = *(const float4*)(Arow + k0 + lc0 + 8);
    float4 a3 = *(const float4*)(Arow + k0 + lc0 + 12);
    float4 b0 = *(const float4*)(Brow + k0 + lc0);
    float4 b1 = *(const float4*)(Brow + k0 + lc0 + 4);
    float4 b2 = *(const float4*)(Brow + k0 + lc0 + 8);
    float4 b3 = *(const float4*)(Brow + k0 + lc0 + 12);
    __syncthreads();
    Ah[kb+0][lrow] = packh2(a0.x, a0.y);
    Ah[kb+1][lrow] = packh2(a0.z, a0.w);
    Ah[kb+2][lrow] = packh2(a1.x, a1.y);
    Ah[kb+3][lrow] = packh2(a1.z, a1.w);
    Ah[kb+4][lrow] = packh2(a2.x, a2.y);
    Ah[kb+5][lrow] = packh2(a2.z, a2.w);
    Ah[kb+6][lrow] = packh2(a3.x, a3.y);
    Ah[kb+7][lrow] = packh2(a3.z, a3.w);
    Bh[kb+0][lrow] = packh2(b0.x, b0.y);
    Bh[kb+1][lrow] = packh2(b0.z, b0.w);
    Bh[kb+2][lrow] = packh2(b1.x, b1.y);
    Bh[kb+3][lrow] = packh2(b1.z, b1.w);
    Bh[kb+4][lrow] = packh2(b2.x, b2.y);
    Bh[kb+5][lrow] = packh2(b2.z, b2.w);
    Bh[kb+6][lrow] = packh2(b3.x, b3.y);
    Bh[kb+7][lrow] = packh2(b3.z, b3.w);
    __syncthreads();
#pragma unroll
    for (int kp = 0; kp < 16; ++kp) {
      uint32 a8[8], b8[8];
      *(uint4*)&a8[0] = *(const uint4*)&Ah[kp][ty*8];
      *(uint4*)&a8[4] = *(const uint4*)&Ah[kp][ty*8+4];
      *(uint4*)&b8[0] = *(const uint4*)&Bh[kp][tx*8];
      *(uint4*)&b8[4] = *(const uint4*)&Bh[kp][tx*8+4];
#pragma unroll
      for (int i = 0; i < 8; ++i)
#pragma unroll
        for (int j = 0; j < 8; ++j) acc[i][j] = dot2h(a8[i], b8[j], acc[i][j]);
    }
  }
#pragma unroll
  for (int i = 0; i < 8; ++i) {
    long m = m0 + ty*8 + i;
    float* crow = C + m * 2048L + n0 + tx*8;
    const float* br = bias + n0 + tx*8;
    float4 o0, o1;
    o0.x = acc[i][0]+br[0]; o0.y = acc[i][1]+br[1]; o0.z = acc[i][2]+br[2]; o0.w = acc[i][3]+br[3];
    o1.x = acc[i][4]+br[4]; o1.y = acc[i][5]+br[5]; o1.z = acc[i][6]+br[6]; o1.w = acc[i][7]+br[7];
    *(float4*)crow = o0; *(float4*)(crow+4) = o1;
  }
}

// ---- M=64 GEMM (used for q projection) ----
__global__ __launch_bounds__(256) void gemm_m64_k(
    const float* __restrict__ A, long lda,
    const float* __restrict__ Bw,
    const float* __restrict__ bias,
    float* __restrict__ P,
    int N, int K)
{
  __shared__ float As[64][64];
  __shared__ float Bs[64][64];
  const int tid = threadIdx.x;
  const int n0 = blockIdx.x * 64;
  const int kc = blockIdx.y;
  const int Kc = K / gridDim.y;
  const int tx = tid & 15, ty = tid >> 4;
  const int row = tid >> 2, q = tid & 3;
  float acc[4][4];
#pragma unroll
  for (int i = 0; i < 4; ++i)
#pragma unroll
    for (int j = 0; j < 4; ++j) acc[i][j] = 0.f;

  for (int k0 = kc * Kc; k0 < kc * Kc + Kc; k0 += 64) {
    float4 a[4], b[4];
#pragma unroll
    for (int c = 0; c < 4; ++c) {
      a[c] = *(const float4*)(A  + (long)row * lda       + k0 + q*16 + c*4);
      b[c] = *(const float4*)(Bw + (long)(n0 + row) * K  + k0 + q*16 + c*4);
    }
    __syncthreads();
#pragma unroll
    for (int c = 0; c < 4; ++c) {
      int kb = q*16 + c*4;
      As[kb+0][row]=a[c].x; As[kb+1][row]=a[c].y; As[kb+2][row]=a[c].z; As[kb+3][row]=a[c].w;
      Bs[kb+0][row]=b[c].x; Bs[kb+1][row]=b[c].y; Bs[kb+2][row]=b[c].z; Bs[kb+3][row]=b[c].w;
    }
    __syncthreads();
#pragma unroll
    for (int kk = 0; kk < 64; ++kk) {
      float4 av = *(const float4*)&As[kk][ty*4];
      float4 bv = *(const float4*)&Bs[kk][tx*4];
      float am[4] = {av.x, av.y, av.z, av.w};
      float bm[4] = {bv.x, bv.y, bv.z, bv.w};
#pragma unroll
      for (int i = 0; i < 4; ++i)
#pragma unroll
        for (int j = 0; j < 4; ++j) acc[i][j] += am[i] * bm[j];
    }
  }
#pragma unroll
  for (int i = 0; i < 4; ++i) {
    int m = ty*4 + i;
    float* pr = P + ((long)kc * 64 + m) * N + n0 + tx*4;
#pragma unroll
    for (int j = 0; j < 4; ++j) {
      float bb = bias ? bias[n0 + tx*4 + j] : 0.f;
      pr[j] = acc[i][j] + bb;
    }
  }
}

// ---- persistent LSTM recurrence: n-split + tagged-word single-round exchange ----
// (verified kernel: 867us/128 steps, 0 bank conflicts. Publish pattern
//  myword=kq*512+tid gives contiguous full-line wave stores -- DO NOT change it;
//  the strided variant pushes the exchange out of L2, 5.5x slower. Packed-h LDS
//  split lo/hi at +132 words keeps the wave's two broadcast reads on disjoint
//  bank quads. BYTE-IDENTICAL to round 6; only nsteps/TCH changed at call site.)
__global__ __launch_bounds__(512, 2) void lstm_seqz_k(
    const uint32* __restrict__ WhP,   // [256 kp][2048 n] this layer (f16 pairs)
    const float* __restrict__ bh,
    const float* __restrict__ ipc,    // [TCH*64][2048] time-major LN'd input proj
    const float* __restrict__ g_hid, const float* __restrict__ b_hid,
    const float* __restrict__ g_cell, const float* __restrict__ b_cell,
    float* __restrict__ hst, float* __restrict__ cst,  // [64][512]
    float* __restrict__ hseq,         // [B,S,H]
    uint64* __restrict__ zbuf,        // [2 parity][32 g][2048 row][2 b] tagged words
    int t0, int nsteps, int gbase)    // gbase >= 1, monotonic over the whole run
{
  const int blk = blockIdx.x;
  const int g   = blk & 31;
  const int kq  = blk >> 5;
  const int tid = threadIdx.x;
  const int b0  = g*2, b1 = g*2 + 1;
  const int r   = tid >> 1;          // row within our 256-row slice
  const int kh  = tid & 1;           // k-half (0: k<256, 1: k>=256)
  // packed h pairs: lo half [0..127], hi half at +132 (bank-quad disjoint from lo)
  __shared__ __align__(16) uint32 hp0[264];
  __shared__ __align__(16) uint32 hp1[264];
  __shared__ float sm[32];

  // register-resident weights: rows kq*256+r, k-pairs kh*128 + [0,128)
  uint4 wreg[32];
  {
    const uint32* base = WhP + (long)(kh * 128) * 2048 + (kq*256 + r);
#pragma unroll
    for (int i = 0; i < 32; ++i) {
      wreg[i].x = base[(long)(4*i + 0) * 2048];
      wreg[i].y = base[(long)(4*i + 1) * 2048];
      wreg[i].z = base[(long)(4*i + 2) * 2048];
      wreg[i].w = base[(long)(4*i + 3) * 2048];
    }
  }

  // per-unit params/state: thread owns unit tid (both batches)
  float bhr[4], ghr[4], bhir[4];
#pragma unroll
  for (int q = 0; q < 4; ++q) {
    bhr[q]  = bh[q*512 + tid];
    ghr[q]  = g_hid[q*512 + tid];
    bhir[q] = b_hid[q*512 + tid];
  }
  const float gcv = g_cell[tid];
  const float bcv = b_cell[tid];
  float c0 = cst[b0*512 + tid];
  float c1 = cst[b1*512 + tid];
  float h0 = hst[b0*512 + tid];
  float h1 = hst[b1*512 + tid];

  // initial full-h pack into LDS (lo at j, hi at j+4 for j>=128)
  {
    const float p0 = __shfl_xor(h0, 1, 64);
    const float p1 = __shfl_xor(h1, 1, 64);
    if (!(tid & 1)) {
      const int j = tid >> 1;
      const int jj = (j < 128) ? j : j + 4;
      hp0[jj] = packh2(h0, p0);
      hp1[jj] = packh2(h1, p1);
    }
  }
  __syncthreads();

  const long myword = (long)(kq*256 + r) * 2 + kh;   // = kq*512 + tid (contiguous)
  const uint32* hb0 = hp0 + kh * 132;
  const uint32* hb1 = hp1 + kh * 132;

  for (int ts = 0; ts < nsteps; ++ts) {
    const int gstep = gbase + ts;
    const uint32 tagw = (uint32)gstep;
    uint64* zp = zbuf + (long)(gstep & 1) * 131072 + (long)g * 4096;

    // prefetch ip for our unit (regular cached loads; hide under GEMV)
    const float* iprow0 = ipc + ((long)ts * 64 + b0) * 2048 + tid;
    const float* iprow1 = ipc + ((long)ts * 64 + b1) * 2048 + tid;
    float ip0[4], ip1[4];
#pragma unroll
    for (int q = 0; q < 4; ++q) { ip0[q] = iprow0[q*512]; ip1[q] = iprow1[q*512]; }

    // GEMV: full-k half for row kq*256+r, both batches (h via LDS broadcast)
    float a0 = 0.f, a1 = 0.f;
#pragma unroll
    for (int i = 0; i < 32; ++i) {
      const uint4 w  = wreg[i];
      const uint4 hv0 = *(const uint4*)&hb0[4*i];
      const uint4 hv1 = *(const uint4*)&hb1[4*i];
      a0 = dot2h(w.x, hv0.x, a0); a0 = dot2h(w.y, hv0.y, a0);
      a0 = dot2h(w.z, hv0.z, a0); a0 = dot2h(w.w, hv0.w, a0);
      a1 = dot2h(w.x, hv1.x, a1); a1 = dot2h(w.y, hv1.y, a1);
      a1 = dot2h(w.z, hv1.z, a1); a1 = dot2h(w.w, hv1.w, a1);
    }
    // combine k-halves within the lane pair
    a0 += __shfl_xor(a0, 1, 64);
    a1 += __shfl_xor(a1, 1, 64);

    // publish one tagged word (fire-and-forget; tag rides with payload)
    {
      const float zval = kh ? a1 : a0;
      const uint64 w = ((uint64)tagw << 32) | (uint64)__builtin_bit_cast(uint32, zval);
      __hip_atomic_store(zp + myword, w, __ATOMIC_RELAXED, __HIP_MEMORY_SCOPE_AGENT);
    }

    // gather the 8 tagged words for unit tid: rows {tid,512+tid,1024+tid,1536+tid} x {b0,b1}
    float z0[4], z1[4];
    {
      uint64 v0[4], v1[4];
      int pend = 0xff;
      while (pend) {
#pragma unroll
        for (int q = 0; q < 4; ++q) {
          const long base = (long)(q*512 + tid) * 2;
          if (pend & (1 << q)) {
            uint64 w = __hip_atomic_load(zp + base, __ATOMIC_RELAXED, __HIP_MEMORY_SCOPE_AGENT);
            if ((uint32)(w >> 32) == tagw) { v0[q] = w; pend &= ~(1 << q); }
          }
          if (pend & (16 << q)) {
            uint64 w = __hip_atomic_load(zp + base + 1, __ATOMIC_RELAXED, __HIP_MEMORY_SCOPE_AGENT);
            if ((uint32)(w >> 32) == tagw) { v1[q] = w; pend &= ~(16 << q); }
          }
        }
        if (pend) __builtin_amdgcn_s_sleep(2);
      }
#pragma unroll
      for (int q = 0; q < 4; ++q) {
        z0[q] = __builtin_bit_cast(float, (uint32)v0[q]) + bhr[q];
        z1[q] = __builtin_bit_cast(float, (uint32)v1[q]) + bhr[q];
      }
    }

    // LN1 over 2048, both batches in one reduction pass
    float s10 = z0[0]+z0[1]+z0[2]+z0[3];
    float s20 = z0[0]*z0[0] + z0[1]*z0[1] + z0[2]*z0[2] + z0[3]*z0[3];
    float s11 = z1[0]+z1[1]+z1[2]+z1[3];
    float s21 = z1[0]*z1[0] + z1[1]*z1[1] + z1[2]*z1[2] + z1[3]*z1[3];
    blk_sum4_w8(s10, s20, s11, s21, sm, tid);
    const float m0 = s10 * (1.f/2048.f);
    const float r0 = rsqrtf(s20 * (1.f/2048.f) - m0*m0 + EPS_LN);
    const float m1 = s11 * (1.f/2048.f);
    const float r1 = rsqrtf(s21 * (1.f/2048.f) - m1*m1 + EPS_LN);

    const float gi0 = ip0[0] + (z0[0] - m0) * r0 * ghr[0] + bhir[0];
    const float gf0 = ip0[1] + (z0[1] - m0) * r0 * ghr[1] + bhir[1];
    const float gg0 = ip0[2] + (z0[2] - m0) * r0 * ghr[2] + bhir[2];
    const float go0 = ip0[3] + (z0[3] - m0) * r0 * ghr[3] + bhir[3];
    const float gi1 = ip1[0] + (z1[0] - m1) * r1 * ghr[0] + bhir[0];
    const float gf1 = ip1[1] + (z1[1] - m1) * r1 * ghr[1] + bhir[1];
    const float gg1 = ip1[2] + (z1[2] - m1) * r1 * ghr[2] + bhir[2];
    const float go1 = ip1[3] + (z1[3] - m1) * r1 * ghr[3] + bhir[3];

    c0 = sigf(gf0) * c0 + sigf(gi0) * tanhfast(gg0);
    c1 = sigf(gf1) * c1 + sigf(gi1) * tanhfast(gg1);

    // LN2 over 512 cells, both batches in one pass
    float t10 = c0, t20 = c0*c0, t11 = c1, t21 = c1*c1;
    blk_sum4_w8(t10, t20, t11, t21, sm, tid);
    const float n0 = t10 * (1.f/512.f);
    const float q0r = rsqrtf(t20 * (1.f/512.f) - n0*n0 + EPS_LN);
    const float n1 = t11 * (1.f/512.f);
    const float q1r = rsqrtf(t21 * (1.f/512.f) - n1*n1 + EPS_LN);
    h0 = sigf(go0) * tanhfast((c0 - n0) * q0r * gcv + bcv);
    h1 = sigf(go1) * tanhfast((c1 - n1) * q1r * gcv + bcv);

    if (kq == 0) {
      hseq[((long)b0 * Sn + t0 + ts) * Hn + tid] = h0;
      hseq[((long)b1 * Sn + t0 + ts) * Hn + tid] = h1;
    }

    // repack full h into LDS for next step (blk_sum4 already synced past GEMV reads)
    const float p0 = __shfl_xor(h0, 1, 64);
    const float p1 = __shfl_xor(h1, 1, 64);
    if (!(tid & 1)) {
      const int j = tid >> 1;
      const int jj = (j < 128) ? j : j + 4;
      hp0[jj] = packh2(h0, p0);
      hp1[jj] = packh2(h1, p1);
    }
    __syncthreads();
  }
  if (kq == 0) {
    hst[b0*512 + tid] = h0; hst[b1*512 + tid] = h1;
    cst[b0*512 + tid] = c0; cst[b1*512 + tid] = c1;
  }
}

// ---- layernorm over rows of 2048 (in-place) ----
__global__ __launch_bounds__(256) void ln_rows_k(
    float* __restrict__ X, const float* __restrict__ g, const float* __restrict__ bt)
{
  const long row = blockIdx.x;
  float* xr = X + row * 2048L;
  const int tid = threadIdx.x;
  __shared__ float sm[4];
  float4 v0 = *(float4*)(xr + tid*8);
  float4 v1 = *(float4*)(xr + tid*8 + 4);
  float s1 = v0.x+v0.y+v0.z+v0.w + v1.x+v1.y+v1.z+v1.w;
  float s2 = v0.x*v0.x+v0.y*v0.y+v0.z*v0.z+v0.w*v0.w
           + v1.x*v1.x+v1.y*v1.y+v1.z*v1.z+v1.w*v1.w;
  s1 = blk_sum(s1, sm, tid);
  s2 = blk_sum(s2, sm, tid);
  const float mean = s1 * (1.f/2048.f);
  const float rstd = rsqrtf(s2 * (1.f/2048.f) - mean*mean + EPS_LN);
  const int base = tid*8;
  float vals[8] = {v0.x,v0.y,v0.z,v0.w,v1.x,v1.y,v1.z,v1.w};
#pragma unroll
  for (int c = 0; c < 8; ++c)
    xr[base + c] = (vals[c] - mean) * rstd * g[base + c] + bt[base + c];
}

// ---- highway combine (elementwise), optional residual skip ----
__global__ __launch_bounds__(256) void highway_ew_k(
    const float* __restrict__ T1, const float* __restrict__ T2, const float* __restrict__ T3,
    const float* __restrict__ hs, float* __restrict__ seq, int skip)
{
  long i = ((long)blockIdx.x * 256 + threadIdx.x) * 4;
  float4 t1 = *(const float4*)(T1 + i);
  float4 t2 = *(const float4*)(T2 + i);
  float4 t3 = *(const float4*)(T3 + i);
  float4 hv = *(const float4*)(hs + i);
  float4 sv;
  if (skip) sv = *(const float4*)(seq + i); else { sv.x=0; sv.y=0; sv.z=0; sv.w=0; }
  float4 o;
  o.x = sigf(t1.x) * fmaxf(t3.x, 0.f) + sigf(t2.x) * hv.x + sv.x;
  o.y = sigf(t1.y) * fmaxf(t3.y, 0.f) + sigf(t2.y) * hv.y + sv.y;
  o.z = sigf(t1.z) * fmaxf(t3.z, 0.f) + sigf(t2.z) * hv.z + sv.z;
  o.w = sigf(t1.w) * fmaxf(t3.w, 0.f) + sigf(t2.w) * hv.w + sv.w;
  *(float4*)(seq + i) = o;
}

__global__ void init_hc_k(float* h, float* c)
{
  int i = blockIdx.x * 256 + threadIdx.x;
  h[i] = 0.f; c[i] = 0.f;
}

// ---- qkh[b][hd][:] = sum_{j in head} q[b, hd*64+j] * Wk[hd*64+j, :]; qbk = q.bk ----
__global__ __launch_bounds__(256) void qkh_k(
    const float* __restrict__ qlst, const float* __restrict__ Wk,
    const float* __restrict__ bk,
    float* __restrict__ qkh, float* __restrict__ qbk)
{
  const int hd = blockIdx.x, cg = blockIdx.y;
  const int b = threadIdx.x & 63, sc = threadIdx.x >> 6;
  const int col0 = cg * 128 + sc * 32;
  float qreg[64];
  const float* qp = qlst + b*512 + hd*64;
#pragma unroll
  for (int j4 = 0; j4 < 16; ++j4) {
    float4 v = *(const float4*)(qp + j4*4);
    qreg[j4*4+0]=v.x; qreg[j4*4+1]=v.y; qreg[j4*4+2]=v.z; qreg[j4*4+3]=v.w;
  }
  float acc[32];
#pragma unroll
  for (int c = 0; c < 32; ++c) acc[c] = 0.f;
  for (int j = 0; j < 64; ++j) {
    float qv = qreg[j];
    const float* wr = Wk + (long)(hd*64 + j)*512 + col0;
#pragma unroll
    for (int c4 = 0; c4 < 8; ++c4) {
      float4 w = *(const float4*)(wr + c4*4);
      acc[c4*4+0] = __builtin_fmaf(qv, w.x, acc[c4*4+0]);
      acc[c4*4+1] = __builtin_fmaf(qv, w.y, acc[c4*4+1]);
      acc[c4*4+2] = __builtin_fmaf(qv, w.z, acc[c4*4+2]);
      acc[c4*4+3] = __builtin_fmaf(qv, w.w, acc[c4*4+3]);
    }
  }
  float* op = qkh + ((long)b*8 + hd)*512 + col0;
#pragma unroll
  for (int c4 = 0; c4 < 8; ++c4) {
    float4 o;
    o.x = acc[c4*4+0]; o.y = acc[c4*4+1]; o.z = acc[c4*4+2]; o.w = acc[c4*4+3];
    *(float4*)(op + c4*4) = o;
  }
  if (cg == 0 && sc == 0) {
    float s = 0.f;
    for (int j = 0; j < 64; ++j) s += qreg[j] * bk[hd*64 + j];
    qbk[b*8 + hd] = s;
  }
}

// ---- fused last-row attention ----
__global__ __launch_bounds__(256) void attn2_k(
    const float* __restrict__ seq,   // [B,S,H]
    const float* __restrict__ qkh,   // [64][8][512]
    const float* __restrict__ qbk,   // [64][8]
    float* __restrict__ u)           // [64][8][512]
{
  const int b = blockIdx.x, hd = blockIdx.y, tid = threadIdx.x;
  __shared__ __align__(16) float qk[512];
  __shared__ float p[512];
  __shared__ float sm[4];
  qk[tid]       = qkh[((long)b*8 + hd)*512 + tid];
  qk[tid + 256] = qkh[((long)b*8 + hd)*512 + tid + 256];
  __syncthreads();
  const float bias = qbk[b*8 + hd];

  float loc[2]; float mx = -3.0e38f;
#pragma unroll
  for (int v = 0; v < 2; ++v) {
    int s = tid + v*256;
    const float4* sr = (const float4*)(seq + ((long)b*512 + s)*512);
    const float4* qv4 = (const float4*)qk;
    float d = 0.f;
    for (int k4 = 0; k4 < 128; ++k4) {
      float4 sv = sr[k4], qv = qv4[k4];
      d += sv.x*qv.x + sv.y*qv.y + sv.z*qv.z + sv.w*qv.w;
    }
    d = (d + bias) * 0.125f;
    loc[v] = d; mx = fmaxf(mx, d);
  }
  const float M = blk_max(mx, sm, tid);
  float sum = 0.f;
#pragma unroll
  for (int v = 0; v < 2; ++v) {
    int s = tid + v*256;
    float e = __expf(loc[v] - M);
    p[s] = e; sum += e;
  }
  const float SM = blk_sum(sum, sm, tid);
  const float inv = 1.f / SM;

  float u0 = 0.f, u1 = 0.f;
  for (int s = 0; s < 512; ++s) {
    float ps = p[s];
    const float* srow = seq + ((long)b*512 + s)*512;
    u0 = __builtin_fmaf(ps, srow[tid], u0);
    u1 = __builtin_fmaf(ps, srow[tid + 256], u1);
  }
  u[((long)b*8 + hd)*512 + tid]       = u0 * inv;
  u[((long)b*8 + hd)*512 + tid + 256] = u1 * inv;
}

// ---- ctx[b][n] = u[b][hd(n)][:] . Wv[n][:] + bv[n] ----
__global__ __launch_bounds__(256) void ctxv_k(
    const float* __restrict__ u, const float* __restrict__ Wv,
    const float* __restrict__ bv, float* __restrict__ ctx)
{
  const int b = blockIdx.x, tid = threadIdx.x;
  __shared__ __align__(16) float ul[8*512];
  for (int i = tid; i < 4096; i += 256) ul[i] = u[(long)b*4096 + i];
  __syncthreads();
#pragma unroll
  for (int v = 0; v < 2; ++v) {
    int n = tid + v*256;
    int hd = n >> 6;
    const float4* wr = (const float4*)(Wv + (long)n*512);
    const float4* uv = (const float4*)&ul[hd*512];
    float acc = 0.f;
    for (int k4 = 0; k4 < 128; ++k4) {
      float4 w = wr[k4], x = uv[k4];
      acc += w.x*x.x + w.y*x.y + w.z*x.z + w.w*x.w;
    }
    ctx[b*512 + n] = acc + bv[n];
  }
}

// ---- output head ----
__global__ __launch_bounds__(256) void head_k(
    const float* __restrict__ ctx,
    const float* __restrict__ Wo, const float* __restrict__ bo,
    const float* __restrict__ seq,
    const float* __restrict__ att_g, const float* __restrict__ att_b,
    const float* __restrict__ on_g, const float* __restrict__ on_b,
    const float* __restrict__ Wp1, const float* __restrict__ bp1,
    const float* __restrict__ Wp2, const float* __restrict__ bp2,
    float* __restrict__ out)
{
  const int b = blockIdx.x, tid = threadIdx.x;
  __shared__ __align__(16) float cs[512];
  __shared__ __align__(16) float buf[512];
  __shared__ float sm[4];
  cs[tid]       = ctx[b*512 + tid];
  cs[tid + 256] = ctx[b*512 + tid + 256];
  __syncthreads();

  const float* srow = seq + ((long)b*512 + 511) * 512;
  float o[2];
#pragma unroll
  for (int v = 0; v < 2; ++v) {
    int j = tid + v*256;
    const float4* w4 = (const float4*)(Wo + (long)j * 512);
    const float4* c4 = (const float4*)cs;
    float acc = 0.f;
    for (int kx = 0; kx < 128; ++kx) {
      float4 w = w4[kx], c = c4[kx];
      acc += w.x*c.x + w.y*c.y + w.z*c.z + w.w*c.w;
    }
    o[v] = acc + bo[j] + srow[j];
  }
  float s1 = o[0] + o[1], s2 = o[0]*o[0] + o[1]*o[1];
  s1 = blk_sum(s1, sm, tid); s2 = blk_sum(s2, sm, tid);
  float m1 = s1 * (1.f/512.f);
  float r1 = rsqrtf(s2 * (1.f/512.f) - m1*m1 + EPS_LN);
  float a[2];
#pragma unroll
  for (int v = 0; v < 2; ++v) {
    int j = tid + v*256;
    a[v] = (o[v] - m1) * r1 * att_g[j] + att_b[j];
  }
  s1 = a[0] + a[1]; s2 = a[0]*a[0] + a[1]*a[1];
  s1 = blk_sum(s1, sm, tid); s2 = blk_sum(s2, sm, tid);
  float m2 = s1 * (1.f/512.f);
  float r2 = rsqrtf(s2 * (1.f/512.f) - m2*m2 + EPS_LN);
#pragma unroll
  for (int v = 0; v < 2; ++v) {
    int j = tid + v*256;
    buf[j] = (a[v] - m2) * r2 * on_g[j] + on_b[j];
  }
  __syncthreads();

  const float4* w1 = (const float4*)(Wp1 + (long)tid * 512);
  const float4* b4 = (const float4*)buf;
  float acc = 0.f;
  for (int kx = 0; kx < 128; ++kx) {
    float4 w = w1[kx], c = b4[kx];
    acc += w.x*c.x + w.y*c.y + w.z*c.z + w.w*c.w;
  }
  float mid = fmaxf(acc + bp1[tid], 0.f);
  float contrib = mid * Wp2[tid];
  float tot = blk_sum(contrib, sm, tid);
  if (tid == 0) out[b] = tot + bp2[0];
}

extern "C" void kernel_launch(void* const* d_in, const int* in_sizes, int n_in,
                              void* d_out, int out_size, void* d_ws, size_t ws_size,
                              hipStream_t stream)
{
  const float* x     = (const float*)d_in[0];
  const float* Wi    = (const float*)d_in[1];
  const float* bi    = (const float*)d_in[2];
  const float* Wh    = (const float*)d_in[3];
  const float* bh    = (const float*)d_in[4];
  const float* g_in  = (const float*)d_in[5];
  const float* b_in  = (const float*)d_in[6];
  const float* g_hid = (const float*)d_in[7];
  const float* b_hid = (const float*)d_in[8];
  const float* g_cell= (const float*)d_in[9];
  const float* b_cell= (const float*)d_in[10];
  const float* hwWt  = (const float*)d_in[11];
  const float* hwbt  = (const float*)d_in[12];
  const float* hwWc  = (const float*)d_in[13];
  const float* hwbc  = (const float*)d_in[14];
  const float* hwWh  = (const float*)d_in[15];
  const float* hwbh  = (const float*)d_in[16];
  const float* Wq    = (const float*)d_in[17];
  const float* bq    = (const float*)d_in[18];
  const float* Wk    = (const float*)d_in[19];
  const float* bk    = (const float*)d_in[20];
  const float* Wv    = (const float*)d_in[21];
  const float* bv    = (const float*)d_in[22];
  const float* Wo    = (const float*)d_in[23];
  const float* bo    = (const float*)d_in[24];
  const float* att_g = (const float*)d_in[25];
  const float* att_b = (const float*)d_in[26];
  const float* on_g  = (const float*)d_in[27];
  const float* on_b  = (const float*)d_in[28];
  const float* Wp1   = (const float*)d_in[29];
  const float* bp1   = (const float*)d_in[30];
  const float* Wp2   = (const float*)d_in[31];
  const float* bp2   = (const float*)d_in[32];
  float* out = (float*)d_out;

  // ---- workspace layout (floats); never touches d_in ----
  const long SEQF = (long)Bn * Sn * Hn;      // 16,777,216
  const long WHPF = 2L * 256 * G4n;          // 1,048,576 (uint32 slots)
  const long ZBF  = 2L * 32 * 2048 * 2;      // 262,144 uint64 = 524,288 floats
  const long wsF  = (long)(ws_size / 4);

  float* ws   = (float*)d_ws;
  float* seq  = ws;                  // [B,S,H]
  float* hseq = seq  + SEQF;         // [B,S,H]
  uint32* WhP = (uint32*)(hseq + SEQF);  // [2][256][2048] packed f16 pairs
  uint64* zbuf = (uint64*)(hseq + SEQF + WHPF);  // [2][32][2048][2] tagged z words
  float* hst  = hseq + SEQF + WHPF + 2*ZBF;  // [64][512]
  float* cst  = hst  + 32768L;
  float* qlst = cst  + 32768L;       // [64][512]
  float* ctx  = qlst + 32768L;       // [64][512]
  float* qkh  = ctx  + 32768L;       // [64][8][512]
  float* qbk  = qkh  + 262144L;      // [64][8] (pad to 1024)
  float* uat  = qbk  + 1024L;        // [64][8][512]
  float* ipc  = uat  + 262144L;      // [TCH*64][2048]
  const long baseF = (ipc - ws);

  int TCH = 512;
  while (TCH > 16 && baseF + (long)TCH * 64 * 2048 > wsF) TCH >>= 1;

  wh_pack_k<<<dim3(16, 64, 2), 256, 0, stream>>>(Wh, WhP);
  init_zbuf_k<<<512, 512, 0, stream>>>(zbuf);

  const int NCH = Sn / TCH;
  const int MROWS = TCH * 64;
  const int NMCH = (Bn * Sn) / MROWS;

  for (int l = 0; l < 2; ++l) {
    const float* seqin = (l == 0) ? x : seq;
    init_hc_k<<<128, 256, 0, stream>>>(hst, cst);
    for (int c = 0; c < NCH; ++c) {
      const int s0 = c * TCH;
      gemm_ip_k<<<dim3(16, TCH/2), 256, 0, stream>>>(seqin, Wi + (long)l*G4n*Hn, bi + l*G4n, ipc, s0);
      ln_rows_k<<<TCH*64, 256, 0, stream>>>(ipc, g_in + l*G4n, b_in + l*G4n);
      lstm_seqz_k<<<256, 512, 0, stream>>>(WhP + (long)l*256*G4n, bh + l*G4n, ipc,
          g_hid + l*G4n, b_hid + l*G4n, g_cell + l*Hn, b_cell + l*Hn,
          hst, cst, hseq, zbuf, s0, TCH, l*Sn + s0 + 1);
    }
    // highway, chunked over M; T buffers live in the (dead) ipc region
    float* T1 = ipc;
    float* T2 = ipc + (long)MROWS * 512;
    float* T3 = ipc + 2L * MROWS * 512;
    for (int mc = 0; mc < NMCH; ++mc) {
      const long m0 = (long)mc * MROWS;
      gemm_bias_k<<<dim3(4, MROWS/128), 256, 0, stream>>>(hseq + m0*512, 512, hwWt + (long)l*Hn*Hn, hwbt + l*Hn, T1, 512, 512);
      gemm_bias_k<<<dim3(4, MROWS/128), 256, 0, stream>>>(hseq + m0*512, 512, hwWc + (long)l*Hn*Hn, hwbc + l*Hn, T2, 512, 512);
      gemm_bias_k<<<dim3(4, MROWS/128), 256, 0, stream>>>(hseq + m0*512, 512, hwWh + (long)l*Hn*Hn, hwbh + l*Hn, T3, 512, 512);
      highway_ew_k<<<(MROWS*512)/1024, 256, 0, stream>>>(T1, T2, T3, hseq + m0*512, seq + m0*512, (l == 0) ? 0 : 1);
    }
  }

  // attention on last query row, K/V never materialized
  gemm_m64_k<<<dim3(8, 1), 256, 0, stream>>>(seq + 511L*512, 512L*512, Wq, bq, qlst, 512, 512);
  qkh_k<<<dim3(8, 4), 256, 0, stream>>>(qlst, Wk, bk, qkh, qbk);
  attn2_k<<<dim3(64, 8), 256, 0, stream>>>(seq, qkh, qbk, uat);
  ctxv_k<<<64, 256, 0, stream>>>(uat, Wv, bv, ctx);
  head_k<<<64, 256, 0, stream>>>(ctx, Wo, bo, seq, att_g, att_b, on_g, on_b, Wp1, bp1, Wp2, bp2, out);
}

// Round 8
// 9253.822 us; speedup vs baseline: 1.0961x; 1.0961x over previous
//
#include <hip/hip_runtime.h>

#define EPS_LN 1e-5f

static constexpr int Bn  = 64;
static constexpr int Sn  = 512;
static constexpr int Hn  = 512;
static constexpr int G4n = 2048;

typedef unsigned int uint32;
typedef unsigned long long uint64;
typedef _Float16 h2v __attribute__((ext_vector_type(2)));

__device__ __forceinline__ float sigf(float x)     { return 1.0f / (1.0f + __expf(-x)); }
__device__ __forceinline__ float tanhfast(float x) { return 1.0f - 2.0f / (1.0f + __expf(2.0f * x)); }

// dot2: acc += w.lo*h.lo + w.hi*h.hi   (f16 inputs, fp32 accumulate)
__device__ __forceinline__ float dot2h(uint32 w, uint32 h, float acc) {
#if defined(__has_builtin)
#if __has_builtin(__builtin_amdgcn_fdot2)
  return __builtin_amdgcn_fdot2(__builtin_bit_cast(h2v, w), __builtin_bit_cast(h2v, h), acc, false);
#define DOT2_DONE 1
#endif
#endif
#ifndef DOT2_DONE
  h2v wv = __builtin_bit_cast(h2v, w);
  h2v hv = __builtin_bit_cast(h2v, h);
  return acc + (float)wv.x * (float)hv.x + (float)wv.y * (float)hv.y;
#endif
}
__device__ __forceinline__ uint32 packh2(float a, float b) {
  h2v v; v.x = (_Float16)a; v.y = (_Float16)b;
  return __builtin_bit_cast(uint32, v);
}

// ---- block reductions (256-thread kernels) ----
__device__ __forceinline__ float blk_sum(float v, float* sm, int tid) {
#pragma unroll
  for (int o = 32; o; o >>= 1) v += __shfl_down(v, o, 64);
  __syncthreads();
  if ((tid & 63) == 0) sm[tid >> 6] = v;
  __syncthreads();
  return sm[0] + sm[1] + sm[2] + sm[3];
}
__device__ __forceinline__ float blk_max(float v, float* sm, int tid) {
#pragma unroll
  for (int o = 32; o; o >>= 1) v = fmaxf(v, __shfl_down(v, o, 64));
  __syncthreads();
  if ((tid & 63) == 0) sm[tid >> 6] = v;
  __syncthreads();
  return fmaxf(fmaxf(sm[0], sm[1]), fmaxf(sm[2], sm[3]));
}

// ---- fused 4-value reduction across a 512-thread (8-wave) block ----
__device__ __forceinline__ void blk_sum4_w8(float& a, float& b, float& c, float& d,
                                            float* sm, int tid) {
#pragma unroll
  for (int o = 32; o; o >>= 1) {
    a += __shfl_down(a, o, 64);
    b += __shfl_down(b, o, 64);
    c += __shfl_down(c, o, 64);
    d += __shfl_down(d, o, 64);
  }
  __syncthreads();
  if ((tid & 63) == 0) {
    float4 v; v.x = a; v.y = b; v.z = c; v.w = d;
    *(float4*)&sm[(tid >> 6) * 4] = v;
  }
  __syncthreads();
  float ra = 0.f, rb = 0.f, rc = 0.f, rd = 0.f;
#pragma unroll
  for (int w = 0; w < 8; ++w) {
    float4 v = *(const float4*)&sm[w * 4];
    ra += v.x; rb += v.y; rc += v.z; rd += v.w;
  }
  a = ra; b = rb; c = rc; d = rd;
}

// ---- Wh pack: WhP[l][kp][n] = half2(Wh[l][n][2kp], Wh[l][n][2kp+1]) ----
__global__ __launch_bounds__(256) void wh_pack_k(
    const float* __restrict__ Wh, uint32* __restrict__ WhP)
{
  __shared__ float tile[32][33];
  const int l = blockIdx.z;
  const int k0 = blockIdx.x * 32;
  const int n0 = blockIdx.y * 32;
  const int row = threadIdx.x >> 5, col = threadIdx.x & 31;
  const float* src = Wh + (long)l * G4n * Hn;
  uint32* dst = WhP + (long)l * 256 * G4n;
#pragma unroll
  for (int rr = 0; rr < 4; ++rr) {
    int nn = row + rr * 8;
    tile[nn][col] = src[(long)(n0 + nn) * Hn + k0 + col];
  }
  __syncthreads();
#pragma unroll
  for (int rr = 0; rr < 2; ++rr) {
    int kpl = row + rr * 8;                     // 0..15
    int kp = (k0 >> 1) + kpl;
    dst[(long)kp * G4n + n0 + col] = packh2(tile[col][2*kpl], tile[col][2*kpl+1]);
  }
}

__global__ void init_zbuf_k(uint64* zbuf)
{
  long i = (long)blockIdx.x * 512 + threadIdx.x;
  zbuf[i] = 0ULL;
}

// ---- ip-chunk GEMM (f16-packed fdot2, K=16 slabs -- round-6 verified), ----
// time-major output: row r = t_local*64 + b
__global__ __launch_bounds__(256) void gemm_ip_k(
    const float* __restrict__ A,       // [B,S,H]
    const float* __restrict__ Bw,      // [2048,512]
    const float* __restrict__ bias,
    float* __restrict__ C,             // [TCH*64, 2048]
    int s0)
{
  __shared__ __align__(16) uint32 Ah[8][128];
  __shared__ __align__(16) uint32 Bh[8][128];
  const int tid = threadIdx.x;
  const long m0 = (long)blockIdx.y * 128;
  const long n0 = (long)blockIdx.x * 128;
  const int tx = tid & 15, ty = tid >> 4;
  const int lrow = tid >> 1;
  const int lc0  = (tid & 1) * 8;
  const int kb   = (tid & 1) * 4;
  float acc[8][8];
#pragma unroll
  for (int i = 0; i < 8; ++i)
#pragma unroll
    for (int j = 0; j < 8; ++j) acc[i][j] = 0.f;

  const long r  = m0 + lrow;
  const long b  = r & 63;
  const long sl = r >> 6;
  const float* Arow = A + (b * Sn + s0 + sl) * Hn;
  const float* Brow = Bw + (n0 + lrow) * 512L;

  for (int k0 = 0; k0 < 512; k0 += 16) {
    float4 a0 = *(const float4*)(Arow + k0 + lc0);
    float4 a1 = *(const float4*)(Arow + k0 + lc0 + 4);
    float4 b0 = *(const float4*)(Brow + k0 + lc0);
    float4 b1 = *(const float4*)(Brow + k0 + lc0 + 4);
    __syncthreads();
    Ah[kb+0][lrow] = packh2(a0.x, a0.y);
    Ah[kb+1][lrow] = packh2(a0.z, a0.w);
    Ah[kb+2][lrow] = packh2(a1.x, a1.y);
    Ah[kb+3][lrow] = packh2(a1.z, a1.w);
    Bh[kb+0][lrow] = packh2(b0.x, b0.y);
    Bh[kb+1][lrow] = packh2(b0.z, b0.w);
    Bh[kb+2][lrow] = packh2(b1.x, b1.y);
    Bh[kb+3][lrow] = packh2(b1.z, b1.w);
    __syncthreads();
#pragma unroll
    for (int kp = 0; kp < 8; ++kp) {
      uint32 a8[8], b8[8];
      *(uint4*)&a8[0] = *(const uint4*)&Ah[kp][ty*8];
      *(uint4*)&a8[4] = *(const uint4*)&Ah[kp][ty*8+4];
      *(uint4*)&b8[0] = *(const uint4*)&Bh[kp][tx*8];
      *(uint4*)&b8[4] = *(const uint4*)&Bh[kp][tx*8+4];
#pragma unroll
      for (int i = 0; i < 8; ++i)
#pragma unroll
        for (int j = 0; j < 8; ++j) acc[i][j] = dot2h(a8[i], b8[j], acc[i][j]);
    }
  }
#pragma unroll
  for (int i = 0; i < 8; ++i) {
    long m = m0 + ty*8 + i;
    float* crow = C + m * 2048L + n0 + tx*8;
    const float* br = bias + n0 + tx*8;
    float4 o0, o1;
    o0.x = acc[i][0]+br[0]; o0.y = acc[i][1]+br[1]; o0.z = acc[i][2]+br[2]; o0.w = acc[i][3]+br[3];
    o1.x = acc[i][4]+br[4]; o1.y = acc[i][5]+br[5]; o1.z = acc[i][6]+br[6]; o1.w = acc[i][7]+br[7];
    *(float4*)crow = o0; *(float4*)(crow+4) = o1;
  }
}

// ---- fused highway: ONE kernel computes all 3 projections of the same A rows
// (A staged into LDS once, not 3x) and applies the elementwise combine in the
// epilogue -- eliminates the 3 T-buffers and highway_ew entirely.
// Tile: 128 rows x 64 cols; 256 threads; per thread 4 rows x 8 cols x 3 mats.
// out[m][n] = sigf(t1)*relu(t3) + sigf(t2)*A[m][n] (+ seq[m][n] if skip)
__global__ __launch_bounds__(256) void hw_fused_k(
    const float* __restrict__ A,       // hseq + m0*512 (lda = 512)
    const float* __restrict__ Wt, const float* __restrict__ bt,
    const float* __restrict__ Wc, const float* __restrict__ bc,
    const float* __restrict__ Wh3, const float* __restrict__ bh3,
    float* __restrict__ seqout,        // seq + m0*512
    int skip)
{
  __shared__ __align__(16) uint32 Ah[8][128];     // [k-pair][row]
  __shared__ __align__(16) uint32 Bh[3][8][68];   // [mat][k-pair][col] pad 68: staging conflict-free
  const int tid = threadIdx.x;
  const long m0 = (long)blockIdx.y * 128;
  const int n0 = blockIdx.x * 64;
  const int tx = tid & 7;            // col-group (8 cols each)
  const int ty = tid >> 3;           // row-group (4 rows each)
  const int lrow = tid >> 1;         // A staging row
  const int lc0  = (tid & 1) * 8;
  const int kbA  = (tid & 1) * 4;
  const int brow = tid >> 2;         // B staging col (0..63)
  const int bk0  = (tid & 3) * 4;
  const int kbB  = (tid & 3) * 2;

  float accT[4][8], accC[4][8], accH[4][8];
#pragma unroll
  for (int i = 0; i < 4; ++i)
#pragma unroll
    for (int j = 0; j < 8; ++j) { accT[i][j] = 0.f; accC[i][j] = 0.f; accH[i][j] = 0.f; }

  const float* Arow = A + (m0 + lrow) * 512;
  const long boff = (long)(n0 + brow) * 512 + bk0;

  for (int k0 = 0; k0 < 512; k0 += 16) {
    float4 a0 = *(const float4*)(Arow + k0 + lc0);
    float4 a1 = *(const float4*)(Arow + k0 + lc0 + 4);
    float4 wt4 = *(const float4*)(Wt  + boff + k0);
    float4 wc4 = *(const float4*)(Wc  + boff + k0);
    float4 wh4 = *(const float4*)(Wh3 + boff + k0);
    __syncthreads();
    Ah[kbA+0][lrow] = packh2(a0.x, a0.y);
    Ah[kbA+1][lrow] = packh2(a0.z, a0.w);
    Ah[kbA+2][lrow] = packh2(a1.x, a1.y);
    Ah[kbA+3][lrow] = packh2(a1.z, a1.w);
    Bh[0][kbB+0][brow] = packh2(wt4.x, wt4.y);
    Bh[0][kbB+1][brow] = packh2(wt4.z, wt4.w);
    Bh[1][kbB+0][brow] = packh2(wc4.x, wc4.y);
    Bh[1][kbB+1][brow] = packh2(wc4.z, wc4.w);
    Bh[2][kbB+0][brow] = packh2(wh4.x, wh4.y);
    Bh[2][kbB+1][brow] = packh2(wh4.z, wh4.w);
    __syncthreads();
#pragma unroll
    for (int kp = 0; kp < 8; ++kp) {
      uint32 a4[4];
      *(uint4*)&a4[0] = *(const uint4*)&Ah[kp][ty*4];
      {
        uint32 b8[8];
        *(uint4*)&b8[0] = *(const uint4*)&Bh[0][kp][tx*8];
        *(uint4*)&b8[4] = *(const uint4*)&Bh[0][kp][tx*8+4];
#pragma unroll
        for (int i = 0; i < 4; ++i)
#pragma unroll
          for (int j = 0; j < 8; ++j) accT[i][j] = dot2h(a4[i], b8[j], accT[i][j]);
      }
      {
        uint32 b8[8];
        *(uint4*)&b8[0] = *(const uint4*)&Bh[1][kp][tx*8];
        *(uint4*)&b8[4] = *(const uint4*)&Bh[1][kp][tx*8+4];
#pragma unroll
        for (int i = 0; i < 4; ++i)
#pragma unroll
          for (int j = 0; j < 8; ++j) accC[i][j] = dot2h(a4[i], b8[j], accC[i][j]);
      }
      {
        uint32 b8[8];
        *(uint4*)&b8[0] = *(const uint4*)&Bh[2][kp][tx*8];
        *(uint4*)&b8[4] = *(const uint4*)&Bh[2][kp][tx*8+4];
#pragma unroll
        for (int i = 0; i < 4; ++i)
#pragma unroll
          for (int j = 0; j < 8; ++j) accH[i][j] = dot2h(a4[i], b8[j], accH[i][j]);
      }
    }
  }

  // epilogue: combine + write seq
  float btr[8], bcr[8], bhr[8];
#pragma unroll
  for (int j = 0; j < 8; ++j) {
    btr[j] = bt[n0 + tx*8 + j];
    bcr[j] = bc[n0 + tx*8 + j];
    bhr[j] = bh3[n0 + tx*8 + j];
  }
#pragma unroll
  for (int i = 0; i < 4; ++i) {
    const long m = m0 + ty*4 + i;
    const float* hrow = A + m * 512 + n0 + tx*8;
    float* srow = seqout + m * 512 + n0 + tx*8;
    float4 h0 = *(const float4*)hrow;
    float4 h1 = *(const float4*)(hrow + 4);
    float hv[8] = {h0.x,h0.y,h0.z,h0.w,h1.x,h1.y,h1.z,h1.w};
    float sv[8] = {0,0,0,0,0,0,0,0};
    if (skip) {
      float4 s0 = *(const float4*)srow;
      float4 s1 = *(const float4*)(srow + 4);
      sv[0]=s0.x; sv[1]=s0.y; sv[2]=s0.z; sv[3]=s0.w;
      sv[4]=s1.x; sv[5]=s1.y; sv[6]=s1.z; sv[7]=s1.w;
    }
    float o[8];
#pragma unroll
    for (int j = 0; j < 8; ++j) {
      const float t1 = accT[i][j] + btr[j];
      const float t2 = accC[i][j] + bcr[j];
      const float t3 = accH[i][j] + bhr[j];
      o[j] = sigf(t1) * fmaxf(t3, 0.f) + sigf(t2) * hv[j] + sv[j];
    }
    float4 o0, o1;
    o0.x=o[0]; o0.y=o[1]; o0.z=o[2]; o0.w=o[3];
    o1.x=o[4]; o1.y=o[5]; o1.z=o[6]; o1.w=o[7];
    *(float4*)srow = o0; *(float4*)(srow + 4) = o1;
  }
}

// ---- M=64 GEMM (used for q projection) ----
__global__ __launch_bounds__(256) void gemm_m64_k(
    const float* __restrict__ A, long lda,
    const float* __restrict__ Bw,
    const float* __restrict__ bias,
    float* __restrict__ P,
    int N, int K)
{
  __shared__ float As[64][64];
  __shared__ float Bs[64][64];
  const int tid = threadIdx.x;
  const int n0 = blockIdx.x * 64;
  const int kc = blockIdx.y;
  const int Kc = K / gridDim.y;
  const int tx = tid & 15, ty = tid >> 4;
  const int row = tid >> 2, q = tid & 3;
  float acc[4][4];
#pragma unroll
  for (int i = 0; i < 4; ++i)
#pragma unroll
    for (int j = 0; j < 4; ++j) acc[i][j] = 0.f;

  for (int k0 = kc * Kc; k0 < kc * Kc + Kc; k0 += 64) {
    float4 a[4], b[4];
#pragma unroll
    for (int c = 0; c < 4; ++c) {
      a[c] = *(const float4*)(A  + (long)row * lda       + k0 + q*16 + c*4);
      b[c] = *(const float4*)(Bw + (long)(n0 + row) * K  + k0 + q*16 + c*4);
    }
    __syncthreads();
#pragma unroll
    for (int c = 0; c < 4; ++c) {
      int kb = q*16 + c*4;
      As[kb+0][row]=a[c].x; As[kb+1][row]=a[c].y; As[kb+2][row]=a[c].z; As[kb+3][row]=a[c].w;
      Bs[kb+0][row]=b[c].x; Bs[kb+1][row]=b[c].y; Bs[kb+2][row]=b[c].z; Bs[kb+3][row]=b[c].w;
    }
    __syncthreads();
#pragma unroll
    for (int kk = 0; kk < 64; ++kk) {
      float4 av = *(const float4*)&As[kk][ty*4];
      float4 bv = *(const float4*)&Bs[kk][tx*4];
      float am[4] = {av.x, av.y, av.z, av.w};
      float bm[4] = {bv.x, bv.y, bv.z, bv.w};
#pragma unroll
      for (int i = 0; i < 4; ++i)
#pragma unroll
        for (int j = 0; j < 4; ++j) acc[i][j] += am[i] * bm[j];
    }
  }
#pragma unroll
  for (int i = 0; i < 4; ++i) {
    int m = ty*4 + i;
    float* pr = P + ((long)kc * 64 + m) * N + n0 + tx*4;
#pragma unroll
    for (int j = 0; j < 4; ++j) {
      float bb = bias ? bias[n0 + tx*4 + j] : 0.f;
      pr[j] = acc[i][j] + bb;
    }
  }
}

// ---- persistent LSTM recurrence: n-split + tagged-word single-round exchange ----
// (verified kernel: 867us/128 steps, 0 bank conflicts. Publish pattern
//  myword=kq*512+tid gives contiguous full-line wave stores -- DO NOT change it;
//  the strided variant pushes the exchange out of L2, 5.5x slower. Packed-h LDS
//  split lo/hi at +132 words keeps the wave's two broadcast reads on disjoint
//  bank quads. BYTE-IDENTICAL to rounds 5-7.)
__global__ __launch_bounds__(512, 2) void lstm_seqz_k(
    const uint32* __restrict__ WhP,   // [256 kp][2048 n] this layer (f16 pairs)
    const float* __restrict__ bh,
    const float* __restrict__ ipc,    // [TCH*64][2048] time-major LN'd input proj
    const float* __restrict__ g_hid, const float* __restrict__ b_hid,
    const float* __restrict__ g_cell, const float* __restrict__ b_cell,
    float* __restrict__ hst, float* __restrict__ cst,  // [64][512]
    float* __restrict__ hseq,         // [B,S,H]
    uint64* __restrict__ zbuf,        // [2 parity][32 g][2048 row][2 b] tagged words
    int t0, int nsteps, int gbase)    // gbase >= 1, monotonic over the whole run
{
  const int blk = blockIdx.x;
  const int g   = blk & 31;
  const int kq  = blk >> 5;
  const int tid = threadIdx.x;
  const int b0  = g*2, b1 = g*2 + 1;
  const int r   = tid >> 1;          // row within our 256-row slice
  const int kh  = tid & 1;           // k-half (0: k<256, 1: k>=256)
  // packed h pairs: lo half [0..127], hi half at +132 (bank-quad disjoint from lo)
  __shared__ __align__(16) uint32 hp0[264];
  __shared__ __align__(16) uint32 hp1[264];
  __shared__ float sm[32];

  // register-resident weights: rows kq*256+r, k-pairs kh*128 + [0,128)
  uint4 wreg[32];
  {
    const uint32* base = WhP + (long)(kh * 128) * 2048 + (kq*256 + r);
#pragma unroll
    for (int i = 0; i < 32; ++i) {
      wreg[i].x = base[(long)(4*i + 0) * 2048];
      wreg[i].y = base[(long)(4*i + 1) * 2048];
      wreg[i].z = base[(long)(4*i + 2) * 2048];
      wreg[i].w = base[(long)(4*i + 3) * 2048];
    }
  }

  // per-unit params/state: thread owns unit tid (both batches)
  float bhr[4], ghr[4], bhir[4];
#pragma unroll
  for (int q = 0; q < 4; ++q) {
    bhr[q]  = bh[q*512 + tid];
    ghr[q]  = g_hid[q*512 + tid];
    bhir[q] = b_hid[q*512 + tid];
  }
  const float gcv = g_cell[tid];
  const float bcv = b_cell[tid];
  float c0 = cst[b0*512 + tid];
  float c1 = cst[b1*512 + tid];
  float h0 = hst[b0*512 + tid];
  float h1 = hst[b1*512 + tid];

  // initial full-h pack into LDS (lo at j, hi at j+4 for j>=128)
  {
    const float p0 = __shfl_xor(h0, 1, 64);
    const float p1 = __shfl_xor(h1, 1, 64);
    if (!(tid & 1)) {
      const int j = tid >> 1;
      const int jj = (j < 128) ? j : j + 4;
      hp0[jj] = packh2(h0, p0);
      hp1[jj] = packh2(h1, p1);
    }
  }
  __syncthreads();

  const long myword = (long)(kq*256 + r) * 2 + kh;   // = kq*512 + tid (contiguous)
  const uint32* hb0 = hp0 + kh * 132;
  const uint32* hb1 = hp1 + kh * 132;

  for (int ts = 0; ts < nsteps; ++ts) {
    const int gstep = gbase + ts;
    const uint32 tagw = (uint32)gstep;
    uint64* zp = zbuf + (long)(gstep & 1) * 131072 + (long)g * 4096;

    // prefetch ip for our unit (regular cached loads; hide under GEMV)
    const float* iprow0 = ipc + ((long)ts * 64 + b0) * 2048 + tid;
    const float* iprow1 = ipc + ((long)ts * 64 + b1) * 2048 + tid;
    float ip0[4], ip1[4];
#pragma unroll
    for (int q = 0; q < 4; ++q) { ip0[q] = iprow0[q*512]; ip1[q] = iprow1[q*512]; }

    // GEMV: full-k half for row kq*256+r, both batches (h via LDS broadcast)
    float a0 = 0.f, a1 = 0.f;
#pragma unroll
    for (int i = 0; i < 32; ++i) {
      const uint4 w  = wreg[i];
      const uint4 hv0 = *(const uint4*)&hb0[4*i];
      const uint4 hv1 = *(const uint4*)&hb1[4*i];
      a0 = dot2h(w.x, hv0.x, a0); a0 = dot2h(w.y, hv0.y, a0);
      a0 = dot2h(w.z, hv0.z, a0); a0 = dot2h(w.w, hv0.w, a0);
      a1 = dot2h(w.x, hv1.x, a1); a1 = dot2h(w.y, hv1.y, a1);
      a1 = dot2h(w.z, hv1.z, a1); a1 = dot2h(w.w, hv1.w, a1);
    }
    // combine k-halves within the lane pair
    a0 += __shfl_xor(a0, 1, 64);
    a1 += __shfl_xor(a1, 1, 64);

    // publish one tagged word (fire-and-forget; tag rides with payload)
    {
      const float zval = kh ? a1 : a0;
      const uint64 w = ((uint64)tagw << 32) | (uint64)__builtin_bit_cast(uint32, zval);
      __hip_atomic_store(zp + myword, w, __ATOMIC_RELAXED, __HIP_MEMORY_SCOPE_AGENT);
    }

    // gather the 8 tagged words for unit tid: rows {tid,512+tid,1024+tid,1536+tid} x {b0,b1}
    float z0[4], z1[4];
    {
      uint64 v0[4], v1[4];
      int pend = 0xff;
      while (pend) {
#pragma unroll
        for (int q = 0; q < 4; ++q) {
          const long base = (long)(q*512 + tid) * 2;
          if (pend & (1 << q)) {
            uint64 w = __hip_atomic_load(zp + base, __ATOMIC_RELAXED, __HIP_MEMORY_SCOPE_AGENT);
            if ((uint32)(w >> 32) == tagw) { v0[q] = w; pend &= ~(1 << q); }
          }
          if (pend & (16 << q)) {
            uint64 w = __hip_atomic_load(zp + base + 1, __ATOMIC_RELAXED, __HIP_MEMORY_SCOPE_AGENT);
            if ((uint32)(w >> 32) == tagw) { v1[q] = w; pend &= ~(16 << q); }
          }
        }
        if (pend) __builtin_amdgcn_s_sleep(2);
      }
#pragma unroll
      for (int q = 0; q < 4; ++q) {
        z0[q] = __builtin_bit_cast(float, (uint32)v0[q]) + bhr[q];
        z1[q] = __builtin_bit_cast(float, (uint32)v1[q]) + bhr[q];
      }
    }

    // LN1 over 2048, both batches in one reduction pass
    float s10 = z0[0]+z0[1]+z0[2]+z0[3];
    float s20 = z0[0]*z0[0] + z0[1]*z0[1] + z0[2]*z0[2] + z0[3]*z0[3];
    float s11 = z1[0]+z1[1]+z1[2]+z1[3];
    float s21 = z1[0]*z1[0] + z1[1]*z1[1] + z1[2]*z1[2] + z1[3]*z1[3];
    blk_sum4_w8(s10, s20, s11, s21, sm, tid);
    const float m0 = s10 * (1.f/2048.f);
    const float r0 = rsqrtf(s20 * (1.f/2048.f) - m0*m0 + EPS_LN);
    const float m1 = s11 * (1.f/2048.f);
    const float r1 = rsqrtf(s21 * (1.f/2048.f) - m1*m1 + EPS_LN);

    const float gi0 = ip0[0] + (z0[0] - m0) * r0 * ghr[0] + bhir[0];
    const float gf0 = ip0[1] + (z0[1] - m0) * r0 * ghr[1] + bhir[1];
    const float gg0 = ip0[2] + (z0[2] - m0) * r0 * ghr[2] + bhir[2];
    const float go0 = ip0[3] + (z0[3] - m0) * r0 * ghr[3] + bhir[3];
    const float gi1 = ip1[0] + (z1[0] - m1) * r1 * ghr[0] + bhir[0];
    const float gf1 = ip1[1] + (z1[1] - m1) * r1 * ghr[1] + bhir[1];
    const float gg1 = ip1[2] + (z1[2] - m1) * r1 * ghr[2] + bhir[2];
    const float go1 = ip1[3] + (z1[3] - m1) * r1 * ghr[3] + bhir[3];

    c0 = sigf(gf0) * c0 + sigf(gi0) * tanhfast(gg0);
    c1 = sigf(gf1) * c1 + sigf(gi1) * tanhfast(gg1);

    // LN2 over 512 cells, both batches in one pass
    float t10 = c0, t20 = c0*c0, t11 = c1, t21 = c1*c1;
    blk_sum4_w8(t10, t20, t11, t21, sm, tid);
    const float n0 = t10 * (1.f/512.f);
    const float q0r = rsqrtf(t20 * (1.f/512.f) - n0*n0 + EPS_LN);
    const float n1 = t11 * (1.f/512.f);
    const float q1r = rsqrtf(t21 * (1.f/512.f) - n1*n1 + EPS_LN);
    h0 = sigf(go0) * tanhfast((c0 - n0) * q0r * gcv + bcv);
    h1 = sigf(go1) * tanhfast((c1 - n1) * q1r * gcv + bcv);

    if (kq == 0) {
      hseq[((long)b0 * Sn + t0 + ts) * Hn + tid] = h0;
      hseq[((long)b1 * Sn + t0 + ts) * Hn + tid] = h1;
    }

    // repack full h into LDS for next step (blk_sum4 already synced past GEMV reads)
    const float p0 = __shfl_xor(h0, 1, 64);
    const float p1 = __shfl_xor(h1, 1, 64);
    if (!(tid & 1)) {
      const int j = tid >> 1;
      const int jj = (j < 128) ? j : j + 4;
      hp0[jj] = packh2(h0, p0);
      hp1[jj] = packh2(h1, p1);
    }
    __syncthreads();
  }
  if (kq == 0) {
    hst[b0*512 + tid] = h0; hst[b1*512 + tid] = h1;
    cst[b0*512 + tid] = c0; cst[b1*512 + tid] = c1;
  }
}

// ---- layernorm over rows of 2048 (in-place) ----
__global__ __launch_bounds__(256) void ln_rows_k(
    float* __restrict__ X, const float* __restrict__ g, const float* __restrict__ bt)
{
  const long row = blockIdx.x;
  float* xr = X + row * 2048L;
  const int tid = threadIdx.x;
  __shared__ float sm[4];
  float4 v0 = *(float4*)(xr + tid*8);
  float4 v1 = *(float4*)(xr + tid*8 + 4);
  float s1 = v0.x+v0.y+v0.z+v0.w + v1.x+v1.y+v1.z+v1.w;
  float s2 = v0.x*v0.x+v0.y*v0.y+v0.z*v0.z+v0.w*v0.w
           + v1.x*v1.x+v1.y*v1.y+v1.z*v1.z+v1.w*v1.w;
  s1 = blk_sum(s1, sm, tid);
  s2 = blk_sum(s2, sm, tid);
  const float mean = s1 * (1.f/2048.f);
  const float rstd = rsqrtf(s2 * (1.f/2048.f) - mean*mean + EPS_LN);
  const int base = tid*8;
  float vals[8] = {v0.x,v0.y,v0.z,v0.w,v1.x,v1.y,v1.z,v1.w};
#pragma unroll
  for (int c = 0; c < 8; ++c)
    xr[base + c] = (vals[c] - mean) * rstd * g[base + c] + bt[base + c];
}

__global__ void init_hc_k(float* h, float* c)
{
  int i = blockIdx.x * 256 + threadIdx.x;
  h[i] = 0.f; c[i] = 0.f;
}

// ---- qkh[b][hd][:] = sum_{j in head} q[b, hd*64+j] * Wk[hd*64+j, :]; qbk = q.bk ----
__global__ __launch_bounds__(256) void qkh_k(
    const float* __restrict__ qlst, const float* __restrict__ Wk,
    const float* __restrict__ bk,
    float* __restrict__ qkh, float* __restrict__ qbk)
{
  const int hd = blockIdx.x, cg = blockIdx.y;
  const int b = threadIdx.x & 63, sc = threadIdx.x >> 6;
  const int col0 = cg * 128 + sc * 32;
  float qreg[64];
  const float* qp = qlst + b*512 + hd*64;
#pragma unroll
  for (int j4 = 0; j4 < 16; ++j4) {
    float4 v = *(const float4*)(qp + j4*4);
    qreg[j4*4+0]=v.x; qreg[j4*4+1]=v.y; qreg[j4*4+2]=v.z; qreg[j4*4+3]=v.w;
  }
  float acc[32];
#pragma unroll
  for (int c = 0; c < 32; ++c) acc[c] = 0.f;
  for (int j = 0; j < 64; ++j) {
    float qv = qreg[j];
    const float* wr = Wk + (long)(hd*64 + j)*512 + col0;
#pragma unroll
    for (int c4 = 0; c4 < 8; ++c4) {
      float4 w = *(const float4*)(wr + c4*4);
      acc[c4*4+0] = __builtin_fmaf(qv, w.x, acc[c4*4+0]);
      acc[c4*4+1] = __builtin_fmaf(qv, w.y, acc[c4*4+1]);
      acc[c4*4+2] = __builtin_fmaf(qv, w.z, acc[c4*4+2]);
      acc[c4*4+3] = __builtin_fmaf(qv, w.w, acc[c4*4+3]);
    }
  }
  float* op = qkh + ((long)b*8 + hd)*512 + col0;
#pragma unroll
  for (int c4 = 0; c4 < 8; ++c4) {
    float4 o;
    o.x = acc[c4*4+0]; o.y = acc[c4*4+1]; o.z = acc[c4*4+2]; o.w = acc[c4*4+3];
    *(float4*)(op + c4*4) = o;
  }
  if (cg == 0 && sc == 0) {
    float s = 0.f;
    for (int j = 0; j < 64; ++j) s += qreg[j] * bk[hd*64 + j];
    qbk[b*8 + hd] = s;
  }
}

// ---- fused last-row attention ----
__global__ __launch_bounds__(256) void attn2_k(
    const float* __restrict__ seq,   // [B,S,H]
    const float* __restrict__ qkh,   // [64][8][512]
    const float* __restrict__ qbk,   // [64][8]
    float* __restrict__ u)           // [64][8][512]
{
  const int b = blockIdx.x, hd = blockIdx.y, tid = threadIdx.x;
  __shared__ __align__(16) float qk[512];
  __shared__ float p[512];
  __shared__ float sm[4];
  qk[tid]       = qkh[((long)b*8 + hd)*512 + tid];
  qk[tid + 256] = qkh[((long)b*8 + hd)*512 + tid + 256];
  __syncthreads();
  const float bias = qbk[b*8 + hd];

  float loc[2]; float mx = -3.0e38f;
#pragma unroll
  for (int v = 0; v < 2; ++v) {
    int s = tid + v*256;
    const float4* sr = (const float4*)(seq + ((long)b*512 + s)*512);
    const float4* qv4 = (const float4*)qk;
    float d = 0.f;
    for (int k4 = 0; k4 < 128; ++k4) {
      float4 sv = sr[k4], qv = qv4[k4];
      d += sv.x*qv.x + sv.y*qv.y + sv.z*qv.z + sv.w*qv.w;
    }
    d = (d + bias) * 0.125f;
    loc[v] = d; mx = fmaxf(mx, d);
  }
  const float M = blk_max(mx, sm, tid);
  float sum = 0.f;
#pragma unroll
  for (int v = 0; v < 2; ++v) {
    int s = tid + v*256;
    float e = __expf(loc[v] - M);
    p[s] = e; sum += e;
  }
  const float SM = blk_sum(sum, sm, tid);
  const float inv = 1.f / SM;

  float u0 = 0.f, u1 = 0.f;
  for (int s = 0; s < 512; ++s) {
    float ps = p[s];
    const float* srow = seq + ((long)b*512 + s)*512;
    u0 = __builtin_fmaf(ps, srow[tid], u0);
    u1 = __builtin_fmaf(ps, srow[tid + 256], u1);
  }
  u[((long)b*8 + hd)*512 + tid]       = u0 * inv;
  u[((long)b*8 + hd)*512 + tid + 256] = u1 * inv;
}

// ---- ctx[b][n] = u[b][hd(n)][:] . Wv[n][:] + bv[n] ----
__global__ __launch_bounds__(256) void ctxv_k(
    const float* __restrict__ u, const float* __restrict__ Wv,
    const float* __restrict__ bv, float* __restrict__ ctx)
{
  const int b = blockIdx.x, tid = threadIdx.x;
  __shared__ __align__(16) float ul[8*512];
  for (int i = tid; i < 4096; i += 256) ul[i] = u[(long)b*4096 + i];
  __syncthreads();
#pragma unroll
  for (int v = 0; v < 2; ++v) {
    int n = tid + v*256;
    int hd = n >> 6;
    const float4* wr = (const float4*)(Wv + (long)n*512);
    const float4* uv = (const float4*)&ul[hd*512];
    float acc = 0.f;
    for (int k4 = 0; k4 < 128; ++k4) {
      float4 w = wr[k4], x = uv[k4];
      acc += w.x*x.x + w.y*x.y + w.z*x.z + w.w*x.w;
    }
    ctx[b*512 + n] = acc + bv[n];
  }
}

// ---- output head ----
__global__ __launch_bounds__(256) void head_k(
    const float* __restrict__ ctx,
    const float* __restrict__ Wo, const float* __restrict__ bo,
    const float* __restrict__ seq,
    const float* __restrict__ att_g, const float* __restrict__ att_b,
    const float* __restrict__ on_g, const float* __restrict__ on_b,
    const float* __restrict__ Wp1, const float* __restrict__ bp1,
    const float* __restrict__ Wp2, const float* __restrict__ bp2,
    float* __restrict__ out)
{
  const int b = blockIdx.x, tid = threadIdx.x;
  __shared__ __align__(16) float cs[512];
  __shared__ __align__(16) float buf[512];
  __shared__ float sm[4];
  cs[tid]       = ctx[b*512 + tid];
  cs[tid + 256] = ctx[b*512 + tid + 256];
  __syncthreads();

  const float* srow = seq + ((long)b*512 + 511) * 512;
  float o[2];
#pragma unroll
  for (int v = 0; v < 2; ++v) {
    int j = tid + v*256;
    const float4* w4 = (const float4*)(Wo + (long)j * 512);
    const float4* c4 = (const float4*)cs;
    float acc = 0.f;
    for (int kx = 0; kx < 128; ++kx) {
      float4 w = w4[kx], c = c4[kx];
      acc += w.x*c.x + w.y*c.y + w.z*c.z + w.w*c.w;
    }
    o[v] = acc + bo[j] + srow[j];
  }
  float s1 = o[0] + o[1], s2 = o[0]*o[0] + o[1]*o[1];
  s1 = blk_sum(s1, sm, tid); s2 = blk_sum(s2, sm, tid);
  float m1 = s1 * (1.f/512.f);
  float r1 = rsqrtf(s2 * (1.f/512.f) - m1*m1 + EPS_LN);
  float a[2];
#pragma unroll
  for (int v = 0; v < 2; ++v) {
    int j = tid + v*256;
    a[v] = (o[v] - m1) * r1 * att_g[j] + att_b[j];
  }
  s1 = a[0] + a[1]; s2 = a[0]*a[0] + a[1]*a[1];
  s1 = blk_sum(s1, sm, tid); s2 = blk_sum(s2, sm, tid);
  float m2 = s1 * (1.f/512.f);
  float r2 = rsqrtf(s2 * (1.f/512.f) - m2*m2 + EPS_LN);
#pragma unroll
  for (int v = 0; v < 2; ++v) {
    int j = tid + v*256;
    buf[j] = (a[v] - m2) * r2 * on_g[j] + on_b[j];
  }
  __syncthreads();

  const float4* w1 = (const float4*)(Wp1 + (long)tid * 512);
  const float4* b4 = (const float4*)buf;
  float acc = 0.f;
  for (int kx = 0; kx < 128; ++kx) {
    float4 w = w1[kx], c = b4[kx];
    acc += w.x*c.x + w.y*c.y + w.z*c.z + w.w*c.w;
  }
  float mid = fmaxf(acc + bp1[tid], 0.f);
  float contrib = mid * Wp2[tid];
  float tot = blk_sum(contrib, sm, tid);
  if (tid == 0) out[b] = tot + bp2[0];
}

extern "C" void kernel_launch(void* const* d_in, const int* in_sizes, int n_in,
                              void* d_out, int out_size, void* d_ws, size_t ws_size,
                              hipStream_t stream)
{
  const float* x     = (const float*)d_in[0];
  const float* Wi    = (const float*)d_in[1];
  const float* bi    = (const float*)d_in[2];
  const float* Wh    = (const float*)d_in[3];
  const float* bh    = (const float*)d_in[4];
  const float* g_in  = (const float*)d_in[5];
  const float* b_in  = (const float*)d_in[6];
  const float* g_hid = (const float*)d_in[7];
  const float* b_hid = (const float*)d_in[8];
  const float* g_cell= (const float*)d_in[9];
  const float* b_cell= (const float*)d_in[10];
  const float* hwWt  = (const float*)d_in[11];
  const float* hwbt  = (const float*)d_in[12];
  const float* hwWc  = (const float*)d_in[13];
  const float* hwbc  = (const float*)d_in[14];
  const float* hwWh  = (const float*)d_in[15];
  const float* hwbh  = (const float*)d_in[16];
  const float* Wq    = (const float*)d_in[17];
  const float* bq    = (const float*)d_in[18];
  const float* Wk    = (const float*)d_in[19];
  const float* bk    = (const float*)d_in[20];
  const float* Wv    = (const float*)d_in[21];
  const float* bv    = (const float*)d_in[22];
  const float* Wo    = (const float*)d_in[23];
  const float* bo    = (const float*)d_in[24];
  const float* att_g = (const float*)d_in[25];
  const float* att_b = (const float*)d_in[26];
  const float* on_g  = (const float*)d_in[27];
  const float* on_b  = (const float*)d_in[28];
  const float* Wp1   = (const float*)d_in[29];
  const float* bp1   = (const float*)d_in[30];
  const float* Wp2   = (const float*)d_in[31];
  const float* bp2   = (const float*)d_in[32];
  float* out = (float*)d_out;

  // ---- workspace layout (floats); never touches d_in ----
  const long SEQF = (long)Bn * Sn * Hn;      // 16,777,216
  const long WHPF = 2L * 256 * G4n;          // 1,048,576 (uint32 slots)
  const long ZBF  = 2L * 32 * 2048 * 2;      // 262,144 uint64 = 524,288 floats
  const long wsF  = (long)(ws_size / 4);

  float* ws   = (float*)d_ws;
  float* seq  = ws;                  // [B,S,H]
  float* hseq = seq  + SEQF;         // [B,S,H]
  uint32* WhP = (uint32*)(hseq + SEQF);  // [2][256][2048] packed f16 pairs
  uint64* zbuf = (uint64*)(hseq + SEQF + WHPF);  // [2][32][2048][2] tagged z words
  float* hst  = hseq + SEQF + WHPF + 2*ZBF;  // [64][512]
  float* cst  = hst  + 32768L;
  float* qlst = cst  + 32768L;       // [64][512]
  float* ctx  = qlst + 32768L;       // [64][512]
  float* qkh  = ctx  + 32768L;       // [64][8][512]
  float* qbk  = qkh  + 262144L;      // [64][8] (pad to 1024)
  float* uat  = qbk  + 1024L;        // [64][8][512]
  float* ipc  = uat  + 262144L;      // [TCH*64][2048]
  const long baseF = (ipc - ws);

  int TCH = 128;
  while (TCH > 16 && baseF + (long)TCH * 64 * 2048 > wsF) TCH >>= 1;

  wh_pack_k<<<dim3(16, 64, 2), 256, 0, stream>>>(Wh, WhP);
  init_zbuf_k<<<512, 512, 0, stream>>>(zbuf);

  const int NCH = Sn / TCH;
  const int MROWS = TCH * 64;
  const int NMCH = (Bn * Sn) / MROWS;

  for (int l = 0; l < 2; ++l) {
    const float* seqin = (l == 0) ? x : seq;
    init_hc_k<<<128, 256, 0, stream>>>(hst, cst);
    for (int c = 0; c < NCH; ++c) {
      const int s0 = c * TCH;
      gemm_ip_k<<<dim3(16, TCH/2), 256, 0, stream>>>(seqin, Wi + (long)l*G4n*Hn, bi + l*G4n, ipc, s0);
      ln_rows_k<<<TCH*64, 256, 0, stream>>>(ipc, g_in + l*G4n, b_in + l*G4n);
      lstm_seqz_k<<<256, 512, 0, stream>>>(WhP + (long)l*256*G4n, bh + l*G4n, ipc,
          g_hid + l*G4n, b_hid + l*G4n, g_cell + l*Hn, b_cell + l*Hn,
          hst, cst, hseq, zbuf, s0, TCH, l*Sn + s0 + 1);
    }
    // fused highway: 3 GEMMs + elementwise combine in one kernel, writes seq
    for (int mc = 0; mc < NMCH; ++mc) {
      const long m0 = (long)mc * MROWS;
      hw_fused_k<<<dim3(8, MROWS/128), 256, 0, stream>>>(
          hseq + m0*512,
          hwWt + (long)l*Hn*Hn, hwbt + l*Hn,
          hwWc + (long)l*Hn*Hn, hwbc + l*Hn,
          hwWh + (long)l*Hn*Hn, hwbh + l*Hn,
          seq + m0*512, (l == 0) ? 0 : 1);
    }
  }

  // attention on last query row, K/V never materialized
  gemm_m64_k<<<dim3(8, 1), 256, 0, stream>>>(seq + 511L*512, 512L*512, Wq, bq, qlst, 512, 512);
  qkh_k<<<dim3(8, 4), 256, 0, stream>>>(qlst, Wk, bk, qkh, qbk);
  attn2_k<<<dim3(64, 8), 256, 0, stream>>>(seq, qkh, qbk, uat);
  ctxv_k<<<64, 256, 0, stream>>>(uat, Wv, bv, ctx);
  head_k<<<64, 256, 0, stream>>>(ctx, Wo, bo, seq, att_g, att_b, on_g, on_b, Wp1, bp1, Wp2, bp2, out);
}

// Round 9
// 9183.656 us; speedup vs baseline: 1.1044x; 1.0076x over previous
//
#include <hip/hip_runtime.h>

#define EPS_LN 1e-5f

static constexpr int Bn  = 64;
static constexpr int Sn  = 512;
static constexpr int Hn  = 512;
static constexpr int G4n = 2048;

typedef unsigned int uint32;
typedef unsigned long long uint64;
typedef _Float16 h2v __attribute__((ext_vector_type(2)));

__device__ __forceinline__ float sigf(float x)     { return 1.0f / (1.0f + __expf(-x)); }
__device__ __forceinline__ float tanhfast(float x) { return 1.0f - 2.0f / (1.0f + __expf(2.0f * x)); }

// dot2: acc += w.lo*h.lo + w.hi*h.hi   (f16 inputs, fp32 accumulate)
__device__ __forceinline__ float dot2h(uint32 w, uint32 h, float acc) {
#if defined(__has_builtin)
#if __has_builtin(__builtin_amdgcn_fdot2)
  return __builtin_amdgcn_fdot2(__builtin_bit_cast(h2v, w), __builtin_bit_cast(h2v, h), acc, false);
#define DOT2_DONE 1
#endif
#endif
#ifndef DOT2_DONE
  h2v wv = __builtin_bit_cast(h2v, w);
  h2v hv = __builtin_bit_cast(h2v, h);
  return acc + (float)wv.x * (float)hv.x + (float)wv.y * (float)hv.y;
#endif
}
__device__ __forceinline__ uint32 packh2(float a, float b) {
  h2v v; v.x = (_Float16)a; v.y = (_Float16)b;
  return __builtin_bit_cast(uint32, v);
}

// ---- block reductions (256-thread kernels) ----
__device__ __forceinline__ float blk_sum(float v, float* sm, int tid) {
#pragma unroll
  for (int o = 32; o; o >>= 1) v += __shfl_down(v, o, 64);
  __syncthreads();
  if ((tid & 63) == 0) sm[tid >> 6] = v;
  __syncthreads();
  return sm[0] + sm[1] + sm[2] + sm[3];
}
__device__ __forceinline__ float blk_max(float v, float* sm, int tid) {
#pragma unroll
  for (int o = 32; o; o >>= 1) v = fmaxf(v, __shfl_down(v, o, 64));
  __syncthreads();
  if ((tid & 63) == 0) sm[tid >> 6] = v;
  __syncthreads();
  return fmaxf(fmaxf(sm[0], sm[1]), fmaxf(sm[2], sm[3]));
}

// ---- fused 4-value reduction across a 512-thread (8-wave) block ----
__device__ __forceinline__ void blk_sum4_w8(float& a, float& b, float& c, float& d,
                                            float* sm, int tid) {
#pragma unroll
  for (int o = 32; o; o >>= 1) {
    a += __shfl_down(a, o, 64);
    b += __shfl_down(b, o, 64);
    c += __shfl_down(c, o, 64);
    d += __shfl_down(d, o, 64);
  }
  __syncthreads();
  if ((tid & 63) == 0) {
    float4 v; v.x = a; v.y = b; v.z = c; v.w = d;
    *(float4*)&sm[(tid >> 6) * 4] = v;
  }
  __syncthreads();
  float ra = 0.f, rb = 0.f, rc = 0.f, rd = 0.f;
#pragma unroll
  for (int w = 0; w < 8; ++w) {
    float4 v = *(const float4*)&sm[w * 4];
    ra += v.x; rb += v.y; rc += v.z; rd += v.w;
  }
  a = ra; b = rb; c = rc; d = rd;
}

// ---- Wh pack: WhP[l][kp][n] = half2(Wh[l][n][2kp], Wh[l][n][2kp+1]) ----
__global__ __launch_bounds__(256) void wh_pack_k(
    const float* __restrict__ Wh, uint32* __restrict__ WhP)
{
  __shared__ float tile[32][33];
  const int l = blockIdx.z;
  const int k0 = blockIdx.x * 32;
  const int n0 = blockIdx.y * 32;
  const int row = threadIdx.x >> 5, col = threadIdx.x & 31;
  const float* src = Wh + (long)l * G4n * Hn;
  uint32* dst = WhP + (long)l * 256 * G4n;
#pragma unroll
  for (int rr = 0; rr < 4; ++rr) {
    int nn = row + rr * 8;
    tile[nn][col] = src[(long)(n0 + nn) * Hn + k0 + col];
  }
  __syncthreads();
#pragma unroll
  for (int rr = 0; rr < 2; ++rr) {
    int kpl = row + rr * 8;                     // 0..15
    int kp = (k0 >> 1) + kpl;
    dst[(long)kp * G4n + n0 + col] = packh2(tile[col][2*kpl], tile[col][2*kpl+1]);
  }
}

__global__ void init_zbuf_k(uint64* zbuf)
{
  long i = (long)blockIdx.x * 512 + threadIdx.x;
  zbuf[i] = 0ULL;
}

// ---- ip-chunk GEMM (f16-packed fdot2, K=16 slabs, global-load prefetch), ----
// time-major output: row r = t_local*64 + b
// Prefetch: next-slab global loads issued right after the LDS-write barrier,
// BEFORE the compute loop -- hides L2 latency under the 64-dot2 inner loop.
__global__ __launch_bounds__(256) void gemm_ip_k(
    const float* __restrict__ A,       // [B,S,H]
    const float* __restrict__ Bw,      // [2048,512]
    const float* __restrict__ bias,
    float* __restrict__ C,             // [TCH*64, 2048]
    int s0)
{
  __shared__ __align__(16) uint32 Ah[8][128];
  __shared__ __align__(16) uint32 Bh[8][128];
  const int tid = threadIdx.x;
  const long m0 = (long)blockIdx.y * 128;
  const long n0 = (long)blockIdx.x * 128;
  const int tx = tid & 15, ty = tid >> 4;
  const int lrow = tid >> 1;
  const int lc0  = (tid & 1) * 8;
  const int kb   = (tid & 1) * 4;
  float acc[8][8];
#pragma unroll
  for (int i = 0; i < 8; ++i)
#pragma unroll
    for (int j = 0; j < 8; ++j) acc[i][j] = 0.f;

  const long r  = m0 + lrow;
  const long b  = r & 63;
  const long sl = r >> 6;
  const float* Arow = A + (b * Sn + s0 + sl) * Hn;
  const float* Brow = Bw + (n0 + lrow) * 512L;

  float4 a0 = *(const float4*)(Arow + lc0);
  float4 a1 = *(const float4*)(Arow + lc0 + 4);
  float4 b0 = *(const float4*)(Brow + lc0);
  float4 b1 = *(const float4*)(Brow + lc0 + 4);

  for (int k0 = 0; k0 < 512; k0 += 16) {
    __syncthreads();
    Ah[kb+0][lrow] = packh2(a0.x, a0.y);
    Ah[kb+1][lrow] = packh2(a0.z, a0.w);
    Ah[kb+2][lrow] = packh2(a1.x, a1.y);
    Ah[kb+3][lrow] = packh2(a1.z, a1.w);
    Bh[kb+0][lrow] = packh2(b0.x, b0.y);
    Bh[kb+1][lrow] = packh2(b0.z, b0.w);
    Bh[kb+2][lrow] = packh2(b1.x, b1.y);
    Bh[kb+3][lrow] = packh2(b1.z, b1.w);
    __syncthreads();
    if (k0 + 16 < 512) {
      a0 = *(const float4*)(Arow + k0 + 16 + lc0);
      a1 = *(const float4*)(Arow + k0 + 16 + lc0 + 4);
      b0 = *(const float4*)(Brow + k0 + 16 + lc0);
      b1 = *(const float4*)(Brow + k0 + 16 + lc0 + 4);
    }
#pragma unroll
    for (int kp = 0; kp < 8; ++kp) {
      uint32 a8[8], b8[8];
      *(uint4*)&a8[0] = *(const uint4*)&Ah[kp][ty*8];
      *(uint4*)&a8[4] = *(const uint4*)&Ah[kp][ty*8+4];
      *(uint4*)&b8[0] = *(const uint4*)&Bh[kp][tx*8];
      *(uint4*)&b8[4] = *(const uint4*)&Bh[kp][tx*8+4];
#pragma unroll
      for (int i = 0; i < 8; ++i)
#pragma unroll
        for (int j = 0; j < 8; ++j) acc[i][j] = dot2h(a8[i], b8[j], acc[i][j]);
    }
  }
#pragma unroll
  for (int i = 0; i < 8; ++i) {
    long m = m0 + ty*8 + i;
    float* crow = C + m * 2048L + n0 + tx*8;
    const float* br = bias + n0 + tx*8;
    float4 o0, o1;
    o0.x = acc[i][0]+br[0]; o0.y = acc[i][1]+br[1]; o0.z = acc[i][2]+br[2]; o0.w = acc[i][3]+br[3];
    o1.x = acc[i][4]+br[4]; o1.y = acc[i][5]+br[5]; o1.z = acc[i][6]+br[6]; o1.w = acc[i][7]+br[7];
    *(float4*)crow = o0; *(float4*)(crow+4) = o1;
  }
}

// ---- fused highway with global-load prefetch: 3 projections of the same A rows
// (A staged once) + elementwise combine in the epilogue. Tile 128x64.
// out[m][n] = sigf(t1)*relu(t3) + sigf(t2)*A[m][n] (+ seq[m][n] if skip)
__global__ __launch_bounds__(256) void hw_fused_k(
    const float* __restrict__ A,       // hseq + m0*512 (lda = 512)
    const float* __restrict__ Wt, const float* __restrict__ bt,
    const float* __restrict__ Wc, const float* __restrict__ bc,
    const float* __restrict__ Wh3, const float* __restrict__ bh3,
    float* __restrict__ seqout,        // seq + m0*512
    int skip)
{
  __shared__ __align__(16) uint32 Ah[8][128];     // [k-pair][row]
  __shared__ __align__(16) uint32 Bh[3][8][68];   // [mat][k-pair][col] pad 68
  const int tid = threadIdx.x;
  const long m0 = (long)blockIdx.y * 128;
  const int n0 = blockIdx.x * 64;
  const int tx = tid & 7;            // col-group (8 cols each)
  const int ty = tid >> 3;           // row-group (4 rows each)
  const int lrow = tid >> 1;         // A staging row
  const int lc0  = (tid & 1) * 8;
  const int kbA  = (tid & 1) * 4;
  const int brow = tid >> 2;         // B staging col (0..63)
  const int bk0  = (tid & 3) * 4;
  const int kbB  = (tid & 3) * 2;

  float accT[4][8], accC[4][8], accH[4][8];
#pragma unroll
  for (int i = 0; i < 4; ++i)
#pragma unroll
    for (int j = 0; j < 8; ++j) { accT[i][j] = 0.f; accC[i][j] = 0.f; accH[i][j] = 0.f; }

  const float* Arow = A + (m0 + lrow) * 512;
  const long boff = (long)(n0 + brow) * 512 + bk0;

  float4 a0 = *(const float4*)(Arow + lc0);
  float4 a1 = *(const float4*)(Arow + lc0 + 4);
  float4 wt4 = *(const float4*)(Wt  + boff);
  float4 wc4 = *(const float4*)(Wc  + boff);
  float4 wh4 = *(const float4*)(Wh3 + boff);

  for (int k0 = 0; k0 < 512; k0 += 16) {
    __syncthreads();
    Ah[kbA+0][lrow] = packh2(a0.x, a0.y);
    Ah[kbA+1][lrow] = packh2(a0.z, a0.w);
    Ah[kbA+2][lrow] = packh2(a1.x, a1.y);
    Ah[kbA+3][lrow] = packh2(a1.z, a1.w);
    Bh[0][kbB+0][brow] = packh2(wt4.x, wt4.y);
    Bh[0][kbB+1][brow] = packh2(wt4.z, wt4.w);
    Bh[1][kbB+0][brow] = packh2(wc4.x, wc4.y);
    Bh[1][kbB+1][brow] = packh2(wc4.z, wc4.w);
    Bh[2][kbB+0][brow] = packh2(wh4.x, wh4.y);
    Bh[2][kbB+1][brow] = packh2(wh4.z, wh4.w);
    __syncthreads();
    if (k0 + 16 < 512) {
      a0 = *(const float4*)(Arow + k0 + 16 + lc0);
      a1 = *(const float4*)(Arow + k0 + 16 + lc0 + 4);
      wt4 = *(const float4*)(Wt  + boff + k0 + 16);
      wc4 = *(const float4*)(Wc  + boff + k0 + 16);
      wh4 = *(const float4*)(Wh3 + boff + k0 + 16);
    }
#pragma unroll
    for (int kp = 0; kp < 8; ++kp) {
      uint32 a4[4];
      *(uint4*)&a4[0] = *(const uint4*)&Ah[kp][ty*4];
      {
        uint32 b8[8];
        *(uint4*)&b8[0] = *(const uint4*)&Bh[0][kp][tx*8];
        *(uint4*)&b8[4] = *(const uint4*)&Bh[0][kp][tx*8+4];
#pragma unroll
        for (int i = 0; i < 4; ++i)
#pragma unroll
          for (int j = 0; j < 8; ++j) accT[i][j] = dot2h(a4[i], b8[j], accT[i][j]);
      }
      {
        uint32 b8[8];
        *(uint4*)&b8[0] = *(const uint4*)&Bh[1][kp][tx*8];
        *(uint4*)&b8[4] = *(const uint4*)&Bh[1][kp][tx*8+4];
#pragma unroll
        for (int i = 0; i < 4; ++i)
#pragma unroll
          for (int j = 0; j < 8; ++j) accC[i][j] = dot2h(a4[i], b8[j], accC[i][j]);
      }
      {
        uint32 b8[8];
        *(uint4*)&b8[0] = *(const uint4*)&Bh[2][kp][tx*8];
        *(uint4*)&b8[4] = *(const uint4*)&Bh[2][kp][tx*8+4];
#pragma unroll
        for (int i = 0; i < 4; ++i)
#pragma unroll
          for (int j = 0; j < 8; ++j) accH[i][j] = dot2h(a4[i], b8[j], accH[i][j]);
      }
    }
  }

  // epilogue: combine + write seq
  float btr[8], bcr[8], bhr[8];
#pragma unroll
  for (int j = 0; j < 8; ++j) {
    btr[j] = bt[n0 + tx*8 + j];
    bcr[j] = bc[n0 + tx*8 + j];
    bhr[j] = bh3[n0 + tx*8 + j];
  }
#pragma unroll
  for (int i = 0; i < 4; ++i) {
    const long m = m0 + ty*4 + i;
    const float* hrow = A + m * 512 + n0 + tx*8;
    float* srow = seqout + m * 512 + n0 + tx*8;
    float4 h0 = *(const float4*)hrow;
    float4 h1 = *(const float4*)(hrow + 4);
    float hv[8] = {h0.x,h0.y,h0.z,h0.w,h1.x,h1.y,h1.z,h1.w};
    float sv[8] = {0,0,0,0,0,0,0,0};
    if (skip) {
      float4 s0 = *(const float4*)srow;
      float4 s1 = *(const float4*)(srow + 4);
      sv[0]=s0.x; sv[1]=s0.y; sv[2]=s0.z; sv[3]=s0.w;
      sv[4]=s1.x; sv[5]=s1.y; sv[6]=s1.z; sv[7]=s1.w;
    }
    float o[8];
#pragma unroll
    for (int j = 0; j < 8; ++j) {
      const float t1 = accT[i][j] + btr[j];
      const float t2 = accC[i][j] + bcr[j];
      const float t3 = accH[i][j] + bhr[j];
      o[j] = sigf(t1) * fmaxf(t3, 0.f) + sigf(t2) * hv[j] + sv[j];
    }
    float4 o0, o1;
    o0.x=o[0]; o0.y=o[1]; o0.z=o[2]; o0.w=o[3];
    o1.x=o[4]; o1.y=o[5]; o1.z=o[6]; o1.w=o[7];
    *(float4*)srow = o0; *(float4*)(srow + 4) = o1;
  }
}

// ---- M=64 GEMM (used for q projection) ----
__global__ __launch_bounds__(256) void gemm_m64_k(
    const float* __restrict__ A, long lda,
    const float* __restrict__ Bw,
    const float* __restrict__ bias,
    float* __restrict__ P,
    int N, int K)
{
  __shared__ float As[64][64];
  __shared__ float Bs[64][64];
  const int tid = threadIdx.x;
  const int n0 = blockIdx.x * 64;
  const int kc = blockIdx.y;
  const int Kc = K / gridDim.y;
  const int tx = tid & 15, ty = tid >> 4;
  const int row = tid >> 2, q = tid & 3;
  float acc[4][4];
#pragma unroll
  for (int i = 0; i < 4; ++i)
#pragma unroll
    for (int j = 0; j < 4; ++j) acc[i][j] = 0.f;

  for (int k0 = kc * Kc; k0 < kc * Kc + Kc; k0 += 64) {
    float4 a[4], b[4];
#pragma unroll
    for (int c = 0; c < 4; ++c) {
      a[c] = *(const float4*)(A  + (long)row * lda       + k0 + q*16 + c*4);
      b[c] = *(const float4*)(Bw + (long)(n0 + row) * K  + k0 + q*16 + c*4);
    }
    __syncthreads();
#pragma unroll
    for (int c = 0; c < 4; ++c) {
      int kb = q*16 + c*4;
      As[kb+0][row]=a[c].x; As[kb+1][row]=a[c].y; As[kb+2][row]=a[c].z; As[kb+3][row]=a[c].w;
      Bs[kb+0][row]=b[c].x; Bs[kb+1][row]=b[c].y; Bs[kb+2][row]=b[c].z; Bs[kb+3][row]=b[c].w;
    }
    __syncthreads();
#pragma unroll
    for (int kk = 0; kk < 64; ++kk) {
      float4 av = *(const float4*)&As[kk][ty*4];
      float4 bv = *(const float4*)&Bs[kk][tx*4];
      float am[4] = {av.x, av.y, av.z, av.w};
      float bm[4] = {bv.x, bv.y, bv.z, bv.w};
#pragma unroll
      for (int i = 0; i < 4; ++i)
#pragma unroll
        for (int j = 0; j < 4; ++j) acc[i][j] += am[i] * bm[j];
    }
  }
#pragma unroll
  for (int i = 0; i < 4; ++i) {
    int m = ty*4 + i;
    float* pr = P + ((long)kc * 64 + m) * N + n0 + tx*4;
#pragma unroll
    for (int j = 0; j < 4; ++j) {
      float bb = bias ? bias[n0 + tx*4 + j] : 0.f;
      pr[j] = acc[i][j] + bb;
    }
  }
}

// ---- persistent LSTM recurrence: n-split + tagged-word single-round exchange ----
// (verified kernel: ~857us/128 steps, 0 bank conflicts. Publish pattern
//  myword=kq*512+tid gives contiguous full-line wave stores -- DO NOT change it;
//  the strided variant pushes the exchange out of L2, 5.5x slower. Packed-h LDS
//  split lo/hi at +132 words keeps the wave's two broadcast reads on disjoint
//  bank quads. BYTE-IDENTICAL to rounds 5-8.)
__global__ __launch_bounds__(512, 2) void lstm_seqz_k(
    const uint32* __restrict__ WhP,   // [256 kp][2048 n] this layer (f16 pairs)
    const float* __restrict__ bh,
    const float* __restrict__ ipc,    // [TCH*64][2048] time-major LN'd input proj
    const float* __restrict__ g_hid, const float* __restrict__ b_hid,
    const float* __restrict__ g_cell, const float* __restrict__ b_cell,
    float* __restrict__ hst, float* __restrict__ cst,  // [64][512]
    float* __restrict__ hseq,         // [B,S,H]
    uint64* __restrict__ zbuf,        // [2 parity][32 g][2048 row][2 b] tagged words
    int t0, int nsteps, int gbase)    // gbase >= 1, monotonic over the whole run
{
  const int blk = blockIdx.x;
  const int g   = blk & 31;
  const int kq  = blk >> 5;
  const int tid = threadIdx.x;
  const int b0  = g*2, b1 = g*2 + 1;
  const int r   = tid >> 1;          // row within our 256-row slice
  const int kh  = tid & 1;           // k-half (0: k<256, 1: k>=256)
  // packed h pairs: lo half [0..127], hi half at +132 (bank-quad disjoint from lo)
  __shared__ __align__(16) uint32 hp0[264];
  __shared__ __align__(16) uint32 hp1[264];
  __shared__ float sm[32];

  // register-resident weights: rows kq*256+r, k-pairs kh*128 + [0,128)
  uint4 wreg[32];
  {
    const uint32* base = WhP + (long)(kh * 128) * 2048 + (kq*256 + r);
#pragma unroll
    for (int i = 0; i < 32; ++i) {
      wreg[i].x = base[(long)(4*i + 0) * 2048];
      wreg[i].y = base[(long)(4*i + 1) * 2048];
      wreg[i].z = base[(long)(4*i + 2) * 2048];
      wreg[i].w = base[(long)(4*i + 3) * 2048];
    }
  }

  // per-unit params/state: thread owns unit tid (both batches)
  float bhr[4], ghr[4], bhir[4];
#pragma unroll
  for (int q = 0; q < 4; ++q) {
    bhr[q]  = bh[q*512 + tid];
    ghr[q]  = g_hid[q*512 + tid];
    bhir[q] = b_hid[q*512 + tid];
  }
  const float gcv = g_cell[tid];
  const float bcv = b_cell[tid];
  float c0 = cst[b0*512 + tid];
  float c1 = cst[b1*512 + tid];
  float h0 = hst[b0*512 + tid];
  float h1 = hst[b1*512 + tid];

  // initial full-h pack into LDS (lo at j, hi at j+4 for j>=128)
  {
    const float p0 = __shfl_xor(h0, 1, 64);
    const float p1 = __shfl_xor(h1, 1, 64);
    if (!(tid & 1)) {
      const int j = tid >> 1;
      const int jj = (j < 128) ? j : j + 4;
      hp0[jj] = packh2(h0, p0);
      hp1[jj] = packh2(h1, p1);
    }
  }
  __syncthreads();

  const long myword = (long)(kq*256 + r) * 2 + kh;   // = kq*512 + tid (contiguous)
  const uint32* hb0 = hp0 + kh * 132;
  const uint32* hb1 = hp1 + kh * 132;

  for (int ts = 0; ts < nsteps; ++ts) {
    const int gstep = gbase + ts;
    const uint32 tagw = (uint32)gstep;
    uint64* zp = zbuf + (long)(gstep & 1) * 131072 + (long)g * 4096;

    // prefetch ip for our unit (regular cached loads; hide under GEMV)
    const float* iprow0 = ipc + ((long)ts * 64 + b0) * 2048 + tid;
    const float* iprow1 = ipc + ((long)ts * 64 + b1) * 2048 + tid;
    float ip0[4], ip1[4];
#pragma unroll
    for (int q = 0; q < 4; ++q) { ip0[q] = iprow0[q*512]; ip1[q] = iprow1[q*512]; }

    // GEMV: full-k half for row kq*256+r, both batches (h via LDS broadcast)
    float a0 = 0.f, a1 = 0.f;
#pragma unroll
    for (int i = 0; i < 32; ++i) {
      const uint4 w  = wreg[i];
      const uint4 hv0 = *(const uint4*)&hb0[4*i];
      const uint4 hv1 = *(const uint4*)&hb1[4*i];
      a0 = dot2h(w.x, hv0.x, a0); a0 = dot2h(w.y, hv0.y, a0);
      a0 = dot2h(w.z, hv0.z, a0); a0 = dot2h(w.w, hv0.w, a0);
      a1 = dot2h(w.x, hv1.x, a1); a1 = dot2h(w.y, hv1.y, a1);
      a1 = dot2h(w.z, hv1.z, a1); a1 = dot2h(w.w, hv1.w, a1);
    }
    // combine k-halves within the lane pair
    a0 += __shfl_xor(a0, 1, 64);
    a1 += __shfl_xor(a1, 1, 64);

    // publish one tagged word (fire-and-forget; tag rides with payload)
    {
      const float zval = kh ? a1 : a0;
      const uint64 w = ((uint64)tagw << 32) | (uint64)__builtin_bit_cast(uint32, zval);
      __hip_atomic_store(zp + myword, w, __ATOMIC_RELAXED, __HIP_MEMORY_SCOPE_AGENT);
    }

    // gather the 8 tagged words for unit tid: rows {tid,512+tid,1024+tid,1536+tid} x {b0,b1}
    float z0[4], z1[4];
    {
      uint64 v0[4], v1[4];
      int pend = 0xff;
      while (pend) {
#pragma unroll
        for (int q = 0; q < 4; ++q) {
          const long base = (long)(q*512 + tid) * 2;
          if (pend & (1 << q)) {
            uint64 w = __hip_atomic_load(zp + base, __ATOMIC_RELAXED, __HIP_MEMORY_SCOPE_AGENT);
            if ((uint32)(w >> 32) == tagw) { v0[q] = w; pend &= ~(1 << q); }
          }
          if (pend & (16 << q)) {
            uint64 w = __hip_atomic_load(zp + base + 1, __ATOMIC_RELAXED, __HIP_MEMORY_SCOPE_AGENT);
            if ((uint32)(w >> 32) == tagw) { v1[q] = w; pend &= ~(16 << q); }
          }
        }
        if (pend) __builtin_amdgcn_s_sleep(2);
      }
#pragma unroll
      for (int q = 0; q < 4; ++q) {
        z0[q] = __builtin_bit_cast(float, (uint32)v0[q]) + bhr[q];
        z1[q] = __builtin_bit_cast(float, (uint32)v1[q]) + bhr[q];
      }
    }

    // LN1 over 2048, both batches in one reduction pass
    float s10 = z0[0]+z0[1]+z0[2]+z0[3];
    float s20 = z0[0]*z0[0] + z0[1]*z0[1] + z0[2]*z0[2] + z0[3]*z0[3];
    float s11 = z1[0]+z1[1]+z1[2]+z1[3];
    float s21 = z1[0]*z1[0] + z1[1]*z1[1] + z1[2]*z1[2] + z1[3]*z1[3];
    blk_sum4_w8(s10, s20, s11, s21, sm, tid);
    const float m0 = s10 * (1.f/2048.f);
    const float r0 = rsqrtf(s20 * (1.f/2048.f) - m0*m0 + EPS_LN);
    const float m1 = s11 * (1.f/2048.f);
    const float r1 = rsqrtf(s21 * (1.f/2048.f) - m1*m1 + EPS_LN);

    const float gi0 = ip0[0] + (z0[0] - m0) * r0 * ghr[0] + bhir[0];
    const float gf0 = ip0[1] + (z0[1] - m0) * r0 * ghr[1] + bhir[1];
    const float gg0 = ip0[2] + (z0[2] - m0) * r0 * ghr[2] + bhir[2];
    const float go0 = ip0[3] + (z0[3] - m0) * r0 * ghr[3] + bhir[3];
    const float gi1 = ip1[0] + (z1[0] - m1) * r1 * ghr[0] + bhir[0];
    const float gf1 = ip1[1] + (z1[1] - m1) * r1 * ghr[1] + bhir[1];
    const float gg1 = ip1[2] + (z1[2] - m1) * r1 * ghr[2] + bhir[2];
    const float go1 = ip1[3] + (z1[3] - m1) * r1 * ghr[3] + bhir[3];

    c0 = sigf(gf0) * c0 + sigf(gi0) * tanhfast(gg0);
    c1 = sigf(gf1) * c1 + sigf(gi1) * tanhfast(gg1);

    // LN2 over 512 cells, both batches in one pass
    float t10 = c0, t20 = c0*c0, t11 = c1, t21 = c1*c1;
    blk_sum4_w8(t10, t20, t11, t21, sm, tid);
    const float n0 = t10 * (1.f/512.f);
    const float q0r = rsqrtf(t20 * (1.f/512.f) - n0*n0 + EPS_LN);
    const float n1 = t11 * (1.f/512.f);
    const float q1r = rsqrtf(t21 * (1.f/512.f) - n1*n1 + EPS_LN);
    h0 = sigf(go0) * tanhfast((c0 - n0) * q0r * gcv + bcv);
    h1 = sigf(go1) * tanhfast((c1 - n1) * q1r * gcv + bcv);

    if (kq == 0) {
      hseq[((long)b0 * Sn + t0 + ts) * Hn + tid] = h0;
      hseq[((long)b1 * Sn + t0 + ts) * Hn + tid] = h1;
    }

    // repack full h into LDS for next step (blk_sum4 already synced past GEMV reads)
    const float p0 = __shfl_xor(h0, 1, 64);
    const float p1 = __shfl_xor(h1, 1, 64);
    if (!(tid & 1)) {
      const int j = tid >> 1;
      const int jj = (j < 128) ? j : j + 4;
      hp0[jj] = packh2(h0, p0);
      hp1[jj] = packh2(h1, p1);
    }
    __syncthreads();
  }
  if (kq == 0) {
    hst[b0*512 + tid] = h0; hst[b1*512 + tid] = h1;
    cst[b0*512 + tid] = c0; cst[b1*512 + tid] = c1;
  }
}

// ---- layernorm over rows of 2048 (in-place) ----
__global__ __launch_bounds__(256) void ln_rows_k(
    float* __restrict__ X, const float* __restrict__ g, const float* __restrict__ bt)
{
  const long row = blockIdx.x;
  float* xr = X + row * 2048L;
  const int tid = threadIdx.x;
  __shared__ float sm[4];
  float4 v0 = *(float4*)(xr + tid*8);
  float4 v1 = *(float4*)(xr + tid*8 + 4);
  float s1 = v0.x+v0.y+v0.z+v0.w + v1.x+v1.y+v1.z+v1.w;
  float s2 = v0.x*v0.x+v0.y*v0.y+v0.z*v0.z+v0.w*v0.w
           + v1.x*v1.x+v1.y*v1.y+v1.z*v1.z+v1.w*v1.w;
  s1 = blk_sum(s1, sm, tid);
  s2 = blk_sum(s2, sm, tid);
  const float mean = s1 * (1.f/2048.f);
  const float rstd = rsqrtf(s2 * (1.f/2048.f) - mean*mean + EPS_LN);
  const int base = tid*8;
  float vals[8] = {v0.x,v0.y,v0.z,v0.w,v1.x,v1.y,v1.z,v1.w};
#pragma unroll
  for (int c = 0; c < 8; ++c)
    xr[base + c] = (vals[c] - mean) * rstd * g[base + c] + bt[base + c];
}

__global__ void init_hc_k(float* h, float* c)
{
  int i = blockIdx.x * 256 + threadIdx.x;
  h[i] = 0.f; c[i] = 0.f;
}

// ---- qkh[b][hd][:] = sum_{j in head} q[b, hd*64+j] * Wk[hd*64+j, :]; qbk = q.bk ----
__global__ __launch_bounds__(256) void qkh_k(
    const float* __restrict__ qlst, const float* __restrict__ Wk,
    const float* __restrict__ bk,
    float* __restrict__ qkh, float* __restrict__ qbk)
{
  const int hd = blockIdx.x, cg = blockIdx.y;
  const int b = threadIdx.x & 63, sc = threadIdx.x >> 6;
  const int col0 = cg * 128 + sc * 32;
  float qreg[64];
  const float* qp = qlst + b*512 + hd*64;
#pragma unroll
  for (int j4 = 0; j4 < 16; ++j4) {
    float4 v = *(const float4*)(qp + j4*4);
    qreg[j4*4+0]=v.x; qreg[j4*4+1]=v.y; qreg[j4*4+2]=v.z; qreg[j4*4+3]=v.w;
  }
  float acc[32];
#pragma unroll
  for (int c = 0; c < 32; ++c) acc[c] = 0.f;
  for (int j = 0; j < 64; ++j) {
    float qv = qreg[j];
    const float* wr = Wk + (long)(hd*64 + j)*512 + col0;
#pragma unroll
    for (int c4 = 0; c4 < 8; ++c4) {
      float4 w = *(const float4*)(wr + c4*4);
      acc[c4*4+0] = __builtin_fmaf(qv, w.x, acc[c4*4+0]);
      acc[c4*4+1] = __builtin_fmaf(qv, w.y, acc[c4*4+1]);
      acc[c4*4+2] = __builtin_fmaf(qv, w.z, acc[c4*4+2]);
      acc[c4*4+3] = __builtin_fmaf(qv, w.w, acc[c4*4+3]);
    }
  }
  float* op = qkh + ((long)b*8 + hd)*512 + col0;
#pragma unroll
  for (int c4 = 0; c4 < 8; ++c4) {
    float4 o;
    o.x = acc[c4*4+0]; o.y = acc[c4*4+1]; o.z = acc[c4*4+2]; o.w = acc[c4*4+3];
    *(float4*)(op + c4*4) = o;
  }
  if (cg == 0 && sc == 0) {
    float s = 0.f;
    for (int j = 0; j < 64; ++j) s += qreg[j] * bk[hd*64 + j];
    qbk[b*8 + hd] = s;
  }
}

// ---- fused last-row attention ----
__global__ __launch_bounds__(256) void attn2_k(
    const float* __restrict__ seq,   // [B,S,H]
    const float* __restrict__ qkh,   // [64][8][512]
    const float* __restrict__ qbk,   // [64][8]
    float* __restrict__ u)           // [64][8][512]
{
  const int b = blockIdx.x, hd = blockIdx.y, tid = threadIdx.x;
  __shared__ __align__(16) float qk[512];
  __shared__ float p[512];
  __shared__ float sm[4];
  qk[tid]       = qkh[((long)b*8 + hd)*512 + tid];
  qk[tid + 256] = qkh[((long)b*8 + hd)*512 + tid + 256];
  __syncthreads();
  const float bias = qbk[b*8 + hd];

  float loc[2]; float mx = -3.0e38f;
#pragma unroll
  for (int v = 0; v < 2; ++v) {
    int s = tid + v*256;
    const float4* sr = (const float4*)(seq + ((long)b*512 + s)*512);
    const float4* qv4 = (const float4*)qk;
    float d = 0.f;
    for (int k4 = 0; k4 < 128; ++k4) {
      float4 sv = sr[k4], qv = qv4[k4];
      d += sv.x*qv.x + sv.y*qv.y + sv.z*qv.z + sv.w*qv.w;
    }
    d = (d + bias) * 0.125f;
    loc[v] = d; mx = fmaxf(mx, d);
  }
  const float M = blk_max(mx, sm, tid);
  float sum = 0.f;
#pragma unroll
  for (int v = 0; v < 2; ++v) {
    int s = tid + v*256;
    float e = __expf(loc[v] - M);
    p[s] = e; sum += e;
  }
  const float SM = blk_sum(sum, sm, tid);
  const float inv = 1.f / SM;

  float u0 = 0.f, u1 = 0.f;
  for (int s = 0; s < 512; ++s) {
    float ps = p[s];
    const float* srow = seq + ((long)b*512 + s)*512;
    u0 = __builtin_fmaf(ps, srow[tid], u0);
    u1 = __builtin_fmaf(ps, srow[tid + 256], u1);
  }
  u[((long)b*8 + hd)*512 + tid]       = u0 * inv;
  u[((long)b*8 + hd)*512 + tid + 256] = u1 * inv;
}

// ---- ctx[b][n] = u[b][hd(n)][:] . Wv[n][:] + bv[n] ----
__global__ __launch_bounds__(256) void ctxv_k(
    const float* __restrict__ u, const float* __restrict__ Wv,
    const float* __restrict__ bv, float* __restrict__ ctx)
{
  const int b = blockIdx.x, tid = threadIdx.x;
  __shared__ __align__(16) float ul[8*512];
  for (int i = tid; i < 4096; i += 256) ul[i] = u[(long)b*4096 + i];
  __syncthreads();
#pragma unroll
  for (int v = 0; v < 2; ++v) {
    int n = tid + v*256;
    int hd = n >> 6;
    const float4* wr = (const float4*)(Wv + (long)n*512);
    const float4* uv = (const float4*)&ul[hd*512];
    float acc = 0.f;
    for (int k4 = 0; k4 < 128; ++k4) {
      float4 w = wr[k4], x = uv[k4];
      acc += w.x*x.x + w.y*x.y + w.z*x.z + w.w*x.w;
    }
    ctx[b*512 + n] = acc + bv[n];
  }
}

// ---- output head ----
__global__ __launch_bounds__(256) void head_k(
    const float* __restrict__ ctx,
    const float* __restrict__ Wo, const float* __restrict__ bo,
    const float* __restrict__ seq,
    const float* __restrict__ att_g, const float* __restrict__ att_b,
    const float* __restrict__ on_g, const float* __restrict__ on_b,
    const float* __restrict__ Wp1, const float* __restrict__ bp1,
    const float* __restrict__ Wp2, const float* __restrict__ bp2,
    float* __restrict__ out)
{
  const int b = blockIdx.x, tid = threadIdx.x;
  __shared__ __align__(16) float cs[512];
  __shared__ __align__(16) float buf[512];
  __shared__ float sm[4];
  cs[tid]       = ctx[b*512 + tid];
  cs[tid + 256] = ctx[b*512 + tid + 256];
  __syncthreads();

  const float* srow = seq + ((long)b*512 + 511) * 512;
  float o[2];
#pragma unroll
  for (int v = 0; v < 2; ++v) {
    int j = tid + v*256;
    const float4* w4 = (const float4*)(Wo + (long)j * 512);
    const float4* c4 = (const float4*)cs;
    float acc = 0.f;
    for (int kx = 0; kx < 128; ++kx) {
      float4 w = w4[kx], c = c4[kx];
      acc += w.x*c.x + w.y*c.y + w.z*c.z + w.w*c.w;
    }
    o[v] = acc + bo[j] + srow[j];
  }
  float s1 = o[0] + o[1], s2 = o[0]*o[0] + o[1]*o[1];
  s1 = blk_sum(s1, sm, tid); s2 = blk_sum(s2, sm, tid);
  float m1 = s1 * (1.f/512.f);
  float r1 = rsqrtf(s2 * (1.f/512.f) - m1*m1 + EPS_LN);
  float a[2];
#pragma unroll
  for (int v = 0; v < 2; ++v) {
    int j = tid + v*256;
    a[v] = (o[v] - m1) * r1 * att_g[j] + att_b[j];
  }
  s1 = a[0] + a[1]; s2 = a[0]*a[0] + a[1]*a[1];
  s1 = blk_sum(s1, sm, tid); s2 = blk_sum(s2, sm, tid);
  float m2 = s1 * (1.f/512.f);
  float r2 = rsqrtf(s2 * (1.f/512.f) - m2*m2 + EPS_LN);
#pragma unroll
  for (int v = 0; v < 2; ++v) {
    int j = tid + v*256;
    buf[j] = (a[v] - m2) * r2 * on_g[j] + on_b[j];
  }
  __syncthreads();

  const float4* w1 = (const float4*)(Wp1 + (long)tid * 512);
  const float4* b4 = (const float4*)buf;
  float acc = 0.f;
  for (int kx = 0; kx < 128; ++kx) {
    float4 w = w1[kx], c = b4[kx];
    acc += w.x*c.x + w.y*c.y + w.z*c.z + w.w*c.w;
  }
  float mid = fmaxf(acc + bp1[tid], 0.f);
  float contrib = mid * Wp2[tid];
  float tot = blk_sum(contrib, sm, tid);
  if (tid == 0) out[b] = tot + bp2[0];
}

extern "C" void kernel_launch(void* const* d_in, const int* in_sizes, int n_in,
                              void* d_out, int out_size, void* d_ws, size_t ws_size,
                              hipStream_t stream)
{
  const float* x     = (const float*)d_in[0];
  const float* Wi    = (const float*)d_in[1];
  const float* bi    = (const float*)d_in[2];
  const float* Wh    = (const float*)d_in[3];
  const float* bh    = (const float*)d_in[4];
  const float* g_in  = (const float*)d_in[5];
  const float* b_in  = (const float*)d_in[6];
  const float* g_hid = (const float*)d_in[7];
  const float* b_hid = (const float*)d_in[8];
  const float* g_cell= (const float*)d_in[9];
  const float* b_cell= (const float*)d_in[10];
  const float* hwWt  = (const float*)d_in[11];
  const float* hwbt  = (const float*)d_in[12];
  const float* hwWc  = (const float*)d_in[13];
  const float* hwbc  = (const float*)d_in[14];
  const float* hwWh  = (const float*)d_in[15];
  const float* hwbh  = (const float*)d_in[16];
  const float* Wq    = (const float*)d_in[17];
  const float* bq    = (const float*)d_in[18];
  const float* Wk    = (const float*)d_in[19];
  const float* bk    = (const float*)d_in[20];
  const float* Wv    = (const float*)d_in[21];
  const float* bv    = (const float*)d_in[22];
  const float* Wo    = (const float*)d_in[23];
  const float* bo    = (const float*)d_in[24];
  const float* att_g = (const float*)d_in[25];
  const float* att_b = (const float*)d_in[26];
  const float* on_g  = (const float*)d_in[27];
  const float* on_b  = (const float*)d_in[28];
  const float* Wp1   = (const float*)d_in[29];
  const float* bp1   = (const float*)d_in[30];
  const float* Wp2   = (const float*)d_in[31];
  const float* bp2   = (const float*)d_in[32];
  float* out = (float*)d_out;

  // ---- workspace layout (floats); never touches d_in ----
  const long SEQF = (long)Bn * Sn * Hn;      // 16,777,216
  const long WHPF = 2L * 256 * G4n;          // 1,048,576 (uint32 slots)
  const long ZBF  = 2L * 32 * 2048 * 2;      // 262,144 uint64 = 524,288 floats
  const long wsF  = (long)(ws_size / 4);

  float* ws   = (float*)d_ws;
  float* seq  = ws;                  // [B,S,H]
  float* hseq = seq  + SEQF;         // [B,S,H]
  uint32* WhP = (uint32*)(hseq + SEQF);  // [2][256][2048] packed f16 pairs
  uint64* zbuf = (uint64*)(hseq + SEQF + WHPF);  // [2][32][2048][2] tagged z words
  float* hst  = hseq + SEQF + WHPF + 2*ZBF;  // [64][512]
  float* cst  = hst  + 32768L;
  float* qlst = cst  + 32768L;       // [64][512]
  float* ctx  = qlst + 32768L;       // [64][512]
  float* qkh  = ctx  + 32768L;       // [64][8][512]
  float* qbk  = qkh  + 262144L;      // [64][8] (pad to 1024)
  float* uat  = qbk  + 1024L;        // [64][8][512]
  float* ipc  = uat  + 262144L;      // [TCH*64][2048]
  const long baseF = (ipc - ws);

  int TCH = 128;
  while (TCH > 16 && baseF + (long)TCH * 64 * 2048 > wsF) TCH >>= 1;

  wh_pack_k<<<dim3(16, 64, 2), 256, 0, stream>>>(Wh, WhP);
  init_zbuf_k<<<512, 512, 0, stream>>>(zbuf);

  const int NCH = Sn / TCH;
  const int MROWS = TCH * 64;
  const int NMCH = (Bn * Sn) / MROWS;

  for (int l = 0; l < 2; ++l) {
    const float* seqin = (l == 0) ? x : seq;
    init_hc_k<<<128, 256, 0, stream>>>(hst, cst);
    for (int c = 0; c < NCH; ++c) {
      const int s0 = c * TCH;
      gemm_ip_k<<<dim3(16, TCH/2), 256, 0, stream>>>(seqin, Wi + (long)l*G4n*Hn, bi + l*G4n, ipc, s0);
      ln_rows_k<<<TCH*64, 256, 0, stream>>>(ipc, g_in + l*G4n, b_in + l*G4n);
      lstm_seqz_k<<<256, 512, 0, stream>>>(WhP + (long)l*256*G4n, bh + l*G4n, ipc,
          g_hid + l*G4n, b_hid + l*G4n, g_cell + l*Hn, b_cell + l*Hn,
          hst, cst, hseq, zbuf, s0, TCH, l*Sn + s0 + 1);
    }
    // fused highway: 3 GEMMs + elementwise combine in one kernel, writes seq
    for (int mc = 0; mc < NMCH; ++mc) {
      const long m0 = (long)mc * MROWS;
      hw_fused_k<<<dim3(8, MROWS/128), 256, 0, stream>>>(
          hseq + m0*512,
          hwWt + (long)l*Hn*Hn, hwbt + l*Hn,
          hwWc + (long)l*Hn*Hn, hwbc + l*Hn,
          hwWh + (long)l*Hn*Hn, hwbh + l*Hn,
          seq + m0*512, (l == 0) ? 0 : 1);
    }
  }

  // attention on last query row, K/V never materialized
  gemm_m64_k<<<dim3(8, 1), 256, 0, stream>>>(seq + 511L*512, 512L*512, Wq, bq, qlst, 512, 512);
  qkh_k<<<dim3(8, 4), 256, 0, stream>>>(qlst, Wk, bk, qkh, qbk);
  attn2_k<<<dim3(64, 8), 256, 0, stream>>>(seq, qkh, qbk, uat);
  ctxv_k<<<64, 256, 0, stream>>>(uat, Wv, bv, ctx);
  head_k<<<64, 256, 0, stream>>>(ctx, Wo, bo, seq, att_g, att_b, on_g, on_b, Wp1, bp1, Wp2, bp2, out);
}

// Round 10
// 9066.536 us; speedup vs baseline: 1.1187x; 1.0129x over previous
//
#include <hip/hip_runtime.h>

#define EPS_LN 1e-5f

static constexpr int Bn  = 64;
static constexpr int Sn  = 512;
static constexpr int Hn  = 512;
static constexpr int G4n = 2048;

typedef unsigned int uint32;
typedef unsigned long long uint64;
typedef _Float16 h2v __attribute__((ext_vector_type(2)));

__device__ __forceinline__ float sigf(float x)     { return 1.0f / (1.0f + __expf(-x)); }
__device__ __forceinline__ float tanhfast(float x) { return 1.0f - 2.0f / (1.0f + __expf(2.0f * x)); }

// dot2: acc += w.lo*h.lo + w.hi*h.hi   (f16 inputs, fp32 accumulate)
__device__ __forceinline__ float dot2h(uint32 w, uint32 h, float acc) {
#if defined(__has_builtin)
#if __has_builtin(__builtin_amdgcn_fdot2)
  return __builtin_amdgcn_fdot2(__builtin_bit_cast(h2v, w), __builtin_bit_cast(h2v, h), acc, false);
#define DOT2_DONE 1
#endif
#endif
#ifndef DOT2_DONE
  h2v wv = __builtin_bit_cast(h2v, w);
  h2v hv = __builtin_bit_cast(h2v, h);
  return acc + (float)wv.x * (float)hv.x + (float)wv.y * (float)hv.y;
#endif
}
__device__ __forceinline__ uint32 packh2(float a, float b) {
  h2v v; v.x = (_Float16)a; v.y = (_Float16)b;
  return __builtin_bit_cast(uint32, v);
}

// ---- block reductions (256-thread kernels) ----
__device__ __forceinline__ float blk_sum(float v, float* sm, int tid) {
#pragma unroll
  for (int o = 32; o; o >>= 1) v += __shfl_down(v, o, 64);
  __syncthreads();
  if ((tid & 63) == 0) sm[tid >> 6] = v;
  __syncthreads();
  return sm[0] + sm[1] + sm[2] + sm[3];
}
__device__ __forceinline__ float blk_max(float v, float* sm, int tid) {
#pragma unroll
  for (int o = 32; o; o >>= 1) v = fmaxf(v, __shfl_down(v, o, 64));
  __syncthreads();
  if ((tid & 63) == 0) sm[tid >> 6] = v;
  __syncthreads();
  return fmaxf(fmaxf(sm[0], sm[1]), fmaxf(sm[2], sm[3]));
}

// ---- fused 4-value reduction across a 512-thread (8-wave) block ----
__device__ __forceinline__ void blk_sum4_w8(float& a, float& b, float& c, float& d,
                                            float* sm, int tid) {
#pragma unroll
  for (int o = 32; o; o >>= 1) {
    a += __shfl_down(a, o, 64);
    b += __shfl_down(b, o, 64);
    c += __shfl_down(c, o, 64);
    d += __shfl_down(d, o, 64);
  }
  __syncthreads();
  if ((tid & 63) == 0) {
    float4 v; v.x = a; v.y = b; v.z = c; v.w = d;
    *(float4*)&sm[(tid >> 6) * 4] = v;
  }
  __syncthreads();
  float ra = 0.f, rb = 0.f, rc = 0.f, rd = 0.f;
#pragma unroll
  for (int w = 0; w < 8; ++w) {
    float4 v = *(const float4*)&sm[w * 4];
    ra += v.x; rb += v.y; rc += v.z; rd += v.w;
  }
  a = ra; b = rb; c = rc; d = rd;
}

// ---- Wh pack: WhP[l][kp][n] = half2(Wh[l][n][2kp], Wh[l][n][2kp+1]) ----
__global__ __launch_bounds__(256) void wh_pack_k(
    const float* __restrict__ Wh, uint32* __restrict__ WhP)
{
  __shared__ float tile[32][33];
  const int l = blockIdx.z;
  const int k0 = blockIdx.x * 32;
  const int n0 = blockIdx.y * 32;
  const int row = threadIdx.x >> 5, col = threadIdx.x & 31;
  const float* src = Wh + (long)l * G4n * Hn;
  uint32* dst = WhP + (long)l * 256 * G4n;
#pragma unroll
  for (int rr = 0; rr < 4; ++rr) {
    int nn = row + rr * 8;
    tile[nn][col] = src[(long)(n0 + nn) * Hn + k0 + col];
  }
  __syncthreads();
#pragma unroll
  for (int rr = 0; rr < 2; ++rr) {
    int kpl = row + rr * 8;                     // 0..15
    int kp = (k0 >> 1) + kpl;
    dst[(long)kp * G4n + n0 + col] = packh2(tile[col][2*kpl], tile[col][2*kpl+1]);
  }
}

__global__ void init_zbuf_k(uint64* zbuf)
{
  long i = (long)blockIdx.x * 512 + threadIdx.x;
  zbuf[i] = 0ULL;
}

// ---- ip-chunk GEMM (f16-packed fdot2, K=16 slabs, global-load prefetch), ----
// time-major PACKED-F16 output: row r = t_local*64 + b, 1024 uint32/row
// (raw projection + bias, NO LayerNorm -- LN is applied inside lstm via ipstats)
__global__ __launch_bounds__(256) void gemm_ip_k(
    const float* __restrict__ A,       // [B,S,H]
    const float* __restrict__ Bw,      // [2048,512]
    const float* __restrict__ bias,
    uint32* __restrict__ C,            // [TCH*64][1024] f16 pairs
    int s0)
{
  __shared__ __align__(16) uint32 Ah[8][128];
  __shared__ __align__(16) uint32 Bh[8][128];
  const int tid = threadIdx.x;
  const long m0 = (long)blockIdx.y * 128;
  const long n0 = (long)blockIdx.x * 128;
  const int tx = tid & 15, ty = tid >> 4;
  const int lrow = tid >> 1;
  const int lc0  = (tid & 1) * 8;
  const int kb   = (tid & 1) * 4;
  float acc[8][8];
#pragma unroll
  for (int i = 0; i < 8; ++i)
#pragma unroll
    for (int j = 0; j < 8; ++j) acc[i][j] = 0.f;

  const long r  = m0 + lrow;
  const long b  = r & 63;
  const long sl = r >> 6;
  const float* Arow = A + (b * Sn + s0 + sl) * Hn;
  const float* Brow = Bw + (n0 + lrow) * 512L;

  float4 a0 = *(const float4*)(Arow + lc0);
  float4 a1 = *(const float4*)(Arow + lc0 + 4);
  float4 b0 = *(const float4*)(Brow + lc0);
  float4 b1 = *(const float4*)(Brow + lc0 + 4);

  for (int k0 = 0; k0 < 512; k0 += 16) {
    __syncthreads();
    Ah[kb+0][lrow] = packh2(a0.x, a0.y);
    Ah[kb+1][lrow] = packh2(a0.z, a0.w);
    Ah[kb+2][lrow] = packh2(a1.x, a1.y);
    Ah[kb+3][lrow] = packh2(a1.z, a1.w);
    Bh[kb+0][lrow] = packh2(b0.x, b0.y);
    Bh[kb+1][lrow] = packh2(b0.z, b0.w);
    Bh[kb+2][lrow] = packh2(b1.x, b1.y);
    Bh[kb+3][lrow] = packh2(b1.z, b1.w);
    __syncthreads();
    if (k0 + 16 < 512) {
      a0 = *(const float4*)(Arow + k0 + 16 + lc0);
      a1 = *(const float4*)(Arow + k0 + 16 + lc0 + 4);
      b0 = *(const float4*)(Brow + k0 + 16 + lc0);
      b1 = *(const float4*)(Brow + k0 + 16 + lc0 + 4);
    }
#pragma unroll
    for (int kp = 0; kp < 8; ++kp) {
      uint32 a8[8], b8[8];
      *(uint4*)&a8[0] = *(const uint4*)&Ah[kp][ty*8];
      *(uint4*)&a8[4] = *(const uint4*)&Ah[kp][ty*8+4];
      *(uint4*)&b8[0] = *(const uint4*)&Bh[kp][tx*8];
      *(uint4*)&b8[4] = *(const uint4*)&Bh[kp][tx*8+4];
#pragma unroll
      for (int i = 0; i < 8; ++i)
#pragma unroll
        for (int j = 0; j < 8; ++j) acc[i][j] = dot2h(a8[i], b8[j], acc[i][j]);
    }
  }
#pragma unroll
  for (int i = 0; i < 8; ++i) {
    long m = m0 + ty*8 + i;
    uint32* crow = C + m * 1024 + (n0 >> 1) + tx*4;
    const float* br = bias + n0 + tx*8;
    uint4 o;
    o.x = packh2(acc[i][0]+br[0], acc[i][1]+br[1]);
    o.y = packh2(acc[i][2]+br[2], acc[i][3]+br[3]);
    o.z = packh2(acc[i][4]+br[4], acc[i][5]+br[5]);
    o.w = packh2(acc[i][6]+br[6], acc[i][7]+br[7]);
    *(uint4*)crow = o;
  }
}

// ---- per-row (mean, rstd) over the f16 ipc rows of 2048 ----
__global__ __launch_bounds__(256) void ipstats_k(
    const uint32* __restrict__ X, float* __restrict__ st)
{
  const long row = blockIdx.x;
  const uint32* xr = X + row * 1024;
  const int tid = threadIdx.x;
  __shared__ float sm[4];
  uint4 w = *(const uint4*)(xr + tid*4);
  h2v a = __builtin_bit_cast(h2v, w.x);
  h2v b = __builtin_bit_cast(h2v, w.y);
  h2v c = __builtin_bit_cast(h2v, w.z);
  h2v d = __builtin_bit_cast(h2v, w.w);
  float v[8] = {(float)a.x,(float)a.y,(float)b.x,(float)b.y,
                (float)c.x,(float)c.y,(float)d.x,(float)d.y};
  float s1 = 0.f, s2 = 0.f;
#pragma unroll
  for (int i = 0; i < 8; ++i) { s1 += v[i]; s2 += v[i]*v[i]; }
  s1 = blk_sum(s1, sm, tid);
  s2 = blk_sum(s2, sm, tid);
  if (tid == 0) {
    const float mean = s1 * (1.f/2048.f);
    const float rstd = rsqrtf(s2 * (1.f/2048.f) - mean*mean + EPS_LN);
    st[row*2]     = mean;
    st[row*2 + 1] = rstd;
  }
}

// ---- fused highway with global-load prefetch: 3 projections of the same A rows
// (A staged once) + elementwise combine in the epilogue. Tile 128x64.
// out[m][n] = sigf(t1)*relu(t3) + sigf(t2)*A[m][n] (+ seq[m][n] if skip)
__global__ __launch_bounds__(256) void hw_fused_k(
    const float* __restrict__ A,       // hseq + m0*512 (lda = 512)
    const float* __restrict__ Wt, const float* __restrict__ bt,
    const float* __restrict__ Wc, const float* __restrict__ bc,
    const float* __restrict__ Wh3, const float* __restrict__ bh3,
    float* __restrict__ seqout,        // seq + m0*512
    int skip)
{
  __shared__ __align__(16) uint32 Ah[8][128];     // [k-pair][row]
  __shared__ __align__(16) uint32 Bh[3][8][68];   // [mat][k-pair][col] pad 68
  const int tid = threadIdx.x;
  const long m0 = (long)blockIdx.y * 128;
  const int n0 = blockIdx.x * 64;
  const int tx = tid & 7;            // col-group (8 cols each)
  const int ty = tid >> 3;           // row-group (4 rows each)
  const int lrow = tid >> 1;         // A staging row
  const int lc0  = (tid & 1) * 8;
  const int kbA  = (tid & 1) * 4;
  const int brow = tid >> 2;         // B staging col (0..63)
  const int bk0  = (tid & 3) * 4;
  const int kbB  = (tid & 3) * 2;

  float accT[4][8], accC[4][8], accH[4][8];
#pragma unroll
  for (int i = 0; i < 4; ++i)
#pragma unroll
    for (int j = 0; j < 8; ++j) { accT[i][j] = 0.f; accC[i][j] = 0.f; accH[i][j] = 0.f; }

  const float* Arow = A + (m0 + lrow) * 512;
  const long boff = (long)(n0 + brow) * 512 + bk0;

  float4 a0 = *(const float4*)(Arow + lc0);
  float4 a1 = *(const float4*)(Arow + lc0 + 4);
  float4 wt4 = *(const float4*)(Wt  + boff);
  float4 wc4 = *(const float4*)(Wc  + boff);
  float4 wh4 = *(const float4*)(Wh3 + boff);

  for (int k0 = 0; k0 < 512; k0 += 16) {
    __syncthreads();
    Ah[kbA+0][lrow] = packh2(a0.x, a0.y);
    Ah[kbA+1][lrow] = packh2(a0.z, a0.w);
    Ah[kbA+2][lrow] = packh2(a1.x, a1.y);
    Ah[kbA+3][lrow] = packh2(a1.z, a1.w);
    Bh[0][kbB+0][brow] = packh2(wt4.x, wt4.y);
    Bh[0][kbB+1][brow] = packh2(wt4.z, wt4.w);
    Bh[1][kbB+0][brow] = packh2(wc4.x, wc4.y);
    Bh[1][kbB+1][brow] = packh2(wc4.z, wc4.w);
    Bh[2][kbB+0][brow] = packh2(wh4.x, wh4.y);
    Bh[2][kbB+1][brow] = packh2(wh4.z, wh4.w);
    __syncthreads();
    if (k0 + 16 < 512) {
      a0 = *(const float4*)(Arow + k0 + 16 + lc0);
      a1 = *(const float4*)(Arow + k0 + 16 + lc0 + 4);
      wt4 = *(const float4*)(Wt  + boff + k0 + 16);
      wc4 = *(const float4*)(Wc  + boff + k0 + 16);
      wh4 = *(const float4*)(Wh3 + boff + k0 + 16);
    }
#pragma unroll
    for (int kp = 0; kp < 8; ++kp) {
      uint32 a4[4];
      *(uint4*)&a4[0] = *(const uint4*)&Ah[kp][ty*4];
      {
        uint32 b8[8];
        *(uint4*)&b8[0] = *(const uint4*)&Bh[0][kp][tx*8];
        *(uint4*)&b8[4] = *(const uint4*)&Bh[0][kp][tx*8+4];
#pragma unroll
        for (int i = 0; i < 4; ++i)
#pragma unroll
          for (int j = 0; j < 8; ++j) accT[i][j] = dot2h(a4[i], b8[j], accT[i][j]);
      }
      {
        uint32 b8[8];
        *(uint4*)&b8[0] = *(const uint4*)&Bh[1][kp][tx*8];
        *(uint4*)&b8[4] = *(const uint4*)&Bh[1][kp][tx*8+4];
#pragma unroll
        for (int i = 0; i < 4; ++i)
#pragma unroll
          for (int j = 0; j < 8; ++j) accC[i][j] = dot2h(a4[i], b8[j], accC[i][j]);
      }
      {
        uint32 b8[8];
        *(uint4*)&b8[0] = *(const uint4*)&Bh[2][kp][tx*8];
        *(uint4*)&b8[4] = *(const uint4*)&Bh[2][kp][tx*8+4];
#pragma unroll
        for (int i = 0; i < 4; ++i)
#pragma unroll
          for (int j = 0; j < 8; ++j) accH[i][j] = dot2h(a4[i], b8[j], accH[i][j]);
      }
    }
  }

  // epilogue: combine + write seq
  float btr[8], bcr[8], bhr[8];
#pragma unroll
  for (int j = 0; j < 8; ++j) {
    btr[j] = bt[n0 + tx*8 + j];
    bcr[j] = bc[n0 + tx*8 + j];
    bhr[j] = bh3[n0 + tx*8 + j];
  }
#pragma unroll
  for (int i = 0; i < 4; ++i) {
    const long m = m0 + ty*4 + i;
    const float* hrow = A + m * 512 + n0 + tx*8;
    float* srow = seqout + m * 512 + n0 + tx*8;
    float4 h0 = *(const float4*)hrow;
    float4 h1 = *(const float4*)(hrow + 4);
    float hv[8] = {h0.x,h0.y,h0.z,h0.w,h1.x,h1.y,h1.z,h1.w};
    float sv[8] = {0,0,0,0,0,0,0,0};
    if (skip) {
      float4 s0 = *(const float4*)srow;
      float4 s1 = *(const float4*)(srow + 4);
      sv[0]=s0.x; sv[1]=s0.y; sv[2]=s0.z; sv[3]=s0.w;
      sv[4]=s1.x; sv[5]=s1.y; sv[6]=s1.z; sv[7]=s1.w;
    }
    float o[8];
#pragma unroll
    for (int j = 0; j < 8; ++j) {
      const float t1 = accT[i][j] + btr[j];
      const float t2 = accC[i][j] + bcr[j];
      const float t3 = accH[i][j] + bhr[j];
      o[j] = sigf(t1) * fmaxf(t3, 0.f) + sigf(t2) * hv[j] + sv[j];
    }
    float4 o0, o1;
    o0.x=o[0]; o0.y=o[1]; o0.z=o[2]; o0.w=o[3];
    o1.x=o[4]; o1.y=o[5]; o1.z=o[6]; o1.w=o[7];
    *(float4*)srow = o0; *(float4*)(srow + 4) = o1;
  }
}

// ---- M=64 GEMM (used for q projection) ----
__global__ __launch_bounds__(256) void gemm_m64_k(
    const float* __restrict__ A, long lda,
    const float* __restrict__ Bw,
    const float* __restrict__ bias,
    float* __restrict__ P,
    int N, int K)
{
  __shared__ float As[64][64];
  __shared__ float Bs[64][64];
  const int tid = threadIdx.x;
  const int n0 = blockIdx.x * 64;
  const int kc = blockIdx.y;
  const int Kc = K / gridDim.y;
  const int tx = tid & 15, ty = tid >> 4;
  const int row = tid >> 2, q = tid & 3;
  float acc[4][4];
#pragma unroll
  for (int i = 0; i < 4; ++i)
#pragma unroll
    for (int j = 0; j < 4; ++j) acc[i][j] = 0.f;

  for (int k0 = kc * Kc; k0 < kc * Kc + Kc; k0 += 64) {
    float4 a[4], b[4];
#pragma unroll
    for (int c = 0; c < 4; ++c) {
      a[c] = *(const float4*)(A  + (long)row * lda       + k0 + q*16 + c*4);
      b[c] = *(const float4*)(Bw + (long)(n0 + row) * K  + k0 + q*16 + c*4);
    }
    __syncthreads();
#pragma unroll
    for (int c = 0; c < 4; ++c) {
      int kb = q*16 + c*4;
      As[kb+0][row]=a[c].x; As[kb+1][row]=a[c].y; As[kb+2][row]=a[c].z; As[kb+3][row]=a[c].w;
      Bs[kb+0][row]=b[c].x; Bs[kb+1][row]=b[c].y; Bs[kb+2][row]=b[c].z; Bs[kb+3][row]=b[c].w;
    }
    __syncthreads();
#pragma unroll
    for (int kk = 0; kk < 64; ++kk) {
      float4 av = *(const float4*)&As[kk][ty*4];
      float4 bv = *(const float4*)&Bs[kk][tx*4];
      float am[4] = {av.x, av.y, av.z, av.w};
      float bm[4] = {bv.x, bv.y, bv.z, bv.w};
#pragma unroll
      for (int i = 0; i < 4; ++i)
#pragma unroll
        for (int j = 0; j < 4; ++j) acc[i][j] += am[i] * bm[j];
    }
  }
#pragma unroll
  for (int i = 0; i < 4; ++i) {
    int m = ty*4 + i;
    float* pr = P + ((long)kc * 64 + m) * N + n0 + tx*4;
#pragma unroll
    for (int j = 0; j < 4; ++j) {
      float bb = bias ? bias[n0 + tx*4 + j] : 0.f;
      pr[j] = acc[i][j] + bb;
    }
  }
}

// ---- persistent LSTM recurrence: n-split + tagged-word single-round exchange ----
// (exchange/GEMV/LDS/publish machinery byte-identical to rounds 5-9, verified
//  at ~868us/128 steps, 0 bank conflicts. Publish pattern myword=kq*512+tid gives
//  contiguous full-line wave stores -- DO NOT change it. Packed-h LDS split lo/hi
//  at +132 words keeps broadcast reads on disjoint bank quads.
//  NEW vs round 9: ip is read from PACKED-F16 ipc with LayerNorm applied on the
//  fly using precomputed per-row (mean,rstd) -- eliminates the ln_rows pass.
//  g_in/b_in per-thread values hoisted to 8 loop-invariant VGPRs.)
__global__ __launch_bounds__(512, 2) void lstm_seqz_k(
    const uint32* __restrict__ WhP,   // [256 kp][2048 n] this layer (f16 pairs)
    const float* __restrict__ bh,
    const uint32* __restrict__ ipc,   // [TCH*64][1024] raw ip (f16 pairs, +bias)
    const float* __restrict__ ipstats,// [TCH*64][2] (mean, rstd)
    const float* __restrict__ g_in, const float* __restrict__ b_in,
    const float* __restrict__ g_hid, const float* __restrict__ b_hid,
    const float* __restrict__ g_cell, const float* __restrict__ b_cell,
    float* __restrict__ hst, float* __restrict__ cst,  // [64][512]
    float* __restrict__ hseq,         // [B,S,H]
    uint64* __restrict__ zbuf,        // [2 parity][32 g][2048 row][2 b] tagged words
    int t0, int nsteps, int gbase)    // gbase >= 1, monotonic over the whole run
{
  const int blk = blockIdx.x;
  const int g   = blk & 31;
  const int kq  = blk >> 5;
  const int tid = threadIdx.x;
  const int b0  = g*2, b1 = g*2 + 1;
  const int r   = tid >> 1;          // row within our 256-row slice
  const int kh  = tid & 1;           // k-half (0: k<256, 1: k>=256)
  // packed h pairs: lo half [0..127], hi half at +132 (bank-quad disjoint from lo)
  __shared__ __align__(16) uint32 hp0[264];
  __shared__ __align__(16) uint32 hp1[264];
  __shared__ float sm[32];

  // register-resident weights: rows kq*256+r, k-pairs kh*128 + [0,128)
  uint4 wreg[32];
  {
    const uint32* base = WhP + (long)(kh * 128) * 2048 + (kq*256 + r);
#pragma unroll
    for (int i = 0; i < 32; ++i) {
      wreg[i].x = base[(long)(4*i + 0) * 2048];
      wreg[i].y = base[(long)(4*i + 1) * 2048];
      wreg[i].z = base[(long)(4*i + 2) * 2048];
      wreg[i].w = base[(long)(4*i + 3) * 2048];
    }
  }

  // per-unit params/state: thread owns unit tid (both batches)
  float bhr[4], ghr[4], bhir[4], ginr[4], binr[4];
#pragma unroll
  for (int q = 0; q < 4; ++q) {
    bhr[q]  = bh[q*512 + tid];
    ghr[q]  = g_hid[q*512 + tid];
    bhir[q] = b_hid[q*512 + tid];
    ginr[q] = g_in[q*512 + tid];
    binr[q] = b_in[q*512 + tid];
  }
  const float gcv = g_cell[tid];
  const float bcv = b_cell[tid];
  float c0 = cst[b0*512 + tid];
  float c1 = cst[b1*512 + tid];
  float h0 = hst[b0*512 + tid];
  float h1 = hst[b1*512 + tid];

  // initial full-h pack into LDS (lo at j, hi at j+4 for j>=128)
  {
    const float p0 = __shfl_xor(h0, 1, 64);
    const float p1 = __shfl_xor(h1, 1, 64);
    if (!(tid & 1)) {
      const int j = tid >> 1;
      const int jj = (j < 128) ? j : j + 4;
      hp0[jj] = packh2(h0, p0);
      hp1[jj] = packh2(h1, p1);
    }
  }
  __syncthreads();

  const long myword = (long)(kq*256 + r) * 2 + kh;   // = kq*512 + tid (contiguous)
  const uint32* hb0 = hp0 + kh * 132;
  const uint32* hb1 = hp1 + kh * 132;

  for (int ts = 0; ts < nsteps; ++ts) {
    const int gstep = gbase + ts;
    const uint32 tagw = (uint32)gstep;
    uint64* zp = zbuf + (long)(gstep & 1) * 131072 + (long)g * 4096;

    // ip: packed-f16 load + on-the-fly LN (stats broadcast; hide under GEMV)
    const uint32* iprow0 = ipc + ((long)ts * 64 + b0) * 1024 + (tid >> 1);
    const uint32* iprow1 = ipc + ((long)ts * 64 + b1) * 1024 + (tid >> 1);
    const float2 st0 = *(const float2*)(ipstats + ((long)ts * 64 + b0) * 2);
    const float2 st1 = *(const float2*)(ipstats + ((long)ts * 64 + b1) * 2);
    float ip0[4], ip1[4];
#pragma unroll
    for (int q = 0; q < 4; ++q) {
      h2v v0 = __builtin_bit_cast(h2v, iprow0[q*256]);
      h2v v1 = __builtin_bit_cast(h2v, iprow1[q*256]);
      const float r0 = kh ? (float)v0.y : (float)v0.x;
      const float r1 = kh ? (float)v1.y : (float)v1.x;
      ip0[q] = (r0 - st0.x) * st0.y * ginr[q] + binr[q];
      ip1[q] = (r1 - st1.x) * st1.y * ginr[q] + binr[q];
    }

    // GEMV: full-k half for row kq*256+r, both batches (h via LDS broadcast)
    float a0 = 0.f, a1 = 0.f;
#pragma unroll
    for (int i = 0; i < 32; ++i) {
      const uint4 w  = wreg[i];
      const uint4 hv0 = *(const uint4*)&hb0[4*i];
      const uint4 hv1 = *(const uint4*)&hb1[4*i];
      a0 = dot2h(w.x, hv0.x, a0); a0 = dot2h(w.y, hv0.y, a0);
      a0 = dot2h(w.z, hv0.z, a0); a0 = dot2h(w.w, hv0.w, a0);
      a1 = dot2h(w.x, hv1.x, a1); a1 = dot2h(w.y, hv1.y, a1);
      a1 = dot2h(w.z, hv1.z, a1); a1 = dot2h(w.w, hv1.w, a1);
    }
    // combine k-halves within the lane pair
    a0 += __shfl_xor(a0, 1, 64);
    a1 += __shfl_xor(a1, 1, 64);

    // publish one tagged word (fire-and-forget; tag rides with payload)
    {
      const float zval = kh ? a1 : a0;
      const uint64 w = ((uint64)tagw << 32) | (uint64)__builtin_bit_cast(uint32, zval);
      __hip_atomic_store(zp + myword, w, __ATOMIC_RELAXED, __HIP_MEMORY_SCOPE_AGENT);
    }

    // gather the 8 tagged words for unit tid: rows {tid,512+tid,1024+tid,1536+tid} x {b0,b1}
    float z0[4], z1[4];
    {
      uint64 v0[4], v1[4];
      int pend = 0xff;
      while (pend) {
#pragma unroll
        for (int q = 0; q < 4; ++q) {
          const long base = (long)(q*512 + tid) * 2;
          if (pend & (1 << q)) {
            uint64 w = __hip_atomic_load(zp + base, __ATOMIC_RELAXED, __HIP_MEMORY_SCOPE_AGENT);
            if ((uint32)(w >> 32) == tagw) { v0[q] = w; pend &= ~(1 << q); }
          }
          if (pend & (16 << q)) {
            uint64 w = __hip_atomic_load(zp + base + 1, __ATOMIC_RELAXED, __HIP_MEMORY_SCOPE_AGENT);
            if ((uint32)(w >> 32) == tagw) { v1[q] = w; pend &= ~(16 << q); }
          }
        }
        if (pend) __builtin_amdgcn_s_sleep(2);
      }
#pragma unroll
      for (int q = 0; q < 4; ++q) {
        z0[q] = __builtin_bit_cast(float, (uint32)v0[q]) + bhr[q];
        z1[q] = __builtin_bit_cast(float, (uint32)v1[q]) + bhr[q];
      }
    }

    // LN1 over 2048, both batches in one reduction pass
    float s10 = z0[0]+z0[1]+z0[2]+z0[3];
    float s20 = z0[0]*z0[0] + z0[1]*z0[1] + z0[2]*z0[2] + z0[3]*z0[3];
    float s11 = z1[0]+z1[1]+z1[2]+z1[3];
    float s21 = z1[0]*z1[0] + z1[1]*z1[1] + z1[2]*z1[2] + z1[3]*z1[3];
    blk_sum4_w8(s10, s20, s11, s21, sm, tid);
    const float m0 = s10 * (1.f/2048.f);
    const float r0 = rsqrtf(s20 * (1.f/2048.f) - m0*m0 + EPS_LN);
    const float m1 = s11 * (1.f/2048.f);
    const float r1 = rsqrtf(s21 * (1.f/2048.f) - m1*m1 + EPS_LN);

    const float gi0 = ip0[0] + (z0[0] - m0) * r0 * ghr[0] + bhir[0];
    const float gf0 = ip0[1] + (z0[1] - m0) * r0 * ghr[1] + bhir[1];
    const float gg0 = ip0[2] + (z0[2] - m0) * r0 * ghr[2] + bhir[2];
    const float go0 = ip0[3] + (z0[3] - m0) * r0 * ghr[3] + bhir[3];
    const float gi1 = ip1[0] + (z1[0] - m1) * r1 * ghr[0] + bhir[0];
    const float gf1 = ip1[1] + (z1[1] - m1) * r1 * ghr[1] + bhir[1];
    const float gg1 = ip1[2] + (z1[2] - m1) * r1 * ghr[2] + bhir[2];
    const float go1 = ip1[3] + (z1[3] - m1) * r1 * ghr[3] + bhir[3];

    c0 = sigf(gf0) * c0 + sigf(gi0) * tanhfast(gg0);
    c1 = sigf(gf1) * c1 + sigf(gi1) * tanhfast(gg1);

    // LN2 over 512 cells, both batches in one pass
    float t10 = c0, t20 = c0*c0, t11 = c1, t21 = c1*c1;
    blk_sum4_w8(t10, t20, t11, t21, sm, tid);
    const float n0 = t10 * (1.f/512.f);
    const float q0r = rsqrtf(t20 * (1.f/512.f) - n0*n0 + EPS_LN);
    const float n1 = t11 * (1.f/512.f);
    const float q1r = rsqrtf(t21 * (1.f/512.f) - n1*n1 + EPS_LN);
    h0 = sigf(go0) * tanhfast((c0 - n0) * q0r * gcv + bcv);
    h1 = sigf(go1) * tanhfast((c1 - n1) * q1r * gcv + bcv);

    if (kq == 0) {
      hseq[((long)b0 * Sn + t0 + ts) * Hn + tid] = h0;
      hseq[((long)b1 * Sn + t0 + ts) * Hn + tid] = h1;
    }

    // repack full h into LDS for next step (blk_sum4 already synced past GEMV reads)
    const float p0 = __shfl_xor(h0, 1, 64);
    const float p1 = __shfl_xor(h1, 1, 64);
    if (!(tid & 1)) {
      const int j = tid >> 1;
      const int jj = (j < 128) ? j : j + 4;
      hp0[jj] = packh2(h0, p0);
      hp1[jj] = packh2(h1, p1);
    }
    __syncthreads();
  }
  if (kq == 0) {
    hst[b0*512 + tid] = h0; hst[b1*512 + tid] = h1;
    cst[b0*512 + tid] = c0; cst[b1*512 + tid] = c1;
  }
}

__global__ void init_hc_k(float* h, float* c)
{
  int i = blockIdx.x * 256 + threadIdx.x;
  h[i] = 0.f; c[i] = 0.f;
}

// ---- qkh[b][hd][:] = sum_{j in head} q[b, hd*64+j] * Wk[hd*64+j, :]; qbk = q.bk ----
__global__ __launch_bounds__(256) void qkh_k(
    const float* __restrict__ qlst, const float* __restrict__ Wk,
    const float* __restrict__ bk,
    float* __restrict__ qkh, float* __restrict__ qbk)
{
  const int hd = blockIdx.x, cg = blockIdx.y;
  const int b = threadIdx.x & 63, sc = threadIdx.x >> 6;
  const int col0 = cg * 128 + sc * 32;
  float qreg[64];
  const float* qp = qlst + b*512 + hd*64;
#pragma unroll
  for (int j4 = 0; j4 < 16; ++j4) {
    float4 v = *(const float4*)(qp + j4*4);
    qreg[j4*4+0]=v.x; qreg[j4*4+1]=v.y; qreg[j4*4+2]=v.z; qreg[j4*4+3]=v.w;
  }
  float acc[32];
#pragma unroll
  for (int c = 0; c < 32; ++c) acc[c] = 0.f;
  for (int j = 0; j < 64; ++j) {
    float qv = qreg[j];
    const float* wr = Wk + (long)(hd*64 + j)*512 + col0;
#pragma unroll
    for (int c4 = 0; c4 < 8; ++c4) {
      float4 w = *(const float4*)(wr + c4*4);
      acc[c4*4+0] = __builtin_fmaf(qv, w.x, acc[c4*4+0]);
      acc[c4*4+1] = __builtin_fmaf(qv, w.y, acc[c4*4+1]);
      acc[c4*4+2] = __builtin_fmaf(qv, w.z, acc[c4*4+2]);
      acc[c4*4+3] = __builtin_fmaf(qv, w.w, acc[c4*4+3]);
    }
  }
  float* op = qkh + ((long)b*8 + hd)*512 + col0;
#pragma unroll
  for (int c4 = 0; c4 < 8; ++c4) {
    float4 o;
    o.x = acc[c4*4+0]; o.y = acc[c4*4+1]; o.z = acc[c4*4+2]; o.w = acc[c4*4+3];
    *(float4*)(op + c4*4) = o;
  }
  if (cg == 0 && sc == 0) {
    float s = 0.f;
    for (int j = 0; j < 64; ++j) s += qreg[j] * bk[hd*64 + j];
    qbk[b*8 + hd] = s;
  }
}

// ---- fused last-row attention ----
__global__ __launch_bounds__(256) void attn2_k(
    const float* __restrict__ seq,   // [B,S,H]
    const float* __restrict__ qkh,   // [64][8][512]
    const float* __restrict__ qbk,   // [64][8]
    float* __restrict__ u)           // [64][8][512]
{
  const int b = blockIdx.x, hd = blockIdx.y, tid = threadIdx.x;
  __shared__ __align__(16) float qk[512];
  __shared__ float p[512];
  __shared__ float sm[4];
  qk[tid]       = qkh[((long)b*8 + hd)*512 + tid];
  qk[tid + 256] = qkh[((long)b*8 + hd)*512 + tid + 256];
  __syncthreads();
  const float bias = qbk[b*8 + hd];

  float loc[2]; float mx = -3.0e38f;
#pragma unroll
  for (int v = 0; v < 2; ++v) {
    int s = tid + v*256;
    const float4* sr = (const float4*)(seq + ((long)b*512 + s)*512);
    const float4* qv4 = (const float4*)qk;
    float d = 0.f;
    for (int k4 = 0; k4 < 128; ++k4) {
      float4 sv = sr[k4], qv = qv4[k4];
      d += sv.x*qv.x + sv.y*qv.y + sv.z*qv.z + sv.w*qv.w;
    }
    d = (d + bias) * 0.125f;
    loc[v] = d; mx = fmaxf(mx, d);
  }
  const float M = blk_max(mx, sm, tid);
  float sum = 0.f;
#pragma unroll
  for (int v = 0; v < 2; ++v) {
    int s = tid + v*256;
    float e = __expf(loc[v] - M);
    p[s] = e; sum += e;
  }
  const float SM = blk_sum(sum, sm, tid);
  const float inv = 1.f / SM;

  float u0 = 0.f, u1 = 0.f;
  for (int s = 0; s < 512; ++s) {
    float ps = p[s];
    const float* srow = seq + ((long)b*512 + s)*512;
    u0 = __builtin_fmaf(ps, srow[tid], u0);
    u1 = __builtin_fmaf(ps, srow[tid + 256], u1);
  }
  u[((long)b*8 + hd)*512 + tid]       = u0 * inv;
  u[((long)b*8 + hd)*512 + tid + 256] = u1 * inv;
}

// ---- ctx[b][n] = u[b][hd(n)][:] . Wv[n][:] + bv[n] ----
__global__ __launch_bounds__(256) void ctxv_k(
    const float* __restrict__ u, const float* __restrict__ Wv,
    const float* __restrict__ bv, float* __restrict__ ctx)
{
  const int b = blockIdx.x, tid = threadIdx.x;
  __shared__ __align__(16) float ul[8*512];
  for (int i = tid; i < 4096; i += 256) ul[i] = u[(long)b*4096 + i];
  __syncthreads();
#pragma unroll
  for (int v = 0; v < 2; ++v) {
    int n = tid + v*256;
    int hd = n >> 6;
    const float4* wr = (const float4*)(Wv + (long)n*512);
    const float4* uv = (const float4*)&ul[hd*512];
    float acc = 0.f;
    for (int k4 = 0; k4 < 128; ++k4) {
      float4 w = wr[k4], x = uv[k4];
      acc += w.x*x.x + w.y*x.y + w.z*x.z + w.w*x.w;
    }
    ctx[b*512 + n] = acc + bv[n];
  }
}

// ---- output head ----
__global__ __launch_bounds__(256) void head_k(
    const float* __restrict__ ctx,
    const float* __restrict__ Wo, const float* __restrict__ bo,
    const float* __restrict__ seq,
    const float* __restrict__ att_g, const float* __restrict__ att_b,
    const float* __restrict__ on_g, const float* __restrict__ on_b,
    const float* __restrict__ Wp1, const float* __restrict__ bp1,
    const float* __restrict__ Wp2, const float* __restrict__ bp2,
    float* __restrict__ out)
{
  const int b = blockIdx.x, tid = threadIdx.x;
  __shared__ __align__(16) float cs[512];
  __shared__ __align__(16) float buf[512];
  __shared__ float sm[4];
  cs[tid]       = ctx[b*512 + tid];
  cs[tid + 256] = ctx[b*512 + tid + 256];
  __syncthreads();

  const float* srow = seq + ((long)b*512 + 511) * 512;
  float o[2];
#pragma unroll
  for (int v = 0; v < 2; ++v) {
    int j = tid + v*256;
    const float4* w4 = (const float4*)(Wo + (long)j * 512);
    const float4* c4 = (const float4*)cs;
    float acc = 0.f;
    for (int kx = 0; kx < 128; ++kx) {
      float4 w = w4[kx], c = c4[kx];
      acc += w.x*c.x + w.y*c.y + w.z*c.z + w.w*c.w;
    }
    o[v] = acc + bo[j] + srow[j];
  }
  float s1 = o[0] + o[1], s2 = o[0]*o[0] + o[1]*o[1];
  s1 = blk_sum(s1, sm, tid); s2 = blk_sum(s2, sm, tid);
  float m1 = s1 * (1.f/512.f);
  float r1 = rsqrtf(s2 * (1.f/512.f) - m1*m1 + EPS_LN);
  float a[2];
#pragma unroll
  for (int v = 0; v < 2; ++v) {
    int j = tid + v*256;
    a[v] = (o[v] - m1) * r1 * att_g[j] + att_b[j];
  }
  s1 = a[0] + a[1]; s2 = a[0]*a[0] + a[1]*a[1];
  s1 = blk_sum(s1, sm, tid); s2 = blk_sum(s2, sm, tid);
  float m2 = s1 * (1.f/512.f);
  float r2 = rsqrtf(s2 * (1.f/512.f) - m2*m2 + EPS_LN);
#pragma unroll
  for (int v = 0; v < 2; ++v) {
    int j = tid + v*256;
    buf[j] = (a[v] - m2) * r2 * on_g[j] + on_b[j];
  }
  __syncthreads();

  const float4* w1 = (const float4*)(Wp1 + (long)tid * 512);
  const float4* b4 = (const float4*)buf;
  float acc = 0.f;
  for (int kx = 0; kx < 128; ++kx) {
    float4 w = w1[kx], c = b4[kx];
    acc += w.x*c.x + w.y*c.y + w.z*c.z + w.w*c.w;
  }
  float mid = fmaxf(acc + bp1[tid], 0.f);
  float contrib = mid * Wp2[tid];
  float tot = blk_sum(contrib, sm, tid);
  if (tid == 0) out[b] = tot + bp2[0];
}

extern "C" void kernel_launch(void* const* d_in, const int* in_sizes, int n_in,
                              void* d_out, int out_size, void* d_ws, size_t ws_size,
                              hipStream_t stream)
{
  const float* x     = (const float*)d_in[0];
  const float* Wi    = (const float*)d_in[1];
  const float* bi    = (const float*)d_in[2];
  const float* Wh    = (const float*)d_in[3];
  const float* bh    = (const float*)d_in[4];
  const float* g_in  = (const float*)d_in[5];
  const float* b_in  = (const float*)d_in[6];
  const float* g_hid = (const float*)d_in[7];
  const float* b_hid = (const float*)d_in[8];
  const float* g_cell= (const float*)d_in[9];
  const float* b_cell= (const float*)d_in[10];
  const float* hwWt  = (const float*)d_in[11];
  const float* hwbt  = (const float*)d_in[12];
  const float* hwWc  = (const float*)d_in[13];
  const float* hwbc  = (const float*)d_in[14];
  const float* hwWh  = (const float*)d_in[15];
  const float* hwbh  = (const float*)d_in[16];
  const float* Wq    = (const float*)d_in[17];
  const float* bq    = (const float*)d_in[18];
  const float* Wk    = (const float*)d_in[19];
  const float* bk    = (const float*)d_in[20];
  const float* Wv    = (const float*)d_in[21];
  const float* bv    = (const float*)d_in[22];
  const float* Wo    = (const float*)d_in[23];
  const float* bo    = (const float*)d_in[24];
  const float* att_g = (const float*)d_in[25];
  const float* att_b = (const float*)d_in[26];
  const float* on_g  = (const float*)d_in[27];
  const float* on_b  = (const float*)d_in[28];
  const float* Wp1   = (const float*)d_in[29];
  const float* bp1   = (const float*)d_in[30];
  const float* Wp2   = (const float*)d_in[31];
  const float* bp2   = (const float*)d_in[32];
  float* out = (float*)d_out;

  // ---- workspace layout (floats); never touches d_in ----
  const long SEQF = (long)Bn * Sn * Hn;      // 16,777,216
  const long WHPF = 2L * 256 * G4n;          // 1,048,576 (uint32 slots)
  const long ZBF  = 2L * 32 * 2048 * 2;      // 262,144 uint64 = 524,288 floats
  const long wsF  = (long)(ws_size / 4);

  float* ws   = (float*)d_ws;
  float* seq  = ws;                  // [B,S,H]
  float* hseq = seq  + SEQF;         // [B,S,H]
  uint32* WhP = (uint32*)(hseq + SEQF);  // [2][256][2048] packed f16 pairs
  uint64* zbuf = (uint64*)(hseq + SEQF + WHPF);  // [2][32][2048][2] tagged z words
  float* hst  = hseq + SEQF + WHPF + 2*ZBF;  // [64][512]
  float* cst  = hst  + 32768L;
  float* qlst = cst  + 32768L;       // [64][512]
  float* ctx  = qlst + 32768L;       // [64][512]
  float* qkh  = ctx  + 32768L;       // [64][8][512]
  float* qbk  = qkh  + 262144L;      // [64][8] (pad to 1024)
  float* uat  = qbk  + 1024L;        // [64][8][512]
  float* ipstats = uat + 262144L;    // [16384][2] (pad to 32768)
  float* ipcF = ipstats + 32768L;    // [TCH*64][1024 uint32] f16 ip pairs
  uint32* ipc = (uint32*)ipcF;
  const long baseF = (ipcF - ws);

  // f16 ipc: TCH=256 costs the same bytes TCH=128 cost in fp32 -> fits
  int TCH = 256;
  while (TCH > 16 && baseF + (long)TCH * 64 * 1024 > wsF) TCH >>= 1;

  wh_pack_k<<<dim3(16, 64, 2), 256, 0, stream>>>(Wh, WhP);
  init_zbuf_k<<<512, 512, 0, stream>>>(zbuf);

  const int NCH = Sn / TCH;
  const int MROWS = TCH * 64;
  const int NMCH = (Bn * Sn) / MROWS;

  for (int l = 0; l < 2; ++l) {
    const float* seqin = (l == 0) ? x : seq;
    init_hc_k<<<128, 256, 0, stream>>>(hst, cst);
    for (int c = 0; c < NCH; ++c) {
      const int s0 = c * TCH;
      gemm_ip_k<<<dim3(16, TCH/2), 256, 0, stream>>>(seqin, Wi + (long)l*G4n*Hn, bi + l*G4n, ipc, s0);
      ipstats_k<<<TCH*64, 256, 0, stream>>>(ipc, ipstats);
      lstm_seqz_k<<<256, 512, 0, stream>>>(WhP + (long)l*256*G4n, bh + l*G4n, ipc, ipstats,
          g_in + l*G4n, b_in + l*G4n,
          g_hid + l*G4n, b_hid + l*G4n, g_cell + l*Hn, b_cell + l*Hn,
          hst, cst, hseq, zbuf, s0, TCH, l*Sn + s0 + 1);
    }
    // fused highway: 3 GEMMs + elementwise combine in one kernel, writes seq
    for (int mc = 0; mc < NMCH; ++mc) {
      const long m0 = (long)mc * MROWS;
      hw_fused_k<<<dim3(8, MROWS/128), 256, 0, stream>>>(
          hseq + m0*512,
          hwWt + (long)l*Hn*Hn, hwbt + l*Hn,
          hwWc + (long)l*Hn*Hn, hwbc + l*Hn,
          hwWh + (long)l*Hn*Hn, hwbh + l*Hn,
          seq + m0*512, (l == 0) ? 0 : 1);
    }
  }

  // attention on last query row, K/V never materialized
  gemm_m64_k<<<dim3(8, 1), 256, 0, stream>>>(seq + 511L*512, 512L*512, Wq, bq, qlst, 512, 512);
  qkh_k<<<dim3(8, 4), 256, 0, stream>>>(qlst, Wk, bk, qkh, qbk);
  attn2_k<<<dim3(64, 8), 256, 0, stream>>>(seq, qkh, qbk, uat);
  ctxv_k<<<64, 256, 0, stream>>>(uat, Wv, bv, ctx);
  head_k<<<64, 256, 0, stream>>>(ctx, Wo, bo, seq, att_g, att_b, on_g, on_b, Wp1, bp1, Wp2, bp2, out);
}

// Round 11
// 8463.476 us; speedup vs baseline: 1.1984x; 1.0713x over previous
//
#include <hip/hip_runtime.h>

#define EPS_LN 1e-5f

static constexpr int Bn  = 64;
static constexpr int Sn  = 512;
static constexpr int Hn  = 512;
static constexpr int G4n = 2048;

typedef unsigned int uint32;
typedef unsigned long long uint64;
typedef _Float16 h2v __attribute__((ext_vector_type(2)));
typedef _Float16 h8v __attribute__((ext_vector_type(8)));
typedef float f4v __attribute__((ext_vector_type(4)));

__device__ __forceinline__ float sigf(float x)     { return 1.0f / (1.0f + __expf(-x)); }
__device__ __forceinline__ float tanhfast(float x) { return 1.0f - 2.0f / (1.0f + __expf(2.0f * x)); }

// dot2: acc += w.lo*h.lo + w.hi*h.hi   (f16 inputs, fp32 accumulate)
__device__ __forceinline__ float dot2h(uint32 w, uint32 h, float acc) {
#if defined(__has_builtin)
#if __has_builtin(__builtin_amdgcn_fdot2)
  return __builtin_amdgcn_fdot2(__builtin_bit_cast(h2v, w), __builtin_bit_cast(h2v, h), acc, false);
#define DOT2_DONE 1
#endif
#endif
#ifndef DOT2_DONE
  h2v wv = __builtin_bit_cast(h2v, w);
  h2v hv = __builtin_bit_cast(h2v, h);
  return acc + (float)wv.x * (float)hv.x + (float)wv.y * (float)hv.y;
#endif
}
__device__ __forceinline__ uint32 packh2(float a, float b) {
  h2v v; v.x = (_Float16)a; v.y = (_Float16)b;
  return __builtin_bit_cast(uint32, v);
}

// ---- block reductions (256-thread kernels) ----
__device__ __forceinline__ float blk_sum(float v, float* sm, int tid) {
#pragma unroll
  for (int o = 32; o; o >>= 1) v += __shfl_down(v, o, 64);
  __syncthreads();
  if ((tid & 63) == 0) sm[tid >> 6] = v;
  __syncthreads();
  return sm[0] + sm[1] + sm[2] + sm[3];
}
__device__ __forceinline__ float blk_max(float v, float* sm, int tid) {
#pragma unroll
  for (int o = 32; o; o >>= 1) v = fmaxf(v, __shfl_down(v, o, 64));
  __syncthreads();
  if ((tid & 63) == 0) sm[tid >> 6] = v;
  __syncthreads();
  return fmaxf(fmaxf(sm[0], sm[1]), fmaxf(sm[2], sm[3]));
}

// ---- fused 4-value reduction across a 512-thread (8-wave) block ----
__device__ __forceinline__ void blk_sum4_w8(float& a, float& b, float& c, float& d,
                                            float* sm, int tid) {
#pragma unroll
  for (int o = 32; o; o >>= 1) {
    a += __shfl_down(a, o, 64);
    b += __shfl_down(b, o, 64);
    c += __shfl_down(c, o, 64);
    d += __shfl_down(d, o, 64);
  }
  __syncthreads();
  if ((tid & 63) == 0) {
    float4 v; v.x = a; v.y = b; v.z = c; v.w = d;
    *(float4*)&sm[(tid >> 6) * 4] = v;
  }
  __syncthreads();
  float ra = 0.f, rb = 0.f, rc = 0.f, rd = 0.f;
#pragma unroll
  for (int w = 0; w < 8; ++w) {
    float4 v = *(const float4*)&sm[w * 4];
    ra += v.x; rb += v.y; rc += v.z; rd += v.w;
  }
  a = ra; b = rb; c = rc; d = rd;
}

// ---- Wh pack: WhP[l][kp][n] = half2(Wh[l][n][2kp], Wh[l][n][2kp+1]) ----
__global__ __launch_bounds__(256) void wh_pack_k(
    const float* __restrict__ Wh, uint32* __restrict__ WhP)
{
  __shared__ float tile[32][33];
  const int l = blockIdx.z;
  const int k0 = blockIdx.x * 32;
  const int n0 = blockIdx.y * 32;
  const int row = threadIdx.x >> 5, col = threadIdx.x & 31;
  const float* src = Wh + (long)l * G4n * Hn;
  uint32* dst = WhP + (long)l * 256 * G4n;
#pragma unroll
  for (int rr = 0; rr < 4; ++rr) {
    int nn = row + rr * 8;
    tile[nn][col] = src[(long)(n0 + nn) * Hn + k0 + col];
  }
  __syncthreads();
#pragma unroll
  for (int rr = 0; rr < 2; ++rr) {
    int kpl = row + rr * 8;                     // 0..15
    int kp = (k0 >> 1) + kpl;
    dst[(long)kp * G4n + n0 + col] = packh2(tile[col][2*kpl], tile[col][2*kpl+1]);
  }
}

__global__ void init_zbuf_k(uint64* zbuf)
{
  long i = (long)blockIdx.x * 512 + threadIdx.x;
  zbuf[i] = 0ULL;
}

// ---- ip-chunk GEMM via MFMA 16x16x32 f16, time-major PACKED-F16 output ----
// Tile 128x128, K-step 32, 256 threads = 4 waves; wave w owns rows [w*32,w*32+32).
// Operands staged [128][32] f16 with padded row stride 20 uint32 (80B: bank-quad
// disjoint across rows, 2-way worst = free; 16B aligned). k-layout assumption is
// self-canceling (same per-lane k-permutation applied to A and B fragments);
// C/D mapping col=lane&15, row=(lane>>4)*4+reg is HW-verified. f32 accumulate.
__global__ __launch_bounds__(256) void gemm_ip_k(
    const float* __restrict__ A,       // [B,S,H]
    const float* __restrict__ Bw,      // [2048,512]
    const float* __restrict__ bias,
    uint32* __restrict__ C,            // [TCH*64][1024] f16 pairs
    int s0)
{
  __shared__ __align__(16) uint32 Ast[128 * 20];
  __shared__ __align__(16) uint32 Bst[128 * 20];
  const int tid = threadIdx.x;
  const long m0 = (long)blockIdx.y * 128;
  const int n0 = blockIdx.x * 128;

  // staging mapping: thread stages row rt (0..127), k-half hf (16 f16 each)
  const int rt = tid >> 1;
  const int hf = tid & 1;
  const long r  = m0 + rt;
  const long b  = r & 63;
  const long sl = r >> 6;
  const float* Arow = A + (b * Sn + s0 + sl) * Hn + hf * 16;
  const float* Brow = Bw + (long)(n0 + rt) * 512 + hf * 16;
  const int sbase = rt * 20 + hf * 8;

  // mfma mapping
  const int w  = tid >> 6;
  const int l  = tid & 63;
  const int lr = l & 15;
  const int lk = (l >> 4) * 4;       // uint32 offset within staged row

  f4v acc[8][2];
#pragma unroll
  for (int ct = 0; ct < 8; ++ct)
#pragma unroll
    for (int mt = 0; mt < 2; ++mt) {
      acc[ct][mt][0] = 0.f; acc[ct][mt][1] = 0.f;
      acc[ct][mt][2] = 0.f; acc[ct][mt][3] = 0.f;
    }

  float4 pa0 = *(const float4*)(Arow + 0);
  float4 pa1 = *(const float4*)(Arow + 4);
  float4 pa2 = *(const float4*)(Arow + 8);
  float4 pa3 = *(const float4*)(Arow + 12);
  float4 pb0 = *(const float4*)(Brow + 0);
  float4 pb1 = *(const float4*)(Brow + 4);
  float4 pb2 = *(const float4*)(Brow + 8);
  float4 pb3 = *(const float4*)(Brow + 12);

  for (int ks = 0; ks < 16; ++ks) {
    __syncthreads();
    {
      uint4 ua0, ua1, ub0, ub1;
      ua0.x = packh2(pa0.x, pa0.y); ua0.y = packh2(pa0.z, pa0.w);
      ua0.z = packh2(pa1.x, pa1.y); ua0.w = packh2(pa1.z, pa1.w);
      ua1.x = packh2(pa2.x, pa2.y); ua1.y = packh2(pa2.z, pa2.w);
      ua1.z = packh2(pa3.x, pa3.y); ua1.w = packh2(pa3.z, pa3.w);
      ub0.x = packh2(pb0.x, pb0.y); ub0.y = packh2(pb0.z, pb0.w);
      ub0.z = packh2(pb1.x, pb1.y); ub0.w = packh2(pb1.z, pb1.w);
      ub1.x = packh2(pb2.x, pb2.y); ub1.y = packh2(pb2.z, pb2.w);
      ub1.z = packh2(pb3.x, pb3.y); ub1.w = packh2(pb3.z, pb3.w);
      *(uint4*)&Ast[sbase]     = ua0;
      *(uint4*)&Ast[sbase + 4] = ua1;
      *(uint4*)&Bst[sbase]     = ub0;
      *(uint4*)&Bst[sbase + 4] = ub1;
    }
    __syncthreads();
    if (ks + 1 < 16) {
      const int ko = (ks + 1) * 32;
      pa0 = *(const float4*)(Arow + ko + 0);
      pa1 = *(const float4*)(Arow + ko + 4);
      pa2 = *(const float4*)(Arow + ko + 8);
      pa3 = *(const float4*)(Arow + ko + 12);
      pb0 = *(const float4*)(Brow + ko + 0);
      pb1 = *(const float4*)(Brow + ko + 4);
      pb2 = *(const float4*)(Brow + ko + 8);
      pb3 = *(const float4*)(Brow + ko + 12);
    }
    // compute: wave w rows, 2 M-tiles x 8 N-tiles
    uint4 aw0 = *(const uint4*)&Ast[(w*32 + lr) * 20 + lk];
    uint4 aw1 = *(const uint4*)&Ast[(w*32 + 16 + lr) * 20 + lk];
    h8v af0 = __builtin_bit_cast(h8v, aw0);
    h8v af1 = __builtin_bit_cast(h8v, aw1);
#pragma unroll
    for (int ct = 0; ct < 8; ++ct) {
      uint4 bw4 = *(const uint4*)&Bst[(ct*16 + lr) * 20 + lk];
      h8v bf = __builtin_bit_cast(h8v, bw4);
      acc[ct][0] = __builtin_amdgcn_mfma_f32_16x16x32_f16(af0, bf, acc[ct][0], 0, 0, 0);
      acc[ct][1] = __builtin_amdgcn_mfma_f32_16x16x32_f16(af1, bf, acc[ct][1], 0, 0, 0);
    }
  }

  // epilogue: bias add, pack col-pairs via shfl (adjacent lanes hold adjacent
  // cols of the same row), even lanes store uint32 into packed-f16 C
  float bs[8];
#pragma unroll
  for (int ct = 0; ct < 8; ++ct) bs[ct] = bias[n0 + ct*16 + lr];
  const long mbase = m0 + w*32 + (l >> 4) * 4;
#pragma unroll
  for (int ct = 0; ct < 8; ++ct) {
    const int cp = (n0 + ct*16 + lr) >> 1;
#pragma unroll
    for (int mt = 0; mt < 2; ++mt) {
#pragma unroll
      for (int j = 0; j < 4; ++j) {
        float v = acc[ct][mt][j] + bs[ct];
        float vh = __shfl_xor(v, 1, 64);
        if (!(l & 1)) {
          const long m = mbase + mt*16 + j;
          C[m * 1024 + cp] = packh2(v, vh);
        }
      }
    }
  }
}

// ---- per-row (mean, rstd) over the f16 ipc rows of 2048 ----
__global__ __launch_bounds__(256) void ipstats_k(
    const uint32* __restrict__ X, float* __restrict__ st)
{
  const long row = blockIdx.x;
  const uint32* xr = X + row * 1024;
  const int tid = threadIdx.x;
  __shared__ float sm[4];
  uint4 w = *(const uint4*)(xr + tid*4);
  h2v a = __builtin_bit_cast(h2v, w.x);
  h2v b = __builtin_bit_cast(h2v, w.y);
  h2v c = __builtin_bit_cast(h2v, w.z);
  h2v d = __builtin_bit_cast(h2v, w.w);
  float v[8] = {(float)a.x,(float)a.y,(float)b.x,(float)b.y,
                (float)c.x,(float)c.y,(float)d.x,(float)d.y};
  float s1 = 0.f, s2 = 0.f;
#pragma unroll
  for (int i = 0; i < 8; ++i) { s1 += v[i]; s2 += v[i]*v[i]; }
  s1 = blk_sum(s1, sm, tid);
  s2 = blk_sum(s2, sm, tid);
  if (tid == 0) {
    const float mean = s1 * (1.f/2048.f);
    const float rstd = rsqrtf(s2 * (1.f/2048.f) - mean*mean + EPS_LN);
    st[row*2]     = mean;
    st[row*2 + 1] = rstd;
  }
}

// ---- fused highway with global-load prefetch: 3 projections of the same A rows
// (A staged once) + elementwise combine in the epilogue. Tile 128x64.
__global__ __launch_bounds__(256) void hw_fused_k(
    const float* __restrict__ A,       // hseq + m0*512 (lda = 512)
    const float* __restrict__ Wt, const float* __restrict__ bt,
    const float* __restrict__ Wc, const float* __restrict__ bc,
    const float* __restrict__ Wh3, const float* __restrict__ bh3,
    float* __restrict__ seqout,        // seq + m0*512
    int skip)
{
  __shared__ __align__(16) uint32 Ah[8][128];     // [k-pair][row]
  __shared__ __align__(16) uint32 Bh[3][8][68];   // [mat][k-pair][col] pad 68
  const int tid = threadIdx.x;
  const long m0 = (long)blockIdx.y * 128;
  const int n0 = blockIdx.x * 64;
  const int tx = tid & 7;            // col-group (8 cols each)
  const int ty = tid >> 3;           // row-group (4 rows each)
  const int lrow = tid >> 1;         // A staging row
  const int lc0  = (tid & 1) * 8;
  const int kbA  = (tid & 1) * 4;
  const int brow = tid >> 2;         // B staging col (0..63)
  const int bk0  = (tid & 3) * 4;
  const int kbB  = (tid & 3) * 2;

  float accT[4][8], accC[4][8], accH[4][8];
#pragma unroll
  for (int i = 0; i < 4; ++i)
#pragma unroll
    for (int j = 0; j < 8; ++j) { accT[i][j] = 0.f; accC[i][j] = 0.f; accH[i][j] = 0.f; }

  const float* Arow = A + (m0 + lrow) * 512;
  const long boff = (long)(n0 + brow) * 512 + bk0;

  float4 a0 = *(const float4*)(Arow + lc0);
  float4 a1 = *(const float4*)(Arow + lc0 + 4);
  float4 wt4 = *(const float4*)(Wt  + boff);
  float4 wc4 = *(const float4*)(Wc  + boff);
  float4 wh4 = *(const float4*)(Wh3 + boff);

  for (int k0 = 0; k0 < 512; k0 += 16) {
    __syncthreads();
    Ah[kbA+0][lrow] = packh2(a0.x, a0.y);
    Ah[kbA+1][lrow] = packh2(a0.z, a0.w);
    Ah[kbA+2][lrow] = packh2(a1.x, a1.y);
    Ah[kbA+3][lrow] = packh2(a1.z, a1.w);
    Bh[0][kbB+0][brow] = packh2(wt4.x, wt4.y);
    Bh[0][kbB+1][brow] = packh2(wt4.z, wt4.w);
    Bh[1][kbB+0][brow] = packh2(wc4.x, wc4.y);
    Bh[1][kbB+1][brow] = packh2(wc4.z, wc4.w);
    Bh[2][kbB+0][brow] = packh2(wh4.x, wh4.y);
    Bh[2][kbB+1][brow] = packh2(wh4.z, wh4.w);
    __syncthreads();
    if (k0 + 16 < 512) {
      a0 = *(const float4*)(Arow + k0 + 16 + lc0);
      a1 = *(const float4*)(Arow + k0 + 16 + lc0 + 4);
      wt4 = *(const float4*)(Wt  + boff + k0 + 16);
      wc4 = *(const float4*)(Wc  + boff + k0 + 16);
      wh4 = *(const float4*)(Wh3 + boff + k0 + 16);
    }
#pragma unroll
    for (int kp = 0; kp < 8; ++kp) {
      uint32 a4[4];
      *(uint4*)&a4[0] = *(const uint4*)&Ah[kp][ty*4];
      {
        uint32 b8[8];
        *(uint4*)&b8[0] = *(const uint4*)&Bh[0][kp][tx*8];
        *(uint4*)&b8[4] = *(const uint4*)&Bh[0][kp][tx*8+4];
#pragma unroll
        for (int i = 0; i < 4; ++i)
#pragma unroll
          for (int j = 0; j < 8; ++j) accT[i][j] = dot2h(a4[i], b8[j], accT[i][j]);
      }
      {
        uint32 b8[8];
        *(uint4*)&b8[0] = *(const uint4*)&Bh[1][kp][tx*8];
        *(uint4*)&b8[4] = *(const uint4*)&Bh[1][kp][tx*8+4];
#pragma unroll
        for (int i = 0; i < 4; ++i)
#pragma unroll
          for (int j = 0; j < 8; ++j) accC[i][j] = dot2h(a4[i], b8[j], accC[i][j]);
      }
      {
        uint32 b8[8];
        *(uint4*)&b8[0] = *(const uint4*)&Bh[2][kp][tx*8];
        *(uint4*)&b8[4] = *(const uint4*)&Bh[2][kp][tx*8+4];
#pragma unroll
        for (int i = 0; i < 4; ++i)
#pragma unroll
          for (int j = 0; j < 8; ++j) accH[i][j] = dot2h(a4[i], b8[j], accH[i][j]);
      }
    }
  }

  // epilogue: combine + write seq
  float btr[8], bcr[8], bhr[8];
#pragma unroll
  for (int j = 0; j < 8; ++j) {
    btr[j] = bt[n0 + tx*8 + j];
    bcr[j] = bc[n0 + tx*8 + j];
    bhr[j] = bh3[n0 + tx*8 + j];
  }
#pragma unroll
  for (int i = 0; i < 4; ++i) {
    const long m = m0 + ty*4 + i;
    const float* hrow = A + m * 512 + n0 + tx*8;
    float* srow = seqout + m * 512 + n0 + tx*8;
    float4 h0 = *(const float4*)hrow;
    float4 h1 = *(const float4*)(hrow + 4);
    float hv[8] = {h0.x,h0.y,h0.z,h0.w,h1.x,h1.y,h1.z,h1.w};
    float sv[8] = {0,0,0,0,0,0,0,0};
    if (skip) {
      float4 s0 = *(const float4*)srow;
      float4 s1 = *(const float4*)(srow + 4);
      sv[0]=s0.x; sv[1]=s0.y; sv[2]=s0.z; sv[3]=s0.w;
      sv[4]=s1.x; sv[5]=s1.y; sv[6]=s1.z; sv[7]=s1.w;
    }
    float o[8];
#pragma unroll
    for (int j = 0; j < 8; ++j) {
      const float t1 = accT[i][j] + btr[j];
      const float t2 = accC[i][j] + bcr[j];
      const float t3 = accH[i][j] + bhr[j];
      o[j] = sigf(t1) * fmaxf(t3, 0.f) + sigf(t2) * hv[j] + sv[j];
    }
    float4 o0, o1;
    o0.x=o[0]; o0.y=o[1]; o0.z=o[2]; o0.w=o[3];
    o1.x=o[4]; o1.y=o[5]; o1.z=o[6]; o1.w=o[7];
    *(float4*)srow = o0; *(float4*)(srow + 4) = o1;
  }
}

// ---- M=64 GEMM (used for q projection) ----
__global__ __launch_bounds__(256) void gemm_m64_k(
    const float* __restrict__ A, long lda,
    const float* __restrict__ Bw,
    const float* __restrict__ bias,
    float* __restrict__ P,
    int N, int K)
{
  __shared__ float As[64][64];
  __shared__ float Bs[64][64];
  const int tid = threadIdx.x;
  const int n0 = blockIdx.x * 64;
  const int kc = blockIdx.y;
  const int Kc = K / gridDim.y;
  const int tx = tid & 15, ty = tid >> 4;
  const int row = tid >> 2, q = tid & 3;
  float acc[4][4];
#pragma unroll
  for (int i = 0; i < 4; ++i)
#pragma unroll
    for (int j = 0; j < 4; ++j) acc[i][j] = 0.f;

  for (int k0 = kc * Kc; k0 < kc * Kc + Kc; k0 += 64) {
    float4 a[4], b[4];
#pragma unroll
    for (int c = 0; c < 4; ++c) {
      a[c] = *(const float4*)(A  + (long)row * lda       + k0 + q*16 + c*4);
      b[c] = *(const float4*)(Bw + (long)(n0 + row) * K  + k0 + q*16 + c*4);
    }
    __syncthreads();
#pragma unroll
    for (int c = 0; c < 4; ++c) {
      int kb = q*16 + c*4;
      As[kb+0][row]=a[c].x; As[kb+1][row]=a[c].y; As[kb+2][row]=a[c].z; As[kb+3][row]=a[c].w;
      Bs[kb+0][row]=b[c].x; Bs[kb+1][row]=b[c].y; Bs[kb+2][row]=b[c].z; Bs[kb+3][row]=b[c].w;
    }
    __syncthreads();
#pragma unroll
    for (int kk = 0; kk < 64; ++kk) {
      float4 av = *(const float4*)&As[kk][ty*4];
      float4 bv = *(const float4*)&Bs[kk][tx*4];
      float am[4] = {av.x, av.y, av.z, av.w};
      float bm[4] = {bv.x, bv.y, bv.z, bv.w};
#pragma unroll
      for (int i = 0; i < 4; ++i)
#pragma unroll
        for (int j = 0; j < 4; ++j) acc[i][j] += am[i] * bm[j];
    }
  }
#pragma unroll
  for (int i = 0; i < 4; ++i) {
    int m = ty*4 + i;
    float* pr = P + ((long)kc * 64 + m) * N + n0 + tx*4;
#pragma unroll
    for (int j = 0; j < 4; ++j) {
      float bb = bias ? bias[n0 + tx*4 + j] : 0.f;
      pr[j] = acc[i][j] + bb;
    }
  }
}

// ---- persistent LSTM recurrence: n-split + tagged-word single-round exchange ----
// (exchange/GEMV/LDS/publish machinery byte-identical to rounds 5-10, verified.
//  Publish pattern myword=kq*512+tid gives contiguous full-line wave stores --
//  DO NOT change it. Packed-h LDS split lo/hi at +132 words keeps broadcast
//  reads on disjoint bank quads. ip read from packed-f16 ipc with on-the-fly LN.)
__global__ __launch_bounds__(512, 2) void lstm_seqz_k(
    const uint32* __restrict__ WhP,   // [256 kp][2048 n] this layer (f16 pairs)
    const float* __restrict__ bh,
    const uint32* __restrict__ ipc,   // [TCH*64][1024] raw ip (f16 pairs, +bias)
    const float* __restrict__ ipstats,// [TCH*64][2] (mean, rstd)
    const float* __restrict__ g_in, const float* __restrict__ b_in,
    const float* __restrict__ g_hid, const float* __restrict__ b_hid,
    const float* __restrict__ g_cell, const float* __restrict__ b_cell,
    float* __restrict__ hst, float* __restrict__ cst,  // [64][512]
    float* __restrict__ hseq,         // [B,S,H]
    uint64* __restrict__ zbuf,        // [2 parity][32 g][2048 row][2 b] tagged words
    int t0, int nsteps, int gbase)    // gbase >= 1, monotonic over the whole run
{
  const int blk = blockIdx.x;
  const int g   = blk & 31;
  const int kq  = blk >> 5;
  const int tid = threadIdx.x;
  const int b0  = g*2, b1 = g*2 + 1;
  const int r   = tid >> 1;          // row within our 256-row slice
  const int kh  = tid & 1;           // k-half (0: k<256, 1: k>=256)
  __shared__ __align__(16) uint32 hp0[264];
  __shared__ __align__(16) uint32 hp1[264];
  __shared__ float sm[32];

  // register-resident weights: rows kq*256+r, k-pairs kh*128 + [0,128)
  uint4 wreg[32];
  {
    const uint32* base = WhP + (long)(kh * 128) * 2048 + (kq*256 + r);
#pragma unroll
    for (int i = 0; i < 32; ++i) {
      wreg[i].x = base[(long)(4*i + 0) * 2048];
      wreg[i].y = base[(long)(4*i + 1) * 2048];
      wreg[i].z = base[(long)(4*i + 2) * 2048];
      wreg[i].w = base[(long)(4*i + 3) * 2048];
    }
  }

  // per-unit params/state: thread owns unit tid (both batches)
  float bhr[4], ghr[4], bhir[4], ginr[4], binr[4];
#pragma unroll
  for (int q = 0; q < 4; ++q) {
    bhr[q]  = bh[q*512 + tid];
    ghr[q]  = g_hid[q*512 + tid];
    bhir[q] = b_hid[q*512 + tid];
    ginr[q] = g_in[q*512 + tid];
    binr[q] = b_in[q*512 + tid];
  }
  const float gcv = g_cell[tid];
  const float bcv = b_cell[tid];
  float c0 = cst[b0*512 + tid];
  float c1 = cst[b1*512 + tid];
  float h0 = hst[b0*512 + tid];
  float h1 = hst[b1*512 + tid];

  // initial full-h pack into LDS (lo at j, hi at j+4 for j>=128)
  {
    const float p0 = __shfl_xor(h0, 1, 64);
    const float p1 = __shfl_xor(h1, 1, 64);
    if (!(tid & 1)) {
      const int j = tid >> 1;
      const int jj = (j < 128) ? j : j + 4;
      hp0[jj] = packh2(h0, p0);
      hp1[jj] = packh2(h1, p1);
    }
  }
  __syncthreads();

  const long myword = (long)(kq*256 + r) * 2 + kh;   // = kq*512 + tid (contiguous)
  const uint32* hb0 = hp0 + kh * 132;
  const uint32* hb1 = hp1 + kh * 132;

  for (int ts = 0; ts < nsteps; ++ts) {
    const int gstep = gbase + ts;
    const uint32 tagw = (uint32)gstep;
    uint64* zp = zbuf + (long)(gstep & 1) * 131072 + (long)g * 4096;

    // ip: packed-f16 load + on-the-fly LN (stats broadcast; hide under GEMV)
    const uint32* iprow0 = ipc + ((long)ts * 64 + b0) * 1024 + (tid >> 1);
    const uint32* iprow1 = ipc + ((long)ts * 64 + b1) * 1024 + (tid >> 1);
    const float2 st0 = *(const float2*)(ipstats + ((long)ts * 64 + b0) * 2);
    const float2 st1 = *(const float2*)(ipstats + ((long)ts * 64 + b1) * 2);
    float ip0[4], ip1[4];
#pragma unroll
    for (int q = 0; q < 4; ++q) {
      h2v v0 = __builtin_bit_cast(h2v, iprow0[q*256]);
      h2v v1 = __builtin_bit_cast(h2v, iprow1[q*256]);
      const float r0 = kh ? (float)v0.y : (float)v0.x;
      const float r1 = kh ? (float)v1.y : (float)v1.x;
      ip0[q] = (r0 - st0.x) * st0.y * ginr[q] + binr[q];
      ip1[q] = (r1 - st1.x) * st1.y * ginr[q] + binr[q];
    }

    // GEMV: full-k half for row kq*256+r, both batches (h via LDS broadcast)
    float a0 = 0.f, a1 = 0.f;
#pragma unroll
    for (int i = 0; i < 32; ++i) {
      const uint4 w  = wreg[i];
      const uint4 hv0 = *(const uint4*)&hb0[4*i];
      const uint4 hv1 = *(const uint4*)&hb1[4*i];
      a0 = dot2h(w.x, hv0.x, a0); a0 = dot2h(w.y, hv0.y, a0);
      a0 = dot2h(w.z, hv0.z, a0); a0 = dot2h(w.w, hv0.w, a0);
      a1 = dot2h(w.x, hv1.x, a1); a1 = dot2h(w.y, hv1.y, a1);
      a1 = dot2h(w.z, hv1.z, a1); a1 = dot2h(w.w, hv1.w, a1);
    }
    // combine k-halves within the lane pair
    a0 += __shfl_xor(a0, 1, 64);
    a1 += __shfl_xor(a1, 1, 64);

    // publish one tagged word (fire-and-forget; tag rides with payload)
    {
      const float zval = kh ? a1 : a0;
      const uint64 w = ((uint64)tagw << 32) | (uint64)__builtin_bit_cast(uint32, zval);
      __hip_atomic_store(zp + myword, w, __ATOMIC_RELAXED, __HIP_MEMORY_SCOPE_AGENT);
    }

    // gather the 8 tagged words for unit tid
    float z0[4], z1[4];
    {
      uint64 v0[4], v1[4];
      int pend = 0xff;
      while (pend) {
#pragma unroll
        for (int q = 0; q < 4; ++q) {
          const long base = (long)(q*512 + tid) * 2;
          if (pend & (1 << q)) {
            uint64 w = __hip_atomic_load(zp + base, __ATOMIC_RELAXED, __HIP_MEMORY_SCOPE_AGENT);
            if ((uint32)(w >> 32) == tagw) { v0[q] = w; pend &= ~(1 << q); }
          }
          if (pend & (16 << q)) {
            uint64 w = __hip_atomic_load(zp + base + 1, __ATOMIC_RELAXED, __HIP_MEMORY_SCOPE_AGENT);
            if ((uint32)(w >> 32) == tagw) { v1[q] = w; pend &= ~(16 << q); }
          }
        }
        if (pend) __builtin_amdgcn_s_sleep(2);
      }
#pragma unroll
      for (int q = 0; q < 4; ++q) {
        z0[q] = __builtin_bit_cast(float, (uint32)v0[q]) + bhr[q];
        z1[q] = __builtin_bit_cast(float, (uint32)v1[q]) + bhr[q];
      }
    }

    // LN1 over 2048, both batches in one reduction pass
    float s10 = z0[0]+z0[1]+z0[2]+z0[3];
    float s20 = z0[0]*z0[0] + z0[1]*z0[1] + z0[2]*z0[2] + z0[3]*z0[3];
    float s11 = z1[0]+z1[1]+z1[2]+z1[3];
    float s21 = z1[0]*z1[0] + z1[1]*z1[1] + z1[2]*z1[2] + z1[3]*z1[3];
    blk_sum4_w8(s10, s20, s11, s21, sm, tid);
    const float m0 = s10 * (1.f/2048.f);
    const float r0 = rsqrtf(s20 * (1.f/2048.f) - m0*m0 + EPS_LN);
    const float m1 = s11 * (1.f/2048.f);
    const float r1 = rsqrtf(s21 * (1.f/2048.f) - m1*m1 + EPS_LN);

    const float gi0 = ip0[0] + (z0[0] - m0) * r0 * ghr[0] + bhir[0];
    const float gf0 = ip0[1] + (z0[1] - m0) * r0 * ghr[1] + bhir[1];
    const float gg0 = ip0[2] + (z0[2] - m0) * r0 * ghr[2] + bhir[2];
    const float go0 = ip0[3] + (z0[3] - m0) * r0 * ghr[3] + bhir[3];
    const float gi1 = ip1[0] + (z1[0] - m1) * r1 * ghr[0] + bhir[0];
    const float gf1 = ip1[1] + (z1[1] - m1) * r1 * ghr[1] + bhir[1];
    const float gg1 = ip1[2] + (z1[2] - m1) * r1 * ghr[2] + bhir[2];
    const float go1 = ip1[3] + (z1[3] - m1) * r1 * ghr[3] + bhir[3];

    c0 = sigf(gf0) * c0 + sigf(gi0) * tanhfast(gg0);
    c1 = sigf(gf1) * c1 + sigf(gi1) * tanhfast(gg1);

    // LN2 over 512 cells, both batches in one pass
    float t10 = c0, t20 = c0*c0, t11 = c1, t21 = c1*c1;
    blk_sum4_w8(t10, t20, t11, t21, sm, tid);
    const float n0 = t10 * (1.f/512.f);
    const float q0r = rsqrtf(t20 * (1.f/512.f) - n0*n0 + EPS_LN);
    const float n1 = t11 * (1.f/512.f);
    const float q1r = rsqrtf(t21 * (1.f/512.f) - n1*n1 + EPS_LN);
    h0 = sigf(go0) * tanhfast((c0 - n0) * q0r * gcv + bcv);
    h1 = sigf(go1) * tanhfast((c1 - n1) * q1r * gcv + bcv);

    if (kq == 0) {
      hseq[((long)b0 * Sn + t0 + ts) * Hn + tid] = h0;
      hseq[((long)b1 * Sn + t0 + ts) * Hn + tid] = h1;
    }

    // repack full h into LDS for next step
    const float p0 = __shfl_xor(h0, 1, 64);
    const float p1 = __shfl_xor(h1, 1, 64);
    if (!(tid & 1)) {
      const int j = tid >> 1;
      const int jj = (j < 128) ? j : j + 4;
      hp0[jj] = packh2(h0, p0);
      hp1[jj] = packh2(h1, p1);
    }
    __syncthreads();
  }
  if (kq == 0) {
    hst[b0*512 + tid] = h0; hst[b1*512 + tid] = h1;
    cst[b0*512 + tid] = c0; cst[b1*512 + tid] = c1;
  }
}

__global__ void init_hc_k(float* h, float* c)
{
  int i = blockIdx.x * 256 + threadIdx.x;
  h[i] = 0.f; c[i] = 0.f;
}

// ---- qkh[b][hd][:] = sum_{j in head} q[b, hd*64+j] * Wk[hd*64+j, :]; qbk = q.bk ----
__global__ __launch_bounds__(256) void qkh_k(
    const float* __restrict__ qlst, const float* __restrict__ Wk,
    const float* __restrict__ bk,
    float* __restrict__ qkh, float* __restrict__ qbk)
{
  const int hd = blockIdx.x, cg = blockIdx.y;
  const int b = threadIdx.x & 63, sc = threadIdx.x >> 6;
  const int col0 = cg * 128 + sc * 32;
  float qreg[64];
  const float* qp = qlst + b*512 + hd*64;
#pragma unroll
  for (int j4 = 0; j4 < 16; ++j4) {
    float4 v = *(const float4*)(qp + j4*4);
    qreg[j4*4+0]=v.x; qreg[j4*4+1]=v.y; qreg[j4*4+2]=v.z; qreg[j4*4+3]=v.w;
  }
  float acc[32];
#pragma unroll
  for (int c = 0; c < 32; ++c) acc[c] = 0.f;
  for (int j = 0; j < 64; ++j) {
    float qv = qreg[j];
    const float* wr = Wk + (long)(hd*64 + j)*512 + col0;
#pragma unroll
    for (int c4 = 0; c4 < 8; ++c4) {
      float4 w = *(const float4*)(wr + c4*4);
      acc[c4*4+0] = __builtin_fmaf(qv, w.x, acc[c4*4+0]);
      acc[c4*4+1] = __builtin_fmaf(qv, w.y, acc[c4*4+1]);
      acc[c4*4+2] = __builtin_fmaf(qv, w.z, acc[c4*4+2]);
      acc[c4*4+3] = __builtin_fmaf(qv, w.w, acc[c4*4+3]);
    }
  }
  float* op = qkh + ((long)b*8 + hd)*512 + col0;
#pragma unroll
  for (int c4 = 0; c4 < 8; ++c4) {
    float4 o;
    o.x = acc[c4*4+0]; o.y = acc[c4*4+1]; o.z = acc[c4*4+2]; o.w = acc[c4*4+3];
    *(float4*)(op + c4*4) = o;
  }
  if (cg == 0 && sc == 0) {
    float s = 0.f;
    for (int j = 0; j < 64; ++j) s += qreg[j] * bk[hd*64 + j];
    qbk[b*8 + hd] = s;
  }
}

// ---- fused last-row attention ----
__global__ __launch_bounds__(256) void attn2_k(
    const float* __restrict__ seq,   // [B,S,H]
    const float* __restrict__ qkh,   // [64][8][512]
    const float* __restrict__ qbk,   // [64][8]
    float* __restrict__ u)           // [64][8][512]
{
  const int b = blockIdx.x, hd = blockIdx.y, tid = threadIdx.x;
  __shared__ __align__(16) float qk[512];
  __shared__ float p[512];
  __shared__ float sm[4];
  qk[tid]       = qkh[((long)b*8 + hd)*512 + tid];
  qk[tid + 256] = qkh[((long)b*8 + hd)*512 + tid + 256];
  __syncthreads();
  const float bias = qbk[b*8 + hd];

  float loc[2]; float mx = -3.0e38f;
#pragma unroll
  for (int v = 0; v < 2; ++v) {
    int s = tid + v*256;
    const float4* sr = (const float4*)(seq + ((long)b*512 + s)*512);
    const float4* qv4 = (const float4*)qk;
    float d = 0.f;
    for (int k4 = 0; k4 < 128; ++k4) {
      float4 sv = sr[k4], qv = qv4[k4];
      d += sv.x*qv.x + sv.y*qv.y + sv.z*qv.z + sv.w*qv.w;
    }
    d = (d + bias) * 0.125f;
    loc[v] = d; mx = fmaxf(mx, d);
  }
  const float M = blk_max(mx, sm, tid);
  float sum = 0.f;
#pragma unroll
  for (int v = 0; v < 2; ++v) {
    int s = tid + v*256;
    float e = __expf(loc[v] - M);
    p[s] = e; sum += e;
  }
  const float SM = blk_sum(sum, sm, tid);
  const float inv = 1.f / SM;

  float u0 = 0.f, u1 = 0.f;
  for (int s = 0; s < 512; ++s) {
    float ps = p[s];
    const float* srow = seq + ((long)b*512 + s)*512;
    u0 = __builtin_fmaf(ps, srow[tid], u0);
    u1 = __builtin_fmaf(ps, srow[tid + 256], u1);
  }
  u[((long)b*8 + hd)*512 + tid]       = u0 * inv;
  u[((long)b*8 + hd)*512 + tid + 256] = u1 * inv;
}

// ---- ctx[b][n] = u[b][hd(n)][:] . Wv[n][:] + bv[n] ----
__global__ __launch_bounds__(256) void ctxv_k(
    const float* __restrict__ u, const float* __restrict__ Wv,
    const float* __restrict__ bv, float* __restrict__ ctx)
{
  const int b = blockIdx.x, tid = threadIdx.x;
  __shared__ __align__(16) float ul[8*512];
  for (int i = tid; i < 4096; i += 256) ul[i] = u[(long)b*4096 + i];
  __syncthreads();
#pragma unroll
  for (int v = 0; v < 2; ++v) {
    int n = tid + v*256;
    int hd = n >> 6;
    const float4* wr = (const float4*)(Wv + (long)n*512);
    const float4* uv = (const float4*)&ul[hd*512];
    float acc = 0.f;
    for (int k4 = 0; k4 < 128; ++k4) {
      float4 w = wr[k4], x = uv[k4];
      acc += w.x*x.x + w.y*x.y + w.z*x.z + w.w*x.w;
    }
    ctx[b*512 + n] = acc + bv[n];
  }
}

// ---- output head ----
__global__ __launch_bounds__(256) void head_k(
    const float* __restrict__ ctx,
    const float* __restrict__ Wo, const float* __restrict__ bo,
    const float* __restrict__ seq,
    const float* __restrict__ att_g, const float* __restrict__ att_b,
    const float* __restrict__ on_g, const float* __restrict__ on_b,
    const float* __restrict__ Wp1, const float* __restrict__ bp1,
    const float* __restrict__ Wp2, const float* __restrict__ bp2,
    float* __restrict__ out)
{
  const int b = blockIdx.x, tid = threadIdx.x;
  __shared__ __align__(16) float cs[512];
  __shared__ __align__(16) float buf[512];
  __shared__ float sm[4];
  cs[tid]       = ctx[b*512 + tid];
  cs[tid + 256] = ctx[b*512 + tid + 256];
  __syncthreads();

  const float* srow = seq + ((long)b*512 + 511) * 512;
  float o[2];
#pragma unroll
  for (int v = 0; v < 2; ++v) {
    int j = tid + v*256;
    const float4* w4 = (const float4*)(Wo + (long)j * 512);
    const float4* c4 = (const float4*)cs;
    float acc = 0.f;
    for (int kx = 0; kx < 128; ++kx) {
      float4 w = w4[kx], c = c4[kx];
      acc += w.x*c.x + w.y*c.y + w.z*c.z + w.w*c.w;
    }
    o[v] = acc + bo[j] + srow[j];
  }
  float s1 = o[0] + o[1], s2 = o[0]*o[0] + o[1]*o[1];
  s1 = blk_sum(s1, sm, tid); s2 = blk_sum(s2, sm, tid);
  float m1 = s1 * (1.f/512.f);
  float r1 = rsqrtf(s2 * (1.f/512.f) - m1*m1 + EPS_LN);
  float a[2];
#pragma unroll
  for (int v = 0; v < 2; ++v) {
    int j = tid + v*256;
    a[v] = (o[v] - m1) * r1 * att_g[j] + att_b[j];
  }
  s1 = a[0] + a[1]; s2 = a[0]*a[0] + a[1]*a[1];
  s1 = blk_sum(s1, sm, tid); s2 = blk_sum(s2, sm, tid);
  float m2 = s1 * (1.f/512.f);
  float r2 = rsqrtf(s2 * (1.f/512.f) - m2*m2 + EPS_LN);
#pragma unroll
  for (int v = 0; v < 2; ++v) {
    int j = tid + v*256;
    buf[j] = (a[v] - m2) * r2 * on_g[j] + on_b[j];
  }
  __syncthreads();

  const float4* w1 = (const float4*)(Wp1 + (long)tid * 512);
  const float4* b4 = (const float4*)buf;
  float acc = 0.f;
  for (int kx = 0; kx < 128; ++kx) {
    float4 w = w1[kx], c = b4[kx];
    acc += w.x*c.x + w.y*c.y + w.z*c.z + w.w*c.w;
  }
  float mid = fmaxf(acc + bp1[tid], 0.f);
  float contrib = mid * Wp2[tid];
  float tot = blk_sum(contrib, sm, tid);
  if (tid == 0) out[b] = tot + bp2[0];
}

extern "C" void kernel_launch(void* const* d_in, const int* in_sizes, int n_in,
                              void* d_out, int out_size, void* d_ws, size_t ws_size,
                              hipStream_t stream)
{
  const float* x     = (const float*)d_in[0];
  const float* Wi    = (const float*)d_in[1];
  const float* bi    = (const float*)d_in[2];
  const float* Wh    = (const float*)d_in[3];
  const float* bh    = (const float*)d_in[4];
  const float* g_in  = (const float*)d_in[5];
  const float* b_in  = (const float*)d_in[6];
  const float* g_hid = (const float*)d_in[7];
  const float* b_hid = (const float*)d_in[8];
  const float* g_cell= (const float*)d_in[9];
  const float* b_cell= (const float*)d_in[10];
  const float* hwWt  = (const float*)d_in[11];
  const float* hwbt  = (const float*)d_in[12];
  const float* hwWc  = (const float*)d_in[13];
  const float* hwbc  = (const float*)d_in[14];
  const float* hwWh  = (const float*)d_in[15];
  const float* hwbh  = (const float*)d_in[16];
  const float* Wq    = (const float*)d_in[17];
  const float* bq    = (const float*)d_in[18];
  const float* Wk    = (const float*)d_in[19];
  const float* bk    = (const float*)d_in[20];
  const float* Wv    = (const float*)d_in[21];
  const float* bv    = (const float*)d_in[22];
  const float* Wo    = (const float*)d_in[23];
  const float* bo    = (const float*)d_in[24];
  const float* att_g = (const float*)d_in[25];
  const float* att_b = (const float*)d_in[26];
  const float* on_g  = (const float*)d_in[27];
  const float* on_b  = (const float*)d_in[28];
  const float* Wp1   = (const float*)d_in[29];
  const float* bp1   = (const float*)d_in[30];
  const float* Wp2   = (const float*)d_in[31];
  const float* bp2   = (const float*)d_in[32];
  float* out = (float*)d_out;

  // ---- workspace layout (floats); never touches d_in ----
  const long SEQF = (long)Bn * Sn * Hn;      // 16,777,216
  const long WHPF = 2L * 256 * G4n;          // 1,048,576 (uint32 slots)
  const long ZBF  = 2L * 32 * 2048 * 2;      // 262,144 uint64 = 524,288 floats
  const long wsF  = (long)(ws_size / 4);

  float* ws   = (float*)d_ws;
  float* seq  = ws;                  // [B,S,H]
  float* hseq = seq  + SEQF;         // [B,S,H]
  uint32* WhP = (uint32*)(hseq + SEQF);  // [2][256][2048] packed f16 pairs
  uint64* zbuf = (uint64*)(hseq + SEQF + WHPF);  // [2][32][2048][2] tagged z words
  float* hst  = hseq + SEQF + WHPF + 2*ZBF;  // [64][512]
  float* cst  = hst  + 32768L;
  float* qlst = cst  + 32768L;       // [64][512]
  float* ctx  = qlst + 32768L;       // [64][512]
  float* qkh  = ctx  + 32768L;       // [64][8][512]
  float* qbk  = qkh  + 262144L;      // [64][8] (pad to 1024)
  float* uat  = qbk  + 1024L;        // [64][8][512]
  float* ipstats = uat + 262144L;    // [TCH*64][2] (pad to 65536)
  float* ipcF = ipstats + 65536L;    // [TCH*64][1024 uint32] f16 ip pairs
  uint32* ipc = (uint32*)ipcF;
  const long baseF = (ipcF - ws);

  // f16 ipc: try TCH=512 (134MB), fall back if workspace too small
  int TCH = 512;
  while (TCH > 16 && baseF + (long)TCH * 64 * 1024 > wsF) TCH >>= 1;

  wh_pack_k<<<dim3(16, 64, 2), 256, 0, stream>>>(Wh, WhP);
  init_zbuf_k<<<512, 512, 0, stream>>>(zbuf);

  const int NCH = Sn / TCH;
  const int MROWS = TCH * 64;
  const int NMCH = (Bn * Sn) / MROWS;

  for (int l = 0; l < 2; ++l) {
    const float* seqin = (l == 0) ? x : seq;
    init_hc_k<<<128, 256, 0, stream>>>(hst, cst);
    for (int c = 0; c < NCH; ++c) {
      const int s0 = c * TCH;
      gemm_ip_k<<<dim3(16, TCH/2), 256, 0, stream>>>(seqin, Wi + (long)l*G4n*Hn, bi + l*G4n, ipc, s0);
      ipstats_k<<<TCH*64, 256, 0, stream>>>(ipc, ipstats);
      lstm_seqz_k<<<256, 512, 0, stream>>>(WhP + (long)l*256*G4n, bh + l*G4n, ipc, ipstats,
          g_in + l*G4n, b_in + l*G4n,
          g_hid + l*G4n, b_hid + l*G4n, g_cell + l*Hn, b_cell + l*Hn,
          hst, cst, hseq, zbuf, s0, TCH, l*Sn + s0 + 1);
    }
    // fused highway: 3 GEMMs + elementwise combine in one kernel, writes seq
    for (int mc = 0; mc < NMCH; ++mc) {
      const long m0 = (long)mc * MROWS;
      hw_fused_k<<<dim3(8, MROWS/128), 256, 0, stream>>>(
          hseq + m0*512,
          hwWt + (long)l*Hn*Hn, hwbt + l*Hn,
          hwWc + (long)l*Hn*Hn, hwbc + l*Hn,
          hwWh + (long)l*Hn*Hn, hwbh + l*Hn,
          seq + m0*512, (l == 0) ? 0 : 1);
    }
  }

  // attention on last query row, K/V never materialized
  gemm_m64_k<<<dim3(8, 1), 256, 0, stream>>>(seq + 511L*512, 512L*512, Wq, bq, qlst, 512, 512);
  qkh_k<<<dim3(8, 4), 256, 0, stream>>>(qlst, Wk, bk, qkh, qbk);
  attn2_k<<<dim3(64, 8), 256, 0, stream>>>(seq, qkh, qbk, uat);
  ctxv_k<<<64, 256, 0, stream>>>(uat, Wv, bv, ctx);
  head_k<<<64, 256, 0, stream>>>(ctx, Wo, bo, seq, att_g, att_b, on_g, on_b, Wp1, bp1, Wp2, bp2, out);
}

// Round 12
// 7928.210 us; speedup vs baseline: 1.2793x; 1.0675x over previous
//
#include <hip/hip_runtime.h>

#define EPS_LN 1e-5f

static constexpr int Bn  = 64;
static constexpr int Sn  = 512;
static constexpr int Hn  = 512;
static constexpr int G4n = 2048;

typedef unsigned int uint32;
typedef unsigned long long uint64;
typedef _Float16 h2v __attribute__((ext_vector_type(2)));
typedef _Float16 h8v __attribute__((ext_vector_type(8)));
typedef float f4v __attribute__((ext_vector_type(4)));

__device__ __forceinline__ float sigf(float x)     { return 1.0f / (1.0f + __expf(-x)); }
__device__ __forceinline__ float tanhfast(float x) { return 1.0f - 2.0f / (1.0f + __expf(2.0f * x)); }

// dot2: acc += w.lo*h.lo + w.hi*h.hi   (f16 inputs, fp32 accumulate)
__device__ __forceinline__ float dot2h(uint32 w, uint32 h, float acc) {
#if defined(__has_builtin)
#if __has_builtin(__builtin_amdgcn_fdot2)
  return __builtin_amdgcn_fdot2(__builtin_bit_cast(h2v, w), __builtin_bit_cast(h2v, h), acc, false);
#define DOT2_DONE 1
#endif
#endif
#ifndef DOT2_DONE
  h2v wv = __builtin_bit_cast(h2v, w);
  h2v hv = __builtin_bit_cast(h2v, h);
  return acc + (float)wv.x * (float)hv.x + (float)wv.y * (float)hv.y;
#endif
}
__device__ __forceinline__ uint32 packh2(float a, float b) {
  h2v v; v.x = (_Float16)a; v.y = (_Float16)b;
  return __builtin_bit_cast(uint32, v);
}

// ---- block reductions (256-thread kernels) ----
__device__ __forceinline__ float blk_sum(float v, float* sm, int tid) {
#pragma unroll
  for (int o = 32; o; o >>= 1) v += __shfl_down(v, o, 64);
  __syncthreads();
  if ((tid & 63) == 0) sm[tid >> 6] = v;
  __syncthreads();
  return sm[0] + sm[1] + sm[2] + sm[3];
}
__device__ __forceinline__ float blk_max(float v, float* sm, int tid) {
#pragma unroll
  for (int o = 32; o; o >>= 1) v = fmaxf(v, __shfl_down(v, o, 64));
  __syncthreads();
  if ((tid & 63) == 0) sm[tid >> 6] = v;
  __syncthreads();
  return fmaxf(fmaxf(sm[0], sm[1]), fmaxf(sm[2], sm[3]));
}

// ---- fused 4-value reduction across a 512-thread (8-wave) block ----
__device__ __forceinline__ void blk_sum4_w8(float& a, float& b, float& c, float& d,
                                            float* sm, int tid) {
#pragma unroll
  for (int o = 32; o; o >>= 1) {
    a += __shfl_down(a, o, 64);
    b += __shfl_down(b, o, 64);
    c += __shfl_down(c, o, 64);
    d += __shfl_down(d, o, 64);
  }
  __syncthreads();
  if ((tid & 63) == 0) {
    float4 v; v.x = a; v.y = b; v.z = c; v.w = d;
    *(float4*)&sm[(tid >> 6) * 4] = v;
  }
  __syncthreads();
  float ra = 0.f, rb = 0.f, rc = 0.f, rd = 0.f;
#pragma unroll
  for (int w = 0; w < 8; ++w) {
    float4 v = *(const float4*)&sm[w * 4];
    ra += v.x; rb += v.y; rc += v.z; rd += v.w;
  }
  a = ra; b = rb; c = rc; d = rd;
}

// ---- Wh pack: WhP[l][kp][n] = half2(Wh[l][n][2kp], Wh[l][n][2kp+1]) ----
__global__ __launch_bounds__(256) void wh_pack_k(
    const float* __restrict__ Wh, uint32* __restrict__ WhP)
{
  __shared__ float tile[32][33];
  const int l = blockIdx.z;
  const int k0 = blockIdx.x * 32;
  const int n0 = blockIdx.y * 32;
  const int row = threadIdx.x >> 5, col = threadIdx.x & 31;
  const float* src = Wh + (long)l * G4n * Hn;
  uint32* dst = WhP + (long)l * 256 * G4n;
#pragma unroll
  for (int rr = 0; rr < 4; ++rr) {
    int nn = row + rr * 8;
    tile[nn][col] = src[(long)(n0 + nn) * Hn + k0 + col];
  }
  __syncthreads();
#pragma unroll
  for (int rr = 0; rr < 2; ++rr) {
    int kpl = row + rr * 8;                     // 0..15
    int kp = (k0 >> 1) + kpl;
    dst[(long)kp * G4n + n0 + col] = packh2(tile[col][2*kpl], tile[col][2*kpl+1]);
  }
}

__global__ void init_zbuf_k(uint64* zbuf)
{
  long i = (long)blockIdx.x * 512 + threadIdx.x;
  zbuf[i] = 0ULL;
}

// ---- ip-chunk GEMM via MFMA 16x16x32 f16, time-major PACKED-F16 output ----
// (verified round 11: absmax 6.7e-4, ~matches MFMA rate)
__global__ __launch_bounds__(256) void gemm_ip_k(
    const float* __restrict__ A,       // [B,S,H]
    const float* __restrict__ Bw,      // [2048,512]
    const float* __restrict__ bias,
    uint32* __restrict__ C,            // [TCH*64][1024] f16 pairs
    int s0)
{
  __shared__ __align__(16) uint32 Ast[128 * 20];
  __shared__ __align__(16) uint32 Bst[128 * 20];
  const int tid = threadIdx.x;
  const long m0 = (long)blockIdx.y * 128;
  const int n0 = blockIdx.x * 128;

  const int rt = tid >> 1;
  const int hf = tid & 1;
  const long r  = m0 + rt;
  const long b  = r & 63;
  const long sl = r >> 6;
  const float* Arow = A + (b * Sn + s0 + sl) * Hn + hf * 16;
  const float* Brow = Bw + (long)(n0 + rt) * 512 + hf * 16;
  const int sbase = rt * 20 + hf * 8;

  const int w  = tid >> 6;
  const int l  = tid & 63;
  const int lr = l & 15;
  const int lk = (l >> 4) * 4;

  f4v acc[8][2];
#pragma unroll
  for (int ct = 0; ct < 8; ++ct)
#pragma unroll
    for (int mt = 0; mt < 2; ++mt) {
      acc[ct][mt][0] = 0.f; acc[ct][mt][1] = 0.f;
      acc[ct][mt][2] = 0.f; acc[ct][mt][3] = 0.f;
    }

  float4 pa0 = *(const float4*)(Arow + 0);
  float4 pa1 = *(const float4*)(Arow + 4);
  float4 pa2 = *(const float4*)(Arow + 8);
  float4 pa3 = *(const float4*)(Arow + 12);
  float4 pb0 = *(const float4*)(Brow + 0);
  float4 pb1 = *(const float4*)(Brow + 4);
  float4 pb2 = *(const float4*)(Brow + 8);
  float4 pb3 = *(const float4*)(Brow + 12);

  for (int ks = 0; ks < 16; ++ks) {
    __syncthreads();
    {
      uint4 ua0, ua1, ub0, ub1;
      ua0.x = packh2(pa0.x, pa0.y); ua0.y = packh2(pa0.z, pa0.w);
      ua0.z = packh2(pa1.x, pa1.y); ua0.w = packh2(pa1.z, pa1.w);
      ua1.x = packh2(pa2.x, pa2.y); ua1.y = packh2(pa2.z, pa2.w);
      ua1.z = packh2(pa3.x, pa3.y); ua1.w = packh2(pa3.z, pa3.w);
      ub0.x = packh2(pb0.x, pb0.y); ub0.y = packh2(pb0.z, pb0.w);
      ub0.z = packh2(pb1.x, pb1.y); ub0.w = packh2(pb1.z, pb1.w);
      ub1.x = packh2(pb2.x, pb2.y); ub1.y = packh2(pb2.z, pb2.w);
      ub1.z = packh2(pb3.x, pb3.y); ub1.w = packh2(pb3.z, pb3.w);
      *(uint4*)&Ast[sbase]     = ua0;
      *(uint4*)&Ast[sbase + 4] = ua1;
      *(uint4*)&Bst[sbase]     = ub0;
      *(uint4*)&Bst[sbase + 4] = ub1;
    }
    __syncthreads();
    if (ks + 1 < 16) {
      const int ko = (ks + 1) * 32;
      pa0 = *(const float4*)(Arow + ko + 0);
      pa1 = *(const float4*)(Arow + ko + 4);
      pa2 = *(const float4*)(Arow + ko + 8);
      pa3 = *(const float4*)(Arow + ko + 12);
      pb0 = *(const float4*)(Brow + ko + 0);
      pb1 = *(const float4*)(Brow + ko + 4);
      pb2 = *(const float4*)(Brow + ko + 8);
      pb3 = *(const float4*)(Brow + ko + 12);
    }
    uint4 aw0 = *(const uint4*)&Ast[(w*32 + lr) * 20 + lk];
    uint4 aw1 = *(const uint4*)&Ast[(w*32 + 16 + lr) * 20 + lk];
    h8v af0 = __builtin_bit_cast(h8v, aw0);
    h8v af1 = __builtin_bit_cast(h8v, aw1);
#pragma unroll
    for (int ct = 0; ct < 8; ++ct) {
      uint4 bw4 = *(const uint4*)&Bst[(ct*16 + lr) * 20 + lk];
      h8v bf = __builtin_bit_cast(h8v, bw4);
      acc[ct][0] = __builtin_amdgcn_mfma_f32_16x16x32_f16(af0, bf, acc[ct][0], 0, 0, 0);
      acc[ct][1] = __builtin_amdgcn_mfma_f32_16x16x32_f16(af1, bf, acc[ct][1], 0, 0, 0);
    }
  }

  float bs[8];
#pragma unroll
  for (int ct = 0; ct < 8; ++ct) bs[ct] = bias[n0 + ct*16 + lr];
  const long mbase = m0 + w*32 + (l >> 4) * 4;
#pragma unroll
  for (int ct = 0; ct < 8; ++ct) {
    const int cp = (n0 + ct*16 + lr) >> 1;
#pragma unroll
    for (int mt = 0; mt < 2; ++mt) {
#pragma unroll
      for (int j = 0; j < 4; ++j) {
        float v = acc[ct][mt][j] + bs[ct];
        float vh = __shfl_xor(v, 1, 64);
        if (!(l & 1)) {
          const long m = mbase + mt*16 + j;
          C[m * 1024 + cp] = packh2(v, vh);
        }
      }
    }
  }
}

// ---- per-row (mean, rstd) over the f16 ipc rows of 2048 ----
__global__ __launch_bounds__(256) void ipstats_k(
    const uint32* __restrict__ X, float* __restrict__ st)
{
  const long row = blockIdx.x;
  const uint32* xr = X + row * 1024;
  const int tid = threadIdx.x;
  __shared__ float sm[4];
  uint4 w = *(const uint4*)(xr + tid*4);
  h2v a = __builtin_bit_cast(h2v, w.x);
  h2v b = __builtin_bit_cast(h2v, w.y);
  h2v c = __builtin_bit_cast(h2v, w.z);
  h2v d = __builtin_bit_cast(h2v, w.w);
  float v[8] = {(float)a.x,(float)a.y,(float)b.x,(float)b.y,
                (float)c.x,(float)c.y,(float)d.x,(float)d.y};
  float s1 = 0.f, s2 = 0.f;
#pragma unroll
  for (int i = 0; i < 8; ++i) { s1 += v[i]; s2 += v[i]*v[i]; }
  s1 = blk_sum(s1, sm, tid);
  s2 = blk_sum(s2, sm, tid);
  if (tid == 0) {
    const float mean = s1 * (1.f/2048.f);
    const float rstd = rsqrtf(s2 * (1.f/2048.f) - mean*mean + EPS_LN);
    st[row*2]     = mean;
    st[row*2 + 1] = rstd;
  }
}

// ---- fused highway via MFMA 16x16x32 f16: 3 projections of the same A rows ----
// Tile 128 rows x 64 cols x 3 matrices; K-step 32; 4 waves; per wave 2 M-tiles x
// 4 N-tiles x 3 mats = 24 MFMAs/K-step. Staging [row][20-uint32] padded (same as
// gemm_ip, verified). accT/accC/accH share the same (row,col) lane mapping so the
// highway combine is lane-local in the epilogue; stores 64B-coalesced per 16 lanes.
// out[m][n] = sigf(t1)*relu(t3) + sigf(t2)*A[m][n] (+ seq[m][n] if skip)
__global__ __launch_bounds__(256) void hw_fused_k(
    const float* __restrict__ A,       // hseq + m0*512 (lda = 512)
    const float* __restrict__ Wt, const float* __restrict__ bt,
    const float* __restrict__ Wc, const float* __restrict__ bc,
    const float* __restrict__ Wh3, const float* __restrict__ bh3,
    float* __restrict__ seqout,        // seq + m0*512
    int skip)
{
  __shared__ __align__(16) uint32 Ast[128 * 20];
  __shared__ __align__(16) uint32 Bst[3 * 64 * 20];
  const int tid = threadIdx.x;
  const long m0 = (long)blockIdx.y * 128;
  const int n0 = blockIdx.x * 64;

  // A staging: row rt, k-half hf (16 f16)
  const int rt = tid >> 1;
  const int hf = tid & 1;
  const float* Arow = A + (m0 + rt) * 512 + hf * 16;
  const int sbaseA = rt * 20 + hf * 8;

  // B staging: 384 half-row units; thread does unit tid and (tid<128) unit tid+256
  // unit u: mat = u>>7, row rr = (u>>1)&63, half hh = u&1
  const int u1 = tid;
  const int u2 = tid + 256;
  const int m1_ = u1 >> 7, r1_ = (u1 >> 1) & 63, h1_ = u1 & 1;
  const int m2_ = u2 >> 7, r2_ = (u2 >> 1) & 63, h2_ = u2 & 1;
  const float* bsrc1 = (m1_ == 0 ? Wt : (m1_ == 1 ? Wc : Wh3)) + (long)(n0 + r1_) * 512 + h1_ * 16;
  const float* bsrc2 = (m2_ == 0 ? Wt : (m2_ == 1 ? Wc : Wh3)) + (long)(n0 + r2_) * 512 + h2_ * 16;
  const int sbaseB1 = m1_ * 1280 + r1_ * 20 + h1_ * 8;
  const int sbaseB2 = m2_ * 1280 + r2_ * 20 + h2_ * 8;

  // mfma mapping
  const int w  = tid >> 6;
  const int l  = tid & 63;
  const int lr = l & 15;
  const int lk = (l >> 4) * 4;

  f4v acc[3][4][2];
#pragma unroll
  for (int mat = 0; mat < 3; ++mat)
#pragma unroll
    for (int nt = 0; nt < 4; ++nt)
#pragma unroll
      for (int mt = 0; mt < 2; ++mt) {
        acc[mat][nt][mt][0] = 0.f; acc[mat][nt][mt][1] = 0.f;
        acc[mat][nt][mt][2] = 0.f; acc[mat][nt][mt][3] = 0.f;
      }

  for (int ks = 0; ks < 16; ++ks) {
    const int ko = ks * 32;
    __syncthreads();
    {
      float4 a0 = *(const float4*)(Arow + ko + 0);
      float4 a1 = *(const float4*)(Arow + ko + 4);
      float4 a2 = *(const float4*)(Arow + ko + 8);
      float4 a3 = *(const float4*)(Arow + ko + 12);
      uint4 ua0, ua1;
      ua0.x = packh2(a0.x, a0.y); ua0.y = packh2(a0.z, a0.w);
      ua0.z = packh2(a1.x, a1.y); ua0.w = packh2(a1.z, a1.w);
      ua1.x = packh2(a2.x, a2.y); ua1.y = packh2(a2.z, a2.w);
      ua1.z = packh2(a3.x, a3.y); ua1.w = packh2(a3.z, a3.w);
      *(uint4*)&Ast[sbaseA]     = ua0;
      *(uint4*)&Ast[sbaseA + 4] = ua1;
    }
    {
      float4 b0 = *(const float4*)(bsrc1 + ko + 0);
      float4 b1 = *(const float4*)(bsrc1 + ko + 4);
      float4 b2 = *(const float4*)(bsrc1 + ko + 8);
      float4 b3 = *(const float4*)(bsrc1 + ko + 12);
      uint4 ub0, ub1;
      ub0.x = packh2(b0.x, b0.y); ub0.y = packh2(b0.z, b0.w);
      ub0.z = packh2(b1.x, b1.y); ub0.w = packh2(b1.z, b1.w);
      ub1.x = packh2(b2.x, b2.y); ub1.y = packh2(b2.z, b2.w);
      ub1.z = packh2(b3.x, b3.y); ub1.w = packh2(b3.z, b3.w);
      *(uint4*)&Bst[sbaseB1]     = ub0;
      *(uint4*)&Bst[sbaseB1 + 4] = ub1;
    }
    if (tid < 128) {
      float4 b0 = *(const float4*)(bsrc2 + ko + 0);
      float4 b1 = *(const float4*)(bsrc2 + ko + 4);
      float4 b2 = *(const float4*)(bsrc2 + ko + 8);
      float4 b3 = *(const float4*)(bsrc2 + ko + 12);
      uint4 ub0, ub1;
      ub0.x = packh2(b0.x, b0.y); ub0.y = packh2(b0.z, b0.w);
      ub0.z = packh2(b1.x, b1.y); ub0.w = packh2(b1.z, b1.w);
      ub1.x = packh2(b2.x, b2.y); ub1.y = packh2(b2.z, b2.w);
      ub1.z = packh2(b3.x, b3.y); ub1.w = packh2(b3.z, b3.w);
      *(uint4*)&Bst[sbaseB2]     = ub0;
      *(uint4*)&Bst[sbaseB2 + 4] = ub1;
    }
    __syncthreads();

    uint4 aw0 = *(const uint4*)&Ast[(w*32 + lr) * 20 + lk];
    uint4 aw1 = *(const uint4*)&Ast[(w*32 + 16 + lr) * 20 + lk];
    h8v af0 = __builtin_bit_cast(h8v, aw0);
    h8v af1 = __builtin_bit_cast(h8v, aw1);
#pragma unroll
    for (int mat = 0; mat < 3; ++mat) {
#pragma unroll
      for (int nt = 0; nt < 4; ++nt) {
        uint4 bw4 = *(const uint4*)&Bst[mat*1280 + (nt*16 + lr) * 20 + lk];
        h8v bf = __builtin_bit_cast(h8v, bw4);
        acc[mat][nt][0] = __builtin_amdgcn_mfma_f32_16x16x32_f16(af0, bf, acc[mat][nt][0], 0, 0, 0);
        acc[mat][nt][1] = __builtin_amdgcn_mfma_f32_16x16x32_f16(af1, bf, acc[mat][nt][1], 0, 0, 0);
      }
    }
  }

  // epilogue: lane-local highway combine, scalar stores (64B-coalesced / 16 lanes)
  float bsT[4], bsC[4], bsH[4];
#pragma unroll
  for (int nt = 0; nt < 4; ++nt) {
    const int col = n0 + nt*16 + lr;
    bsT[nt] = bt[col];
    bsC[nt] = bc[col];
    bsH[nt] = bh3[col];
  }
  const long mbase = m0 + w*32 + (l >> 4) * 4;
#pragma unroll
  for (int nt = 0; nt < 4; ++nt) {
    const int col = n0 + nt*16 + lr;
#pragma unroll
    for (int mt = 0; mt < 2; ++mt) {
#pragma unroll
      for (int j = 0; j < 4; ++j) {
        const long m = mbase + mt*16 + j;
        const float t1 = acc[0][nt][mt][j] + bsT[nt];
        const float t2 = acc[1][nt][mt][j] + bsC[nt];
        const float t3 = acc[2][nt][mt][j] + bsH[nt];
        const float hvv = A[m * 512 + col];
        const float svv = skip ? seqout[m * 512 + col] : 0.f;
        seqout[m * 512 + col] = sigf(t1) * fmaxf(t3, 0.f) + sigf(t2) * hvv + svv;
      }
    }
  }
}

// ---- M=64 GEMM (used for q projection) ----
__global__ __launch_bounds__(256) void gemm_m64_k(
    const float* __restrict__ A, long lda,
    const float* __restrict__ Bw,
    const float* __restrict__ bias,
    float* __restrict__ P,
    int N, int K)
{
  __shared__ float As[64][64];
  __shared__ float Bs[64][64];
  const int tid = threadIdx.x;
  const int n0 = blockIdx.x * 64;
  const int kc = blockIdx.y;
  const int Kc = K / gridDim.y;
  const int tx = tid & 15, ty = tid >> 4;
  const int row = tid >> 2, q = tid & 3;
  float acc[4][4];
#pragma unroll
  for (int i = 0; i < 4; ++i)
#pragma unroll
    for (int j = 0; j < 4; ++j) acc[i][j] = 0.f;

  for (int k0 = kc * Kc; k0 < kc * Kc + Kc; k0 += 64) {
    float4 a[4], b[4];
#pragma unroll
    for (int c = 0; c < 4; ++c) {
      a[c] = *(const float4*)(A  + (long)row * lda       + k0 + q*16 + c*4);
      b[c] = *(const float4*)(Bw + (long)(n0 + row) * K  + k0 + q*16 + c*4);
    }
    __syncthreads();
#pragma unroll
    for (int c = 0; c < 4; ++c) {
      int kb = q*16 + c*4;
      As[kb+0][row]=a[c].x; As[kb+1][row]=a[c].y; As[kb+2][row]=a[c].z; As[kb+3][row]=a[c].w;
      Bs[kb+0][row]=b[c].x; Bs[kb+1][row]=b[c].y; Bs[kb+2][row]=b[c].z; Bs[kb+3][row]=b[c].w;
    }
    __syncthreads();
#pragma unroll
    for (int kk = 0; kk < 64; ++kk) {
      float4 av = *(const float4*)&As[kk][ty*4];
      float4 bv = *(const float4*)&Bs[kk][tx*4];
      float am[4] = {av.x, av.y, av.z, av.w};
      float bm[4] = {bv.x, bv.y, bv.z, bv.w};
#pragma unroll
      for (int i = 0; i < 4; ++i)
#pragma unroll
        for (int j = 0; j < 4; ++j) acc[i][j] += am[i] * bm[j];
    }
  }
#pragma unroll
  for (int i = 0; i < 4; ++i) {
    int m = ty*4 + i;
    float* pr = P + ((long)kc * 64 + m) * N + n0 + tx*4;
#pragma unroll
    for (int j = 0; j < 4; ++j) {
      float bb = bias ? bias[n0 + tx*4 + j] : 0.f;
      pr[j] = acc[i][j] + bb;
    }
  }
}

// ---- persistent LSTM recurrence: n-split + tagged-word single-round exchange ----
// (exchange/GEMV/LDS/publish machinery byte-identical to rounds 5-11, verified.
//  Publish pattern myword=kq*512+tid gives contiguous full-line wave stores --
//  DO NOT change it. Packed-h LDS split lo/hi at +132 words keeps broadcast
//  reads on disjoint bank quads. ip read from packed-f16 ipc with on-the-fly LN.)
__global__ __launch_bounds__(512, 2) void lstm_seqz_k(
    const uint32* __restrict__ WhP,   // [256 kp][2048 n] this layer (f16 pairs)
    const float* __restrict__ bh,
    const uint32* __restrict__ ipc,   // [TCH*64][1024] raw ip (f16 pairs, +bias)
    const float* __restrict__ ipstats,// [TCH*64][2] (mean, rstd)
    const float* __restrict__ g_in, const float* __restrict__ b_in,
    const float* __restrict__ g_hid, const float* __restrict__ b_hid,
    const float* __restrict__ g_cell, const float* __restrict__ b_cell,
    float* __restrict__ hst, float* __restrict__ cst,  // [64][512]
    float* __restrict__ hseq,         // [B,S,H]
    uint64* __restrict__ zbuf,        // [2 parity][32 g][2048 row][2 b] tagged words
    int t0, int nsteps, int gbase)    // gbase >= 1, monotonic over the whole run
{
  const int blk = blockIdx.x;
  const int g   = blk & 31;
  const int kq  = blk >> 5;
  const int tid = threadIdx.x;
  const int b0  = g*2, b1 = g*2 + 1;
  const int r   = tid >> 1;          // row within our 256-row slice
  const int kh  = tid & 1;           // k-half (0: k<256, 1: k>=256)
  __shared__ __align__(16) uint32 hp0[264];
  __shared__ __align__(16) uint32 hp1[264];
  __shared__ float sm[32];

  // register-resident weights: rows kq*256+r, k-pairs kh*128 + [0,128)
  uint4 wreg[32];
  {
    const uint32* base = WhP + (long)(kh * 128) * 2048 + (kq*256 + r);
#pragma unroll
    for (int i = 0; i < 32; ++i) {
      wreg[i].x = base[(long)(4*i + 0) * 2048];
      wreg[i].y = base[(long)(4*i + 1) * 2048];
      wreg[i].z = base[(long)(4*i + 2) * 2048];
      wreg[i].w = base[(long)(4*i + 3) * 2048];
    }
  }

  // per-unit params/state: thread owns unit tid (both batches)
  float bhr[4], ghr[4], bhir[4], ginr[4], binr[4];
#pragma unroll
  for (int q = 0; q < 4; ++q) {
    bhr[q]  = bh[q*512 + tid];
    ghr[q]  = g_hid[q*512 + tid];
    bhir[q] = b_hid[q*512 + tid];
    ginr[q] = g_in[q*512 + tid];
    binr[q] = b_in[q*512 + tid];
  }
  const float gcv = g_cell[tid];
  const float bcv = b_cell[tid];
  float c0 = cst[b0*512 + tid];
  float c1 = cst[b1*512 + tid];
  float h0 = hst[b0*512 + tid];
  float h1 = hst[b1*512 + tid];

  // initial full-h pack into LDS (lo at j, hi at j+4 for j>=128)
  {
    const float p0 = __shfl_xor(h0, 1, 64);
    const float p1 = __shfl_xor(h1, 1, 64);
    if (!(tid & 1)) {
      const int j = tid >> 1;
      const int jj = (j < 128) ? j : j + 4;
      hp0[jj] = packh2(h0, p0);
      hp1[jj] = packh2(h1, p1);
    }
  }
  __syncthreads();

  const long myword = (long)(kq*256 + r) * 2 + kh;   // = kq*512 + tid (contiguous)
  const uint32* hb0 = hp0 + kh * 132;
  const uint32* hb1 = hp1 + kh * 132;

  for (int ts = 0; ts < nsteps; ++ts) {
    const int gstep = gbase + ts;
    const uint32 tagw = (uint32)gstep;
    uint64* zp = zbuf + (long)(gstep & 1) * 131072 + (long)g * 4096;

    // ip: packed-f16 load + on-the-fly LN (stats broadcast; hide under GEMV)
    const uint32* iprow0 = ipc + ((long)ts * 64 + b0) * 1024 + (tid >> 1);
    const uint32* iprow1 = ipc + ((long)ts * 64 + b1) * 1024 + (tid >> 1);
    const float2 st0 = *(const float2*)(ipstats + ((long)ts * 64 + b0) * 2);
    const float2 st1 = *(const float2*)(ipstats + ((long)ts * 64 + b1) * 2);
    float ip0[4], ip1[4];
#pragma unroll
    for (int q = 0; q < 4; ++q) {
      h2v v0 = __builtin_bit_cast(h2v, iprow0[q*256]);
      h2v v1 = __builtin_bit_cast(h2v, iprow1[q*256]);
      const float r0 = kh ? (float)v0.y : (float)v0.x;
      const float r1 = kh ? (float)v1.y : (float)v1.x;
      ip0[q] = (r0 - st0.x) * st0.y * ginr[q] + binr[q];
      ip1[q] = (r1 - st1.x) * st1.y * ginr[q] + binr[q];
    }

    // GEMV: full-k half for row kq*256+r, both batches (h via LDS broadcast)
    float a0 = 0.f, a1 = 0.f;
#pragma unroll
    for (int i = 0; i < 32; ++i) {
      const uint4 w  = wreg[i];
      const uint4 hv0 = *(const uint4*)&hb0[4*i];
      const uint4 hv1 = *(const uint4*)&hb1[4*i];
      a0 = dot2h(w.x, hv0.x, a0); a0 = dot2h(w.y, hv0.y, a0);
      a0 = dot2h(w.z, hv0.z, a0); a0 = dot2h(w.w, hv0.w, a0);
      a1 = dot2h(w.x, hv1.x, a1); a1 = dot2h(w.y, hv1.y, a1);
      a1 = dot2h(w.z, hv1.z, a1); a1 = dot2h(w.w, hv1.w, a1);
    }
    // combine k-halves within the lane pair
    a0 += __shfl_xor(a0, 1, 64);
    a1 += __shfl_xor(a1, 1, 64);

    // publish one tagged word (fire-and-forget; tag rides with payload)
    {
      const float zval = kh ? a1 : a0;
      const uint64 w = ((uint64)tagw << 32) | (uint64)__builtin_bit_cast(uint32, zval);
      __hip_atomic_store(zp + myword, w, __ATOMIC_RELAXED, __HIP_MEMORY_SCOPE_AGENT);
    }

    // gather the 8 tagged words for unit tid
    float z0[4], z1[4];
    {
      uint64 v0[4], v1[4];
      int pend = 0xff;
      while (pend) {
#pragma unroll
        for (int q = 0; q < 4; ++q) {
          const long base = (long)(q*512 + tid) * 2;
          if (pend & (1 << q)) {
            uint64 w = __hip_atomic_load(zp + base, __ATOMIC_RELAXED, __HIP_MEMORY_SCOPE_AGENT);
            if ((uint32)(w >> 32) == tagw) { v0[q] = w; pend &= ~(1 << q); }
          }
          if (pend & (16 << q)) {
            uint64 w = __hip_atomic_load(zp + base + 1, __ATOMIC_RELAXED, __HIP_MEMORY_SCOPE_AGENT);
            if ((uint32)(w >> 32) == tagw) { v1[q] = w; pend &= ~(16 << q); }
          }
        }
        if (pend) __builtin_amdgcn_s_sleep(2);
      }
#pragma unroll
      for (int q = 0; q < 4; ++q) {
        z0[q] = __builtin_bit_cast(float, (uint32)v0[q]) + bhr[q];
        z1[q] = __builtin_bit_cast(float, (uint32)v1[q]) + bhr[q];
      }
    }

    // LN1 over 2048, both batches in one reduction pass
    float s10 = z0[0]+z0[1]+z0[2]+z0[3];
    float s20 = z0[0]*z0[0] + z0[1]*z0[1] + z0[2]*z0[2] + z0[3]*z0[3];
    float s11 = z1[0]+z1[1]+z1[2]+z1[3];
    float s21 = z1[0]*z1[0] + z1[1]*z1[1] + z1[2]*z1[2] + z1[3]*z1[3];
    blk_sum4_w8(s10, s20, s11, s21, sm, tid);
    const float m0 = s10 * (1.f/2048.f);
    const float r0 = rsqrtf(s20 * (1.f/2048.f) - m0*m0 + EPS_LN);
    const float m1 = s11 * (1.f/2048.f);
    const float r1 = rsqrtf(s21 * (1.f/2048.f) - m1*m1 + EPS_LN);

    const float gi0 = ip0[0] + (z0[0] - m0) * r0 * ghr[0] + bhir[0];
    const float gf0 = ip0[1] + (z0[1] - m0) * r0 * ghr[1] + bhir[1];
    const float gg0 = ip0[2] + (z0[2] - m0) * r0 * ghr[2] + bhir[2];
    const float go0 = ip0[3] + (z0[3] - m0) * r0 * ghr[3] + bhir[3];
    const float gi1 = ip1[0] + (z1[0] - m1) * r1 * ghr[0] + bhir[0];
    const float gf1 = ip1[1] + (z1[1] - m1) * r1 * ghr[1] + bhir[1];
    const float gg1 = ip1[2] + (z1[2] - m1) * r1 * ghr[2] + bhir[2];
    const float go1 = ip1[3] + (z1[3] - m1) * r1 * ghr[3] + bhir[3];

    c0 = sigf(gf0) * c0 + sigf(gi0) * tanhfast(gg0);
    c1 = sigf(gf1) * c1 + sigf(gi1) * tanhfast(gg1);

    // LN2 over 512 cells, both batches in one pass
    float t10 = c0, t20 = c0*c0, t11 = c1, t21 = c1*c1;
    blk_sum4_w8(t10, t20, t11, t21, sm, tid);
    const float n0 = t10 * (1.f/512.f);
    const float q0r = rsqrtf(t20 * (1.f/512.f) - n0*n0 + EPS_LN);
    const float n1 = t11 * (1.f/512.f);
    const float q1r = rsqrtf(t21 * (1.f/512.f) - n1*n1 + EPS_LN);
    h0 = sigf(go0) * tanhfast((c0 - n0) * q0r * gcv + bcv);
    h1 = sigf(go1) * tanhfast((c1 - n1) * q1r * gcv + bcv);

    if (kq == 0) {
      hseq[((long)b0 * Sn + t0 + ts) * Hn + tid] = h0;
      hseq[((long)b1 * Sn + t0 + ts) * Hn + tid] = h1;
    }

    // repack full h into LDS for next step
    const float p0 = __shfl_xor(h0, 1, 64);
    const float p1 = __shfl_xor(h1, 1, 64);
    if (!(tid & 1)) {
      const int j = tid >> 1;
      const int jj = (j < 128) ? j : j + 4;
      hp0[jj] = packh2(h0, p0);
      hp1[jj] = packh2(h1, p1);
    }
    __syncthreads();
  }
  if (kq == 0) {
    hst[b0*512 + tid] = h0; hst[b1*512 + tid] = h1;
    cst[b0*512 + tid] = c0; cst[b1*512 + tid] = c1;
  }
}

__global__ void init_hc_k(float* h, float* c)
{
  int i = blockIdx.x * 256 + threadIdx.x;
  h[i] = 0.f; c[i] = 0.f;
}

// ---- qkh[b][hd][:] = sum_{j in head} q[b, hd*64+j] * Wk[hd*64+j, :]; qbk = q.bk ----
__global__ __launch_bounds__(256) void qkh_k(
    const float* __restrict__ qlst, const float* __restrict__ Wk,
    const float* __restrict__ bk,
    float* __restrict__ qkh, float* __restrict__ qbk)
{
  const int hd = blockIdx.x, cg = blockIdx.y;
  const int b = threadIdx.x & 63, sc = threadIdx.x >> 6;
  const int col0 = cg * 128 + sc * 32;
  float qreg[64];
  const float* qp = qlst + b*512 + hd*64;
#pragma unroll
  for (int j4 = 0; j4 < 16; ++j4) {
    float4 v = *(const float4*)(qp + j4*4);
    qreg[j4*4+0]=v.x; qreg[j4*4+1]=v.y; qreg[j4*4+2]=v.z; qreg[j4*4+3]=v.w;
  }
  float acc[32];
#pragma unroll
  for (int c = 0; c < 32; ++c) acc[c] = 0.f;
  for (int j = 0; j < 64; ++j) {
    float qv = qreg[j];
    const float* wr = Wk + (long)(hd*64 + j)*512 + col0;
#pragma unroll
    for (int c4 = 0; c4 < 8; ++c4) {
      float4 w = *(const float4*)(wr + c4*4);
      acc[c4*4+0] = __builtin_fmaf(qv, w.x, acc[c4*4+0]);
      acc[c4*4+1] = __builtin_fmaf(qv, w.y, acc[c4*4+1]);
      acc[c4*4+2] = __builtin_fmaf(qv, w.z, acc[c4*4+2]);
      acc[c4*4+3] = __builtin_fmaf(qv, w.w, acc[c4*4+3]);
    }
  }
  float* op = qkh + ((long)b*8 + hd)*512 + col0;
#pragma unroll
  for (int c4 = 0; c4 < 8; ++c4) {
    float4 o;
    o.x = acc[c4*4+0]; o.y = acc[c4*4+1]; o.z = acc[c4*4+2]; o.w = acc[c4*4+3];
    *(float4*)(op + c4*4) = o;
  }
  if (cg == 0 && sc == 0) {
    float s = 0.f;
    for (int j = 0; j < 64; ++j) s += qreg[j] * bk[hd*64 + j];
    qbk[b*8 + hd] = s;
  }
}

// ---- fused last-row attention ----
__global__ __launch_bounds__(256) void attn2_k(
    const float* __restrict__ seq,   // [B,S,H]
    const float* __restrict__ qkh,   // [64][8][512]
    const float* __restrict__ qbk,   // [64][8]
    float* __restrict__ u)           // [64][8][512]
{
  const int b = blockIdx.x, hd = blockIdx.y, tid = threadIdx.x;
  __shared__ __align__(16) float qk[512];
  __shared__ float p[512];
  __shared__ float sm[4];
  qk[tid]       = qkh[((long)b*8 + hd)*512 + tid];
  qk[tid + 256] = qkh[((long)b*8 + hd)*512 + tid + 256];
  __syncthreads();
  const float bias = qbk[b*8 + hd];

  float loc[2]; float mx = -3.0e38f;
#pragma unroll
  for (int v = 0; v < 2; ++v) {
    int s = tid + v*256;
    const float4* sr = (const float4*)(seq + ((long)b*512 + s)*512);
    const float4* qv4 = (const float4*)qk;
    float d = 0.f;
    for (int k4 = 0; k4 < 128; ++k4) {
      float4 sv = sr[k4], qv = qv4[k4];
      d += sv.x*qv.x + sv.y*qv.y + sv.z*qv.z + sv.w*qv.w;
    }
    d = (d + bias) * 0.125f;
    loc[v] = d; mx = fmaxf(mx, d);
  }
  const float M = blk_max(mx, sm, tid);
  float sum = 0.f;
#pragma unroll
  for (int v = 0; v < 2; ++v) {
    int s = tid + v*256;
    float e = __expf(loc[v] - M);
    p[s] = e; sum += e;
  }
  const float SM = blk_sum(sum, sm, tid);
  const float inv = 1.f / SM;

  float u0 = 0.f, u1 = 0.f;
  for (int s = 0; s < 512; ++s) {
    float ps = p[s];
    const float* srow = seq + ((long)b*512 + s)*512;
    u0 = __builtin_fmaf(ps, srow[tid], u0);
    u1 = __builtin_fmaf(ps, srow[tid + 256], u1);
  }
  u[((long)b*8 + hd)*512 + tid]       = u0 * inv;
  u[((long)b*8 + hd)*512 + tid + 256] = u1 * inv;
}

// ---- ctx[b][n] = u[b][hd(n)][:] . Wv[n][:] + bv[n] ----
__global__ __launch_bounds__(256) void ctxv_k(
    const float* __restrict__ u, const float* __restrict__ Wv,
    const float* __restrict__ bv, float* __restrict__ ctx)
{
  const int b = blockIdx.x, tid = threadIdx.x;
  __shared__ __align__(16) float ul[8*512];
  for (int i = tid; i < 4096; i += 256) ul[i] = u[(long)b*4096 + i];
  __syncthreads();
#pragma unroll
  for (int v = 0; v < 2; ++v) {
    int n = tid + v*256;
    int hd = n >> 6;
    const float4* wr = (const float4*)(Wv + (long)n*512);
    const float4* uv = (const float4*)&ul[hd*512];
    float acc = 0.f;
    for (int k4 = 0; k4 < 128; ++k4) {
      float4 w = wr[k4], x = uv[k4];
      acc += w.x*x.x + w.y*x.y + w.z*x.z + w.w*x.w;
    }
    ctx[b*512 + n] = acc + bv[n];
  }
}

// ---- output head ----
__global__ __launch_bounds__(256) void head_k(
    const float* __restrict__ ctx,
    const float* __restrict__ Wo, const float* __restrict__ bo,
    const float* __restrict__ seq,
    const float* __restrict__ att_g, const float* __restrict__ att_b,
    const float* __restrict__ on_g, const float* __restrict__ on_b,
    const float* __restrict__ Wp1, const float* __restrict__ bp1,
    const float* __restrict__ Wp2, const float* __restrict__ bp2,
    float* __restrict__ out)
{
  const int b = blockIdx.x, tid = threadIdx.x;
  __shared__ __align__(16) float cs[512];
  __shared__ __align__(16) float buf[512];
  __shared__ float sm[4];
  cs[tid]       = ctx[b*512 + tid];
  cs[tid + 256] = ctx[b*512 + tid + 256];
  __syncthreads();

  const float* srow = seq + ((long)b*512 + 511) * 512;
  float o[2];
#pragma unroll
  for (int v = 0; v < 2; ++v) {
    int j = tid + v*256;
    const float4* w4 = (const float4*)(Wo + (long)j * 512);
    const float4* c4 = (const float4*)cs;
    float acc = 0.f;
    for (int kx = 0; kx < 128; ++kx) {
      float4 w = w4[kx], c = c4[kx];
      acc += w.x*c.x + w.y*c.y + w.z*c.z + w.w*c.w;
    }
    o[v] = acc + bo[j] + srow[j];
  }
  float s1 = o[0] + o[1], s2 = o[0]*o[0] + o[1]*o[1];
  s1 = blk_sum(s1, sm, tid); s2 = blk_sum(s2, sm, tid);
  float m1 = s1 * (1.f/512.f);
  float r1 = rsqrtf(s2 * (1.f/512.f) - m1*m1 + EPS_LN);
  float a[2];
#pragma unroll
  for (int v = 0; v < 2; ++v) {
    int j = tid + v*256;
    a[v] = (o[v] - m1) * r1 * att_g[j] + att_b[j];
  }
  s1 = a[0] + a[1]; s2 = a[0]*a[0] + a[1]*a[1];
  s1 = blk_sum(s1, sm, tid); s2 = blk_sum(s2, sm, tid);
  float m2 = s1 * (1.f/512.f);
  float r2 = rsqrtf(s2 * (1.f/512.f) - m2*m2 + EPS_LN);
#pragma unroll
  for (int v = 0; v < 2; ++v) {
    int j = tid + v*256;
    buf[j] = (a[v] - m2) * r2 * on_g[j] + on_b[j];
  }
  __syncthreads();

  const float4* w1 = (const float4*)(Wp1 + (long)tid * 512);
  const float4* b4 = (const float4*)buf;
  float acc = 0.f;
  for (int kx = 0; kx < 128; ++kx) {
    float4 w = w1[kx], c = b4[kx];
    acc += w.x*c.x + w.y*c.y + w.z*c.z + w.w*c.w;
  }
  float mid = fmaxf(acc + bp1[tid], 0.f);
  float contrib = mid * Wp2[tid];
  float tot = blk_sum(contrib, sm, tid);
  if (tid == 0) out[b] = tot + bp2[0];
}

extern "C" void kernel_launch(void* const* d_in, const int* in_sizes, int n_in,
                              void* d_out, int out_size, void* d_ws, size_t ws_size,
                              hipStream_t stream)
{
  const float* x     = (const float*)d_in[0];
  const float* Wi    = (const float*)d_in[1];
  const float* bi    = (const float*)d_in[2];
  const float* Wh    = (const float*)d_in[3];
  const float* bh    = (const float*)d_in[4];
  const float* g_in  = (const float*)d_in[5];
  const float* b_in  = (const float*)d_in[6];
  const float* g_hid = (const float*)d_in[7];
  const float* b_hid = (const float*)d_in[8];
  const float* g_cell= (const float*)d_in[9];
  const float* b_cell= (const float*)d_in[10];
  const float* hwWt  = (const float*)d_in[11];
  const float* hwbt  = (const float*)d_in[12];
  const float* hwWc  = (const float*)d_in[13];
  const float* hwbc  = (const float*)d_in[14];
  const float* hwWh  = (const float*)d_in[15];
  const float* hwbh  = (const float*)d_in[16];
  const float* Wq    = (const float*)d_in[17];
  const float* bq    = (const float*)d_in[18];
  const float* Wk    = (const float*)d_in[19];
  const float* bk    = (const float*)d_in[20];
  const float* Wv    = (const float*)d_in[21];
  const float* bv    = (const float*)d_in[22];
  const float* Wo    = (const float*)d_in[23];
  const float* bo    = (const float*)d_in[24];
  const float* att_g = (const float*)d_in[25];
  const float* att_b = (const float*)d_in[26];
  const float* on_g  = (const float*)d_in[27];
  const float* on_b  = (const float*)d_in[28];
  const float* Wp1   = (const float*)d_in[29];
  const float* bp1   = (const float*)d_in[30];
  const float* Wp2   = (const float*)d_in[31];
  const float* bp2   = (const float*)d_in[32];
  float* out = (float*)d_out;

  // ---- workspace layout (floats); never touches d_in ----
  const long SEQF = (long)Bn * Sn * Hn;      // 16,777,216
  const long WHPF = 2L * 256 * G4n;          // 1,048,576 (uint32 slots)
  const long ZBF  = 2L * 32 * 2048 * 2;      // 262,144 uint64 = 524,288 floats
  const long wsF  = (long)(ws_size / 4);

  float* ws   = (float*)d_ws;
  float* seq  = ws;                  // [B,S,H]
  float* hseq = seq  + SEQF;         // [B,S,H]
  uint32* WhP = (uint32*)(hseq + SEQF);  // [2][256][2048] packed f16 pairs
  uint64* zbuf = (uint64*)(hseq + SEQF + WHPF);  // [2][32][2048][2] tagged z words
  float* hst  = hseq + SEQF + WHPF + 2*ZBF;  // [64][512]
  float* cst  = hst  + 32768L;
  float* qlst = cst  + 32768L;       // [64][512]
  float* ctx  = qlst + 32768L;       // [64][512]
  float* qkh  = ctx  + 32768L;       // [64][8][512]
  float* qbk  = qkh  + 262144L;      // [64][8] (pad to 1024)
  float* uat  = qbk  + 1024L;        // [64][8][512]
  float* ipstats = uat + 262144L;    // [TCH*64][2] (pad to 65536)
  float* ipcF = ipstats + 65536L;    // [TCH*64][1024 uint32] f16 ip pairs
  uint32* ipc = (uint32*)ipcF;
  const long baseF = (ipcF - ws);

  // f16 ipc: try TCH=512 (134MB), fall back if workspace too small
  int TCH = 512;
  while (TCH > 16 && baseF + (long)TCH * 64 * 1024 > wsF) TCH >>= 1;

  wh_pack_k<<<dim3(16, 64, 2), 256, 0, stream>>>(Wh, WhP);
  init_zbuf_k<<<512, 512, 0, stream>>>(zbuf);

  const int NCH = Sn / TCH;
  const int MROWS = TCH * 64;
  const int NMCH = (Bn * Sn) / MROWS;

  for (int l = 0; l < 2; ++l) {
    const float* seqin = (l == 0) ? x : seq;
    init_hc_k<<<128, 256, 0, stream>>>(hst, cst);
    for (int c = 0; c < NCH; ++c) {
      const int s0 = c * TCH;
      gemm_ip_k<<<dim3(16, TCH/2), 256, 0, stream>>>(seqin, Wi + (long)l*G4n*Hn, bi + l*G4n, ipc, s0);
      ipstats_k<<<TCH*64, 256, 0, stream>>>(ipc, ipstats);
      lstm_seqz_k<<<256, 512, 0, stream>>>(WhP + (long)l*256*G4n, bh + l*G4n, ipc, ipstats,
          g_in + l*G4n, b_in + l*G4n,
          g_hid + l*G4n, b_hid + l*G4n, g_cell + l*Hn, b_cell + l*Hn,
          hst, cst, hseq, zbuf, s0, TCH, l*Sn + s0 + 1);
    }
    // fused highway: 3 MFMA GEMMs + elementwise combine in one kernel, writes seq
    for (int mc = 0; mc < NMCH; ++mc) {
      const long m0 = (long)mc * MROWS;
      hw_fused_k<<<dim3(8, MROWS/128), 256, 0, stream>>>(
          hseq + m0*512,
          hwWt + (long)l*Hn*Hn, hwbt + l*Hn,
          hwWc + (long)l*Hn*Hn, hwbc + l*Hn,
          hwWh + (long)l*Hn*Hn, hwbh + l*Hn,
          seq + m0*512, (l == 0) ? 0 : 1);
    }
  }

  // attention on last query row, K/V never materialized
  gemm_m64_k<<<dim3(8, 1), 256, 0, stream>>>(seq + 511L*512, 512L*512, Wq, bq, qlst, 512, 512);
  qkh_k<<<dim3(8, 4), 256, 0, stream>>>(qlst, Wk, bk, qkh, qbk);
  attn2_k<<<dim3(64, 8), 256, 0, stream>>>(seq, qkh, qbk, uat);
  ctxv_k<<<64, 256, 0, stream>>>(uat, Wv, bv, ctx);
  head_k<<<64, 256, 0, stream>>>(ctx, Wo, bo, seq, att_g, att_b, on_g, on_b, Wp1, bp1, Wp2, bp2, out);
}

// Round 13
// 7801.064 us; speedup vs baseline: 1.3002x; 1.0163x over previous
//
#include <hip/hip_runtime.h>

#define EPS_LN 1e-5f

static constexpr int Bn  = 64;
static constexpr int Sn  = 512;
static constexpr int Hn  = 512;
static constexpr int G4n = 2048;

typedef unsigned int uint32;
typedef unsigned long long uint64;
typedef _Float16 h2v __attribute__((ext_vector_type(2)));
typedef _Float16 h8v __attribute__((ext_vector_type(8)));
typedef float f4v __attribute__((ext_vector_type(4)));

__device__ __forceinline__ float sigf(float x)     { return 1.0f / (1.0f + __expf(-x)); }
__device__ __forceinline__ float tanhfast(float x) { return 1.0f - 2.0f / (1.0f + __expf(2.0f * x)); }

// dot2: acc += w.lo*h.lo + w.hi*h.hi   (f16 inputs, fp32 accumulate)
__device__ __forceinline__ float dot2h(uint32 w, uint32 h, float acc) {
#if defined(__has_builtin)
#if __has_builtin(__builtin_amdgcn_fdot2)
  return __builtin_amdgcn_fdot2(__builtin_bit_cast(h2v, w), __builtin_bit_cast(h2v, h), acc, false);
#define DOT2_DONE 1
#endif
#endif
#ifndef DOT2_DONE
  h2v wv = __builtin_bit_cast(h2v, w);
  h2v hv = __builtin_bit_cast(h2v, h);
  return acc + (float)wv.x * (float)hv.x + (float)wv.y * (float)hv.y;
#endif
}
__device__ __forceinline__ uint32 packh2(float a, float b) {
  h2v v; v.x = (_Float16)a; v.y = (_Float16)b;
  return __builtin_bit_cast(uint32, v);
}

// ---- block reductions (256-thread kernels) ----
__device__ __forceinline__ float blk_sum(float v, float* sm, int tid) {
#pragma unroll
  for (int o = 32; o; o >>= 1) v += __shfl_down(v, o, 64);
  __syncthreads();
  if ((tid & 63) == 0) sm[tid >> 6] = v;
  __syncthreads();
  return sm[0] + sm[1] + sm[2] + sm[3];
}
__device__ __forceinline__ float blk_max(float v, float* sm, int tid) {
#pragma unroll
  for (int o = 32; o; o >>= 1) v = fmaxf(v, __shfl_down(v, o, 64));
  __syncthreads();
  if ((tid & 63) == 0) sm[tid >> 6] = v;
  __syncthreads();
  return fmaxf(fmaxf(sm[0], sm[1]), fmaxf(sm[2], sm[3]));
}

// ---- fused 4-value reduction across a 512-thread (8-wave) block ----
__device__ __forceinline__ void blk_sum4_w8(float& a, float& b, float& c, float& d,
                                            float* sm, int tid) {
#pragma unroll
  for (int o = 32; o; o >>= 1) {
    a += __shfl_down(a, o, 64);
    b += __shfl_down(b, o, 64);
    c += __shfl_down(c, o, 64);
    d += __shfl_down(d, o, 64);
  }
  __syncthreads();
  if ((tid & 63) == 0) {
    float4 v; v.x = a; v.y = b; v.z = c; v.w = d;
    *(float4*)&sm[(tid >> 6) * 4] = v;
  }
  __syncthreads();
  float ra = 0.f, rb = 0.f, rc = 0.f, rd = 0.f;
#pragma unroll
  for (int w = 0; w < 8; ++w) {
    float4 v = *(const float4*)&sm[w * 4];
    ra += v.x; rb += v.y; rc += v.z; rd += v.w;
  }
  a = ra; b = rb; c = rc; d = rd;
}

// ---- Wh pack: WhP[l][kp][n] = half2(Wh[l][n][2kp], Wh[l][n][2kp+1]) ----
__global__ __launch_bounds__(256) void wh_pack_k(
    const float* __restrict__ Wh, uint32* __restrict__ WhP)
{
  __shared__ float tile[32][33];
  const int l = blockIdx.z;
  const int k0 = blockIdx.x * 32;
  const int n0 = blockIdx.y * 32;
  const int row = threadIdx.x >> 5, col = threadIdx.x & 31;
  const float* src = Wh + (long)l * G4n * Hn;
  uint32* dst = WhP + (long)l * 256 * G4n;
#pragma unroll
  for (int rr = 0; rr < 4; ++rr) {
    int nn = row + rr * 8;
    tile[nn][col] = src[(long)(n0 + nn) * Hn + k0 + col];
  }
  __syncthreads();
#pragma unroll
  for (int rr = 0; rr < 2; ++rr) {
    int kpl = row + rr * 8;                     // 0..15
    int kp = (k0 >> 1) + kpl;
    dst[(long)kp * G4n + n0 + col] = packh2(tile[col][2*kpl], tile[col][2*kpl+1]);
  }
}

__global__ void init_zbuf_k(uint64* zbuf)
{
  long i = (long)blockIdx.x * 512 + threadIdx.x;
  zbuf[i] = 0ULL;
}

// ---- ip-chunk GEMM via MFMA 16x16x32 f16, time-major PACKED-F16 output ----
// (verified rounds 11-12). NEW: epilogue also accumulates per-row (sum, sumsq)
// partials into st[] via 16-lane shfl reduction + atomicAdd -- replaces the
// separate ipstats pass. st must be zeroed before the dispatch.
__global__ __launch_bounds__(256) void gemm_ip_k(
    const float* __restrict__ A,       // [B,S,H]
    const float* __restrict__ Bw,      // [2048,512]
    const float* __restrict__ bias,
    uint32* __restrict__ C,            // [TCH*64][1024] f16 pairs
    float* __restrict__ st,            // [TCH*64][2] raw (s1, s2), pre-zeroed
    int s0)
{
  __shared__ __align__(16) uint32 Ast[128 * 20];
  __shared__ __align__(16) uint32 Bst[128 * 20];
  const int tid = threadIdx.x;
  const long m0 = (long)blockIdx.y * 128;
  const int n0 = blockIdx.x * 128;

  const int rt = tid >> 1;
  const int hf = tid & 1;
  const long r  = m0 + rt;
  const long b  = r & 63;
  const long sl = r >> 6;
  const float* Arow = A + (b * Sn + s0 + sl) * Hn + hf * 16;
  const float* Brow = Bw + (long)(n0 + rt) * 512 + hf * 16;
  const int sbase = rt * 20 + hf * 8;

  const int w  = tid >> 6;
  const int l  = tid & 63;
  const int lr = l & 15;
  const int lk = (l >> 4) * 4;

  f4v acc[8][2];
#pragma unroll
  for (int ct = 0; ct < 8; ++ct)
#pragma unroll
    for (int mt = 0; mt < 2; ++mt) {
      acc[ct][mt][0] = 0.f; acc[ct][mt][1] = 0.f;
      acc[ct][mt][2] = 0.f; acc[ct][mt][3] = 0.f;
    }

  float4 pa0 = *(const float4*)(Arow + 0);
  float4 pa1 = *(const float4*)(Arow + 4);
  float4 pa2 = *(const float4*)(Arow + 8);
  float4 pa3 = *(const float4*)(Arow + 12);
  float4 pb0 = *(const float4*)(Brow + 0);
  float4 pb1 = *(const float4*)(Brow + 4);
  float4 pb2 = *(const float4*)(Brow + 8);
  float4 pb3 = *(const float4*)(Brow + 12);

  for (int ks = 0; ks < 16; ++ks) {
    __syncthreads();
    {
      uint4 ua0, ua1, ub0, ub1;
      ua0.x = packh2(pa0.x, pa0.y); ua0.y = packh2(pa0.z, pa0.w);
      ua0.z = packh2(pa1.x, pa1.y); ua0.w = packh2(pa1.z, pa1.w);
      ua1.x = packh2(pa2.x, pa2.y); ua1.y = packh2(pa2.z, pa2.w);
      ua1.z = packh2(pa3.x, pa3.y); ua1.w = packh2(pa3.z, pa3.w);
      ub0.x = packh2(pb0.x, pb0.y); ub0.y = packh2(pb0.z, pb0.w);
      ub0.z = packh2(pb1.x, pb1.y); ub0.w = packh2(pb1.z, pb1.w);
      ub1.x = packh2(pb2.x, pb2.y); ub1.y = packh2(pb2.z, pb2.w);
      ub1.z = packh2(pb3.x, pb3.y); ub1.w = packh2(pb3.z, pb3.w);
      *(uint4*)&Ast[sbase]     = ua0;
      *(uint4*)&Ast[sbase + 4] = ua1;
      *(uint4*)&Bst[sbase]     = ub0;
      *(uint4*)&Bst[sbase + 4] = ub1;
    }
    __syncthreads();
    if (ks + 1 < 16) {
      const int ko = (ks + 1) * 32;
      pa0 = *(const float4*)(Arow + ko + 0);
      pa1 = *(const float4*)(Arow + ko + 4);
      pa2 = *(const float4*)(Arow + ko + 8);
      pa3 = *(const float4*)(Arow + ko + 12);
      pb0 = *(const float4*)(Brow + ko + 0);
      pb1 = *(const float4*)(Brow + ko + 4);
      pb2 = *(const float4*)(Brow + ko + 8);
      pb3 = *(const float4*)(Brow + ko + 12);
    }
    uint4 aw0 = *(const uint4*)&Ast[(w*32 + lr) * 20 + lk];
    uint4 aw1 = *(const uint4*)&Ast[(w*32 + 16 + lr) * 20 + lk];
    h8v af0 = __builtin_bit_cast(h8v, aw0);
    h8v af1 = __builtin_bit_cast(h8v, aw1);
#pragma unroll
    for (int ct = 0; ct < 8; ++ct) {
      uint4 bw4 = *(const uint4*)&Bst[(ct*16 + lr) * 20 + lk];
      h8v bf = __builtin_bit_cast(h8v, bw4);
      acc[ct][0] = __builtin_amdgcn_mfma_f32_16x16x32_f16(af0, bf, acc[ct][0], 0, 0, 0);
      acc[ct][1] = __builtin_amdgcn_mfma_f32_16x16x32_f16(af1, bf, acc[ct][1], 0, 0, 0);
    }
  }

  float bs[8];
#pragma unroll
  for (int ct = 0; ct < 8; ++ct) bs[ct] = bias[n0 + ct*16 + lr];
  const long mbase = m0 + w*32 + (l >> 4) * 4;

  // per-row partial stats over this block's 128 cols -> atomicAdd into st
#pragma unroll
  for (int mt = 0; mt < 2; ++mt) {
#pragma unroll
    for (int j = 0; j < 4; ++j) {
      float s1 = 0.f, s2 = 0.f;
#pragma unroll
      for (int ct = 0; ct < 8; ++ct) {
        const float v = acc[ct][mt][j] + bs[ct];
        s1 += v; s2 += v * v;
      }
#pragma unroll
      for (int o = 1; o < 16; o <<= 1) {
        s1 += __shfl_xor(s1, o, 16);
        s2 += __shfl_xor(s2, o, 16);
      }
      if (lr == 0) {
        const long m = mbase + mt*16 + j;
        atomicAdd(&st[m*2],     s1);
        atomicAdd(&st[m*2 + 1], s2);
      }
    }
  }

  // pack + store
#pragma unroll
  for (int ct = 0; ct < 8; ++ct) {
    const int cp = (n0 + ct*16 + lr) >> 1;
#pragma unroll
    for (int mt = 0; mt < 2; ++mt) {
#pragma unroll
      for (int j = 0; j < 4; ++j) {
        float v = acc[ct][mt][j] + bs[ct];
        float vh = __shfl_xor(v, 1, 64);
        if (!(l & 1)) {
          const long m = mbase + mt*16 + j;
          C[m * 1024 + cp] = packh2(v, vh);
        }
      }
    }
  }
}

// ---- fused highway via MFMA 16x16x32 f16: 3 projections of the same A rows ----
// A is PACKED-F16 hseq (lda = 256 uint32). GEMM inputs bit-identical to the fp32
// version (staging quantized to f16 anyway); only the epilogue h-term is f16 now.
// out[m][n] = sigf(t1)*relu(t3) + sigf(t2)*A[m][n] (+ seq[m][n] if skip)
__global__ __launch_bounds__(256) void hw_fused_k(
    const uint32* __restrict__ A,      // hseqH + m0*256 (f16 pairs)
    const float* __restrict__ Wt, const float* __restrict__ bt,
    const float* __restrict__ Wc, const float* __restrict__ bc,
    const float* __restrict__ Wh3, const float* __restrict__ bh3,
    float* __restrict__ seqout,        // seq + m0*512
    int skip)
{
  __shared__ __align__(16) uint32 Ast[128 * 20];
  __shared__ __align__(16) uint32 Bst[3 * 64 * 20];
  const int tid = threadIdx.x;
  const long m0 = (long)blockIdx.y * 128;
  const int n0 = blockIdx.x * 64;

  // A staging: row rt, k-half hf (16 f16 = 8 uint32, direct copy)
  const int rt = tid >> 1;
  const int hf = tid & 1;
  const uint32* Arow = A + (m0 + rt) * 256 + hf * 8;
  const int sbaseA = rt * 20 + hf * 8;

  // B staging: 384 half-row units; thread does unit tid and (tid<128) unit tid+256
  const int u1 = tid;
  const int u2 = tid + 256;
  const int m1_ = u1 >> 7, r1_ = (u1 >> 1) & 63, h1_ = u1 & 1;
  const int m2_ = u2 >> 7, r2_ = (u2 >> 1) & 63, h2_ = u2 & 1;
  const float* bsrc1 = (m1_ == 0 ? Wt : (m1_ == 1 ? Wc : Wh3)) + (long)(n0 + r1_) * 512 + h1_ * 16;
  const float* bsrc2 = (m2_ == 0 ? Wt : (m2_ == 1 ? Wc : Wh3)) + (long)(n0 + r2_) * 512 + h2_ * 16;
  const int sbaseB1 = m1_ * 1280 + r1_ * 20 + h1_ * 8;
  const int sbaseB2 = m2_ * 1280 + r2_ * 20 + h2_ * 8;

  const int w  = tid >> 6;
  const int l  = tid & 63;
  const int lr = l & 15;
  const int lk = (l >> 4) * 4;

  f4v acc[3][4][2];
#pragma unroll
  for (int mat = 0; mat < 3; ++mat)
#pragma unroll
    for (int nt = 0; nt < 4; ++nt)
#pragma unroll
      for (int mt = 0; mt < 2; ++mt) {
        acc[mat][nt][mt][0] = 0.f; acc[mat][nt][mt][1] = 0.f;
        acc[mat][nt][mt][2] = 0.f; acc[mat][nt][mt][3] = 0.f;
      }

  for (int ks = 0; ks < 16; ++ks) {
    const int ko = ks * 32;
    __syncthreads();
    {
      uint4 ua0 = *(const uint4*)(Arow + ks*16);
      uint4 ua1 = *(const uint4*)(Arow + ks*16 + 4);
      *(uint4*)&Ast[sbaseA]     = ua0;
      *(uint4*)&Ast[sbaseA + 4] = ua1;
    }
    {
      float4 b0 = *(const float4*)(bsrc1 + ko + 0);
      float4 b1 = *(const float4*)(bsrc1 + ko + 4);
      float4 b2 = *(const float4*)(bsrc1 + ko + 8);
      float4 b3 = *(const float4*)(bsrc1 + ko + 12);
      uint4 ub0, ub1;
      ub0.x = packh2(b0.x, b0.y); ub0.y = packh2(b0.z, b0.w);
      ub0.z = packh2(b1.x, b1.y); ub0.w = packh2(b1.z, b1.w);
      ub1.x = packh2(b2.x, b2.y); ub1.y = packh2(b2.z, b2.w);
      ub1.z = packh2(b3.x, b3.y); ub1.w = packh2(b3.z, b3.w);
      *(uint4*)&Bst[sbaseB1]     = ub0;
      *(uint4*)&Bst[sbaseB1 + 4] = ub1;
    }
    if (tid < 128) {
      float4 b0 = *(const float4*)(bsrc2 + ko + 0);
      float4 b1 = *(const float4*)(bsrc2 + ko + 4);
      float4 b2 = *(const float4*)(bsrc2 + ko + 8);
      float4 b3 = *(const float4*)(bsrc2 + ko + 12);
      uint4 ub0, ub1;
      ub0.x = packh2(b0.x, b0.y); ub0.y = packh2(b0.z, b0.w);
      ub0.z = packh2(b1.x, b1.y); ub0.w = packh2(b1.z, b1.w);
      ub1.x = packh2(b2.x, b2.y); ub1.y = packh2(b2.z, b2.w);
      ub1.z = packh2(b3.x, b3.y); ub1.w = packh2(b3.z, b3.w);
      *(uint4*)&Bst[sbaseB2]     = ub0;
      *(uint4*)&Bst[sbaseB2 + 4] = ub1;
    }
    __syncthreads();

    uint4 aw0 = *(const uint4*)&Ast[(w*32 + lr) * 20 + lk];
    uint4 aw1 = *(const uint4*)&Ast[(w*32 + 16 + lr) * 20 + lk];
    h8v af0 = __builtin_bit_cast(h8v, aw0);
    h8v af1 = __builtin_bit_cast(h8v, aw1);
#pragma unroll
    for (int mat = 0; mat < 3; ++mat) {
#pragma unroll
      for (int nt = 0; nt < 4; ++nt) {
        uint4 bw4 = *(const uint4*)&Bst[mat*1280 + (nt*16 + lr) * 20 + lk];
        h8v bf = __builtin_bit_cast(h8v, bw4);
        acc[mat][nt][0] = __builtin_amdgcn_mfma_f32_16x16x32_f16(af0, bf, acc[mat][nt][0], 0, 0, 0);
        acc[mat][nt][1] = __builtin_amdgcn_mfma_f32_16x16x32_f16(af1, bf, acc[mat][nt][1], 0, 0, 0);
      }
    }
  }

  // epilogue: lane-local highway combine
  float bsT[4], bsC[4], bsH[4];
#pragma unroll
  for (int nt = 0; nt < 4; ++nt) {
    const int col = n0 + nt*16 + lr;
    bsT[nt] = bt[col];
    bsC[nt] = bc[col];
    bsH[nt] = bh3[col];
  }
  const long mbase = m0 + w*32 + (l >> 4) * 4;
#pragma unroll
  for (int nt = 0; nt < 4; ++nt) {
    const int col = n0 + nt*16 + lr;
#pragma unroll
    for (int mt = 0; mt < 2; ++mt) {
#pragma unroll
      for (int j = 0; j < 4; ++j) {
        const long m = mbase + mt*16 + j;
        const float t1 = acc[0][nt][mt][j] + bsT[nt];
        const float t2 = acc[1][nt][mt][j] + bsC[nt];
        const float t3 = acc[2][nt][mt][j] + bsH[nt];
        h2v hp = __builtin_bit_cast(h2v, A[m * 256 + (col >> 1)]);
        const float hvv = (lr & 1) ? (float)hp.y : (float)hp.x;
        const float svv = skip ? seqout[m * 512 + col] : 0.f;
        seqout[m * 512 + col] = sigf(t1) * fmaxf(t3, 0.f) + sigf(t2) * hvv + svv;
      }
    }
  }
}

// ---- M=64 GEMM (used for q projection) ----
__global__ __launch_bounds__(256) void gemm_m64_k(
    const float* __restrict__ A, long lda,
    const float* __restrict__ Bw,
    const float* __restrict__ bias,
    float* __restrict__ P,
    int N, int K)
{
  __shared__ float As[64][64];
  __shared__ float Bs[64][64];
  const int tid = threadIdx.x;
  const int n0 = blockIdx.x * 64;
  const int kc = blockIdx.y;
  const int Kc = K / gridDim.y;
  const int tx = tid & 15, ty = tid >> 4;
  const int row = tid >> 2, q = tid & 3;
  float acc[4][4];
#pragma unroll
  for (int i = 0; i < 4; ++i)
#pragma unroll
    for (int j = 0; j < 4; ++j) acc[i][j] = 0.f;

  for (int k0 = kc * Kc; k0 < kc * Kc + Kc; k0 += 64) {
    float4 a[4], b[4];
#pragma unroll
    for (int c = 0; c < 4; ++c) {
      a[c] = *(const float4*)(A  + (long)row * lda       + k0 + q*16 + c*4);
      b[c] = *(const float4*)(Bw + (long)(n0 + row) * K  + k0 + q*16 + c*4);
    }
    __syncthreads();
#pragma unroll
    for (int c = 0; c < 4; ++c) {
      int kb = q*16 + c*4;
      As[kb+0][row]=a[c].x; As[kb+1][row]=a[c].y; As[kb+2][row]=a[c].z; As[kb+3][row]=a[c].w;
      Bs[kb+0][row]=b[c].x; Bs[kb+1][row]=b[c].y; Bs[kb+2][row]=b[c].z; Bs[kb+3][row]=b[c].w;
    }
    __syncthreads();
#pragma unroll
    for (int kk = 0; kk < 64; ++kk) {
      float4 av = *(const float4*)&As[kk][ty*4];
      float4 bv = *(const float4*)&Bs[kk][tx*4];
      float am[4] = {av.x, av.y, av.z, av.w};
      float bm[4] = {bv.x, bv.y, bv.z, bv.w};
#pragma unroll
      for (int i = 0; i < 4; ++i)
#pragma unroll
        for (int j = 0; j < 4; ++j) acc[i][j] += am[i] * bm[j];
    }
  }
#pragma unroll
  for (int i = 0; i < 4; ++i) {
    int m = ty*4 + i;
    float* pr = P + ((long)kc * 64 + m) * N + n0 + tx*4;
#pragma unroll
    for (int j = 0; j < 4; ++j) {
      float bb = bias ? bias[n0 + tx*4 + j] : 0.f;
      pr[j] = acc[i][j] + bb;
    }
  }
}

// ---- persistent LSTM recurrence: n-split + tagged-word single-round exchange ----
// (exchange/GEMV/LDS/publish machinery byte-identical to rounds 5-12, verified.
//  Publish pattern myword=kq*512+tid gives contiguous full-line wave stores --
//  DO NOT change it. Packed-h LDS split lo/hi at +132 words keeps broadcast
//  reads on disjoint bank quads.
//  NEW vs round 12 (both outside the exchange machinery): (a) ipstats now holds
//  raw (s1,s2) sums -> mean/rstd computed inline; (b) hseq stored as packed f16
//  pairs by even threads, reusing the repack shfl values.)
__global__ __launch_bounds__(512, 2) void lstm_seqz_k(
    const uint32* __restrict__ WhP,   // [256 kp][2048 n] this layer (f16 pairs)
    const float* __restrict__ bh,
    const uint32* __restrict__ ipc,   // [TCH*64][1024] raw ip (f16 pairs, +bias)
    const float* __restrict__ ipstats,// [TCH*64][2] raw (s1, s2)
    const float* __restrict__ g_in, const float* __restrict__ b_in,
    const float* __restrict__ g_hid, const float* __restrict__ b_hid,
    const float* __restrict__ g_cell, const float* __restrict__ b_cell,
    float* __restrict__ hst, float* __restrict__ cst,  // [64][512]
    uint32* __restrict__ hseqH,       // [B,S,256] packed f16 pairs
    uint64* __restrict__ zbuf,        // [2 parity][32 g][2048 row][2 b] tagged words
    int t0, int nsteps, int gbase)    // gbase >= 1, monotonic over the whole run
{
  const int blk = blockIdx.x;
  const int g   = blk & 31;
  const int kq  = blk >> 5;
  const int tid = threadIdx.x;
  const int b0  = g*2, b1 = g*2 + 1;
  const int r   = tid >> 1;          // row within our 256-row slice
  const int kh  = tid & 1;           // k-half (0: k<256, 1: k>=256)
  __shared__ __align__(16) uint32 hp0[264];
  __shared__ __align__(16) uint32 hp1[264];
  __shared__ float sm[32];

  // register-resident weights: rows kq*256+r, k-pairs kh*128 + [0,128)
  uint4 wreg[32];
  {
    const uint32* base = WhP + (long)(kh * 128) * 2048 + (kq*256 + r);
#pragma unroll
    for (int i = 0; i < 32; ++i) {
      wreg[i].x = base[(long)(4*i + 0) * 2048];
      wreg[i].y = base[(long)(4*i + 1) * 2048];
      wreg[i].z = base[(long)(4*i + 2) * 2048];
      wreg[i].w = base[(long)(4*i + 3) * 2048];
    }
  }

  // per-unit params/state: thread owns unit tid (both batches)
  float bhr[4], ghr[4], bhir[4], ginr[4], binr[4];
#pragma unroll
  for (int q = 0; q < 4; ++q) {
    bhr[q]  = bh[q*512 + tid];
    ghr[q]  = g_hid[q*512 + tid];
    bhir[q] = b_hid[q*512 + tid];
    ginr[q] = g_in[q*512 + tid];
    binr[q] = b_in[q*512 + tid];
  }
  const float gcv = g_cell[tid];
  const float bcv = b_cell[tid];
  float c0 = cst[b0*512 + tid];
  float c1 = cst[b1*512 + tid];
  float h0 = hst[b0*512 + tid];
  float h1 = hst[b1*512 + tid];

  // initial full-h pack into LDS (lo at j, hi at j+4 for j>=128)
  {
    const float p0 = __shfl_xor(h0, 1, 64);
    const float p1 = __shfl_xor(h1, 1, 64);
    if (!(tid & 1)) {
      const int j = tid >> 1;
      const int jj = (j < 128) ? j : j + 4;
      hp0[jj] = packh2(h0, p0);
      hp1[jj] = packh2(h1, p1);
    }
  }
  __syncthreads();

  const long myword = (long)(kq*256 + r) * 2 + kh;   // = kq*512 + tid (contiguous)
  const uint32* hb0 = hp0 + kh * 132;
  const uint32* hb1 = hp1 + kh * 132;

  for (int ts = 0; ts < nsteps; ++ts) {
    const int gstep = gbase + ts;
    const uint32 tagw = (uint32)gstep;
    uint64* zp = zbuf + (long)(gstep & 1) * 131072 + (long)g * 4096;

    // ip: packed-f16 load + on-the-fly LN from raw (s1,s2) stats
    const uint32* iprow0 = ipc + ((long)ts * 64 + b0) * 1024 + (tid >> 1);
    const uint32* iprow1 = ipc + ((long)ts * 64 + b1) * 1024 + (tid >> 1);
    const float2 st0 = *(const float2*)(ipstats + ((long)ts * 64 + b0) * 2);
    const float2 st1 = *(const float2*)(ipstats + ((long)ts * 64 + b1) * 2);
    const float ipm0 = st0.x * (1.f/2048.f);
    const float ipr0 = rsqrtf(st0.y * (1.f/2048.f) - ipm0*ipm0 + EPS_LN);
    const float ipm1 = st1.x * (1.f/2048.f);
    const float ipr1 = rsqrtf(st1.y * (1.f/2048.f) - ipm1*ipm1 + EPS_LN);
    float ip0[4], ip1[4];
#pragma unroll
    for (int q = 0; q < 4; ++q) {
      h2v v0 = __builtin_bit_cast(h2v, iprow0[q*256]);
      h2v v1 = __builtin_bit_cast(h2v, iprow1[q*256]);
      const float r0 = kh ? (float)v0.y : (float)v0.x;
      const float r1 = kh ? (float)v1.y : (float)v1.x;
      ip0[q] = (r0 - ipm0) * ipr0 * ginr[q] + binr[q];
      ip1[q] = (r1 - ipm1) * ipr1 * ginr[q] + binr[q];
    }

    // GEMV: full-k half for row kq*256+r, both batches (h via LDS broadcast)
    float a0 = 0.f, a1 = 0.f;
#pragma unroll
    for (int i = 0; i < 32; ++i) {
      const uint4 w  = wreg[i];
      const uint4 hv0 = *(const uint4*)&hb0[4*i];
      const uint4 hv1 = *(const uint4*)&hb1[4*i];
      a0 = dot2h(w.x, hv0.x, a0); a0 = dot2h(w.y, hv0.y, a0);
      a0 = dot2h(w.z, hv0.z, a0); a0 = dot2h(w.w, hv0.w, a0);
      a1 = dot2h(w.x, hv1.x, a1); a1 = dot2h(w.y, hv1.y, a1);
      a1 = dot2h(w.z, hv1.z, a1); a1 = dot2h(w.w, hv1.w, a1);
    }
    // combine k-halves within the lane pair
    a0 += __shfl_xor(a0, 1, 64);
    a1 += __shfl_xor(a1, 1, 64);

    // publish one tagged word (fire-and-forget; tag rides with payload)
    {
      const float zval = kh ? a1 : a0;
      const uint64 w = ((uint64)tagw << 32) | (uint64)__builtin_bit_cast(uint32, zval);
      __hip_atomic_store(zp + myword, w, __ATOMIC_RELAXED, __HIP_MEMORY_SCOPE_AGENT);
    }

    // gather the 8 tagged words for unit tid
    float z0[4], z1[4];
    {
      uint64 v0[4], v1[4];
      int pend = 0xff;
      while (pend) {
#pragma unroll
        for (int q = 0; q < 4; ++q) {
          const long base = (long)(q*512 + tid) * 2;
          if (pend & (1 << q)) {
            uint64 w = __hip_atomic_load(zp + base, __ATOMIC_RELAXED, __HIP_MEMORY_SCOPE_AGENT);
            if ((uint32)(w >> 32) == tagw) { v0[q] = w; pend &= ~(1 << q); }
          }
          if (pend & (16 << q)) {
            uint64 w = __hip_atomic_load(zp + base + 1, __ATOMIC_RELAXED, __HIP_MEMORY_SCOPE_AGENT);
            if ((uint32)(w >> 32) == tagw) { v1[q] = w; pend &= ~(16 << q); }
          }
        }
        if (pend) __builtin_amdgcn_s_sleep(2);
      }
#pragma unroll
      for (int q = 0; q < 4; ++q) {
        z0[q] = __builtin_bit_cast(float, (uint32)v0[q]) + bhr[q];
        z1[q] = __builtin_bit_cast(float, (uint32)v1[q]) + bhr[q];
      }
    }

    // LN1 over 2048, both batches in one reduction pass
    float s10 = z0[0]+z0[1]+z0[2]+z0[3];
    float s20 = z0[0]*z0[0] + z0[1]*z0[1] + z0[2]*z0[2] + z0[3]*z0[3];
    float s11 = z1[0]+z1[1]+z1[2]+z1[3];
    float s21 = z1[0]*z1[0] + z1[1]*z1[1] + z1[2]*z1[2] + z1[3]*z1[3];
    blk_sum4_w8(s10, s20, s11, s21, sm, tid);
    const float m0 = s10 * (1.f/2048.f);
    const float r0 = rsqrtf(s20 * (1.f/2048.f) - m0*m0 + EPS_LN);
    const float m1 = s11 * (1.f/2048.f);
    const float r1 = rsqrtf(s21 * (1.f/2048.f) - m1*m1 + EPS_LN);

    const float gi0 = ip0[0] + (z0[0] - m0) * r0 * ghr[0] + bhir[0];
    const float gf0 = ip0[1] + (z0[1] - m0) * r0 * ghr[1] + bhir[1];
    const float gg0 = ip0[2] + (z0[2] - m0) * r0 * ghr[2] + bhir[2];
    const float go0 = ip0[3] + (z0[3] - m0) * r0 * ghr[3] + bhir[3];
    const float gi1 = ip1[0] + (z1[0] - m1) * r1 * ghr[0] + bhir[0];
    const float gf1 = ip1[1] + (z1[1] - m1) * r1 * ghr[1] + bhir[1];
    const float gg1 = ip1[2] + (z1[2] - m1) * r1 * ghr[2] + bhir[2];
    const float go1 = ip1[3] + (z1[3] - m1) * r1 * ghr[3] + bhir[3];

    c0 = sigf(gf0) * c0 + sigf(gi0) * tanhfast(gg0);
    c1 = sigf(gf1) * c1 + sigf(gi1) * tanhfast(gg1);

    // LN2 over 512 cells, both batches in one pass
    float t10 = c0, t20 = c0*c0, t11 = c1, t21 = c1*c1;
    blk_sum4_w8(t10, t20, t11, t21, sm, tid);
    const float n0 = t10 * (1.f/512.f);
    const float q0r = rsqrtf(t20 * (1.f/512.f) - n0*n0 + EPS_LN);
    const float n1 = t11 * (1.f/512.f);
    const float q1r = rsqrtf(t21 * (1.f/512.f) - n1*n1 + EPS_LN);
    h0 = sigf(go0) * tanhfast((c0 - n0) * q0r * gcv + bcv);
    h1 = sigf(go1) * tanhfast((c1 - n1) * q1r * gcv + bcv);

    // repack full h into LDS for next step; even threads also store packed hseq
    const float p0 = __shfl_xor(h0, 1, 64);
    const float p1 = __shfl_xor(h1, 1, 64);
    if (!(tid & 1)) {
      const int j = tid >> 1;
      const int jj = (j < 128) ? j : j + 4;
      hp0[jj] = packh2(h0, p0);
      hp1[jj] = packh2(h1, p1);
      if (kq == 0) {
        hseqH[((long)b0 * Sn + t0 + ts) * 256 + j] = packh2(h0, p0);
        hseqH[((long)b1 * Sn + t0 + ts) * 256 + j] = packh2(h1, p1);
      }
    }
    __syncthreads();
  }
  if (kq == 0) {
    hst[b0*512 + tid] = h0; hst[b1*512 + tid] = h1;
    cst[b0*512 + tid] = c0; cst[b1*512 + tid] = c1;
  }
}

__global__ void init_hc_k(float* h, float* c)
{
  int i = blockIdx.x * 256 + threadIdx.x;
  h[i] = 0.f; c[i] = 0.f;
}

// ---- qkh[b][hd][:] = sum_{j in head} q[b, hd*64+j] * Wk[hd*64+j, :]; qbk = q.bk ----
__global__ __launch_bounds__(256) void qkh_k(
    const float* __restrict__ qlst, const float* __restrict__ Wk,
    const float* __restrict__ bk,
    float* __restrict__ qkh, float* __restrict__ qbk)
{
  const int hd = blockIdx.x, cg = blockIdx.y;
  const int b = threadIdx.x & 63, sc = threadIdx.x >> 6;
  const int col0 = cg * 128 + sc * 32;
  float qreg[64];
  const float* qp = qlst + b*512 + hd*64;
#pragma unroll
  for (int j4 = 0; j4 < 16; ++j4) {
    float4 v = *(const float4*)(qp + j4*4);
    qreg[j4*4+0]=v.x; qreg[j4*4+1]=v.y; qreg[j4*4+2]=v.z; qreg[j4*4+3]=v.w;
  }
  float acc[32];
#pragma unroll
  for (int c = 0; c < 32; ++c) acc[c] = 0.f;
  for (int j = 0; j < 64; ++j) {
    float qv = qreg[j];
    const float* wr = Wk + (long)(hd*64 + j)*512 + col0;
#pragma unroll
    for (int c4 = 0; c4 < 8; ++c4) {
      float4 w = *(const float4*)(wr + c4*4);
      acc[c4*4+0] = __builtin_fmaf(qv, w.x, acc[c4*4+0]);
      acc[c4*4+1] = __builtin_fmaf(qv, w.y, acc[c4*4+1]);
      acc[c4*4+2] = __builtin_fmaf(qv, w.z, acc[c4*4+2]);
      acc[c4*4+3] = __builtin_fmaf(qv, w.w, acc[c4*4+3]);
    }
  }
  float* op = qkh + ((long)b*8 + hd)*512 + col0;
#pragma unroll
  for (int c4 = 0; c4 < 8; ++c4) {
    float4 o;
    o.x = acc[c4*4+0]; o.y = acc[c4*4+1]; o.z = acc[c4*4+2]; o.w = acc[c4*4+3];
    *(float4*)(op + c4*4) = o;
  }
  if (cg == 0 && sc == 0) {
    float s = 0.f;
    for (int j = 0; j < 64; ++j) s += qreg[j] * bk[hd*64 + j];
    qbk[b*8 + hd] = s;
  }
}

// ---- fused last-row attention ----
__global__ __launch_bounds__(256) void attn2_k(
    const float* __restrict__ seq,   // [B,S,H]
    const float* __restrict__ qkh,   // [64][8][512]
    const float* __restrict__ qbk,   // [64][8]
    float* __restrict__ u)           // [64][8][512]
{
  const int b = blockIdx.x, hd = blockIdx.y, tid = threadIdx.x;
  __shared__ __align__(16) float qk[512];
  __shared__ float p[512];
  __shared__ float sm[4];
  qk[tid]       = qkh[((long)b*8 + hd)*512 + tid];
  qk[tid + 256] = qkh[((long)b*8 + hd)*512 + tid + 256];
  __syncthreads();
  const float bias = qbk[b*8 + hd];

  float loc[2]; float mx = -3.0e38f;
#pragma unroll
  for (int v = 0; v < 2; ++v) {
    int s = tid + v*256;
    const float4* sr = (const float4*)(seq + ((long)b*512 + s)*512);
    const float4* qv4 = (const float4*)qk;
    float d = 0.f;
    for (int k4 = 0; k4 < 128; ++k4) {
      float4 sv = sr[k4], qv = qv4[k4];
      d += sv.x*qv.x + sv.y*qv.y + sv.z*qv.z + sv.w*qv.w;
    }
    d = (d + bias) * 0.125f;
    loc[v] = d; mx = fmaxf(mx, d);
  }
  const float M = blk_max(mx, sm, tid);
  float sum = 0.f;
#pragma unroll
  for (int v = 0; v < 2; ++v) {
    int s = tid + v*256;
    float e = __expf(loc[v] - M);
    p[s] = e; sum += e;
  }
  const float SM = blk_sum(sum, sm, tid);
  const float inv = 1.f / SM;

  float u0 = 0.f, u1 = 0.f;
  for (int s = 0; s < 512; ++s) {
    float ps = p[s];
    const float* srow = seq + ((long)b*512 + s)*512;
    u0 = __builtin_fmaf(ps, srow[tid], u0);
    u1 = __builtin_fmaf(ps, srow[tid + 256], u1);
  }
  u[((long)b*8 + hd)*512 + tid]       = u0 * inv;
  u[((long)b*8 + hd)*512 + tid + 256] = u1 * inv;
}

// ---- ctx[b][n] = u[b][hd(n)][:] . Wv[n][:] + bv[n] ----
__global__ __launch_bounds__(256) void ctxv_k(
    const float* __restrict__ u, const float* __restrict__ Wv,
    const float* __restrict__ bv, float* __restrict__ ctx)
{
  const int b = blockIdx.x, tid = threadIdx.x;
  __shared__ __align__(16) float ul[8*512];
  for (int i = tid; i < 4096; i += 256) ul[i] = u[(long)b*4096 + i];
  __syncthreads();
#pragma unroll
  for (int v = 0; v < 2; ++v) {
    int n = tid + v*256;
    int hd = n >> 6;
    const float4* wr = (const float4*)(Wv + (long)n*512);
    const float4* uv = (const float4*)&ul[hd*512];
    float acc = 0.f;
    for (int k4 = 0; k4 < 128; ++k4) {
      float4 w = wr[k4], x = uv[k4];
      acc += w.x*x.x + w.y*x.y + w.z*x.z + w.w*x.w;
    }
    ctx[b*512 + n] = acc + bv[n];
  }
}

// ---- output head ----
__global__ __launch_bounds__(256) void head_k(
    const float* __restrict__ ctx,
    const float* __restrict__ Wo, const float* __restrict__ bo,
    const float* __restrict__ seq,
    const float* __restrict__ att_g, const float* __restrict__ att_b,
    const float* __restrict__ on_g, const float* __restrict__ on_b,
    const float* __restrict__ Wp1, const float* __restrict__ bp1,
    const float* __restrict__ Wp2, const float* __restrict__ bp2,
    float* __restrict__ out)
{
  const int b = blockIdx.x, tid = threadIdx.x;
  __shared__ __align__(16) float cs[512];
  __shared__ __align__(16) float buf[512];
  __shared__ float sm[4];
  cs[tid]       = ctx[b*512 + tid];
  cs[tid + 256] = ctx[b*512 + tid + 256];
  __syncthreads();

  const float* srow = seq + ((long)b*512 + 511) * 512;
  float o[2];
#pragma unroll
  for (int v = 0; v < 2; ++v) {
    int j = tid + v*256;
    const float4* w4 = (const float4*)(Wo + (long)j * 512);
    const float4* c4 = (const float4*)cs;
    float acc = 0.f;
    for (int kx = 0; kx < 128; ++kx) {
      float4 w = w4[kx], c = c4[kx];
      acc += w.x*c.x + w.y*c.y + w.z*c.z + w.w*c.w;
    }
    o[v] = acc + bo[j] + srow[j];
  }
  float s1 = o[0] + o[1], s2 = o[0]*o[0] + o[1]*o[1];
  s1 = blk_sum(s1, sm, tid); s2 = blk_sum(s2, sm, tid);
  float m1 = s1 * (1.f/512.f);
  float r1 = rsqrtf(s2 * (1.f/512.f) - m1*m1 + EPS_LN);
  float a[2];
#pragma unroll
  for (int v = 0; v < 2; ++v) {
    int j = tid + v*256;
    a[v] = (o[v] - m1) * r1 * att_g[j] + att_b[j];
  }
  s1 = a[0] + a[1]; s2 = a[0]*a[0] + a[1]*a[1];
  s1 = blk_sum(s1, sm, tid); s2 = blk_sum(s2, sm, tid);
  float m2 = s1 * (1.f/512.f);
  float r2 = rsqrtf(s2 * (1.f/512.f) - m2*m2 + EPS_LN);
#pragma unroll
  for (int v = 0; v < 2; ++v) {
    int j = tid + v*256;
    buf[j] = (a[v] - m2) * r2 * on_g[j] + on_b[j];
  }
  __syncthreads();

  const float4* w1 = (const float4*)(Wp1 + (long)tid * 512);
  const float4* b4 = (const float4*)buf;
  float acc = 0.f;
  for (int kx = 0; kx < 128; ++kx) {
    float4 w = w1[kx], c = b4[kx];
    acc += w.x*c.x + w.y*c.y + w.z*c.z + w.w*c.w;
  }
  float mid = fmaxf(acc + bp1[tid], 0.f);
  float contrib = mid * Wp2[tid];
  float tot = blk_sum(contrib, sm, tid);
  if (tid == 0) out[b] = tot + bp2[0];
}

extern "C" void kernel_launch(void* const* d_in, const int* in_sizes, int n_in,
                              void* d_out, int out_size, void* d_ws, size_t ws_size,
                              hipStream_t stream)
{
  const float* x     = (const float*)d_in[0];
  const float* Wi    = (const float*)d_in[1];
  const float* bi    = (const float*)d_in[2];
  const float* Wh    = (const float*)d_in[3];
  const float* bh    = (const float*)d_in[4];
  const float* g_in  = (const float*)d_in[5];
  const float* b_in  = (const float*)d_in[6];
  const float* g_hid = (const float*)d_in[7];
  const float* b_hid = (const float*)d_in[8];
  const float* g_cell= (const float*)d_in[9];
  const float* b_cell= (const float*)d_in[10];
  const float* hwWt  = (const float*)d_in[11];
  const float* hwbt  = (const float*)d_in[12];
  const float* hwWc  = (const float*)d_in[13];
  const float* hwbc  = (const float*)d_in[14];
  const float* hwWh  = (const float*)d_in[15];
  const float* hwbh  = (const float*)d_in[16];
  const float* Wq    = (const float*)d_in[17];
  const float* bq    = (const float*)d_in[18];
  const float* Wk    = (const float*)d_in[19];
  const float* bk    = (const float*)d_in[20];
  const float* Wv    = (const float*)d_in[21];
  const float* bv    = (const float*)d_in[22];
  const float* Wo    = (const float*)d_in[23];
  const float* bo    = (const float*)d_in[24];
  const float* att_g = (const float*)d_in[25];
  const float* att_b = (const float*)d_in[26];
  const float* on_g  = (const float*)d_in[27];
  const float* on_b  = (const float*)d_in[28];
  const float* Wp1   = (const float*)d_in[29];
  const float* bp1   = (const float*)d_in[30];
  const float* Wp2   = (const float*)d_in[31];
  const float* bp2   = (const float*)d_in[32];
  float* out = (float*)d_out;

  // ---- workspace layout (floats); never touches d_in ----
  const long SEQF  = (long)Bn * Sn * Hn;     // 16,777,216
  const long HSEQF = SEQF / 2;               // 8,388,608 uint32 slots (f16 hseq)
  const long WHPF  = 2L * 256 * G4n;         // 1,048,576 (uint32 slots)
  const long ZBF   = 2L * 32 * 2048 * 2;     // 262,144 uint64
  const long wsF   = (long)(ws_size / 4);

  float* ws   = (float*)d_ws;
  float* seq  = ws;                  // [B,S,H] fp32
  uint32* hseqH = (uint32*)(seq + SEQF);     // [B,S,256] f16 pairs
  uint32* WhP = (uint32*)(seq + SEQF + HSEQF);
  uint64* zbuf = (uint64*)(seq + SEQF + HSEQF + WHPF);
  float* hst  = seq + SEQF + HSEQF + WHPF + 2*ZBF;  // [64][512]
  float* cst  = hst  + 32768L;
  float* qlst = cst  + 32768L;       // [64][512]
  float* ctx  = qlst + 32768L;       // [64][512]
  float* qkh  = ctx  + 32768L;       // [64][8][512]
  float* qbk  = qkh  + 262144L;      // [64][8] (pad to 1024)
  float* uat  = qbk  + 1024L;        // [64][8][512]
  float* ipstats = uat + 262144L;    // [TCH*64][2] raw sums (pad to 65536)
  float* ipcF = ipstats + 65536L;    // [TCH*64][1024 uint32] f16 ip pairs
  uint32* ipc = (uint32*)ipcF;
  const long baseF = (ipcF - ws);

  // f16 ipc + f16 hseq: try TCH=512, fall back if workspace too small
  int TCH = 512;
  while (TCH > 16 && baseF + (long)TCH * 64 * 1024 > wsF) TCH >>= 1;

  wh_pack_k<<<dim3(16, 64, 2), 256, 0, stream>>>(Wh, WhP);
  init_zbuf_k<<<512, 512, 0, stream>>>(zbuf);

  const int NCH = Sn / TCH;
  const int MROWS = TCH * 64;
  const int NMCH = (Bn * Sn) / MROWS;

  for (int l = 0; l < 2; ++l) {
    const float* seqin = (l == 0) ? x : seq;
    init_hc_k<<<128, 256, 0, stream>>>(hst, cst);
    for (int c = 0; c < NCH; ++c) {
      const int s0 = c * TCH;
      hipMemsetAsync(ipstats, 0, (size_t)TCH * 64 * 2 * sizeof(float), stream);
      gemm_ip_k<<<dim3(16, TCH/2), 256, 0, stream>>>(seqin, Wi + (long)l*G4n*Hn, bi + l*G4n, ipc, ipstats, s0);
      lstm_seqz_k<<<256, 512, 0, stream>>>(WhP + (long)l*256*G4n, bh + l*G4n, ipc, ipstats,
          g_in + l*G4n, b_in + l*G4n,
          g_hid + l*G4n, b_hid + l*G4n, g_cell + l*Hn, b_cell + l*Hn,
          hst, cst, hseqH, zbuf, s0, TCH, l*Sn + s0 + 1);
    }
    // fused highway: 3 MFMA GEMMs + elementwise combine, writes seq (A = f16 hseq)
    for (int mc = 0; mc < NMCH; ++mc) {
      const long m0 = (long)mc * MROWS;
      hw_fused_k<<<dim3(8, MROWS/128), 256, 0, stream>>>(
          hseqH + m0*256,
          hwWt + (long)l*Hn*Hn, hwbt + l*Hn,
          hwWc + (long)l*Hn*Hn, hwbc + l*Hn,
          hwWh + (long)l*Hn*Hn, hwbh + l*Hn,
          seq + m0*512, (l == 0) ? 0 : 1);
    }
  }

  // attention on last query row, K/V never materialized
  gemm_m64_k<<<dim3(8, 1), 256, 0, stream>>>(seq + 511L*512, 512L*512, Wq, bq, qlst, 512, 512);
  qkh_k<<<dim3(8, 4), 256, 0, stream>>>(qlst, Wk, bk, qkh, qbk);
  attn2_k<<<dim3(64, 8), 256, 0, stream>>>(seq, qkh, qbk, uat);
  ctxv_k<<<64, 256, 0, stream>>>(uat, Wv, bv, ctx);
  head_k<<<64, 256, 0, stream>>>(ctx, Wo, bo, seq, att_g, att_b, on_g, on_b, Wp1, bp1, Wp2, bp2, out);
}